// Round 1
// baseline (3229.174 us; speedup 1.0000x reference)
//
#include <hip/hip_runtime.h>
#include <math.h>

// ---------------------------------------------------------------------------
// ConformerBlock: fp32 correctness-first implementation.
// B=4, T=2048, D=512, H=8, hd=64, K=31.  M = B*T = 8192.
// ---------------------------------------------------------------------------

#define MM 8192
#define DD 512

__device__ __forceinline__ float blk_sum256(float v, float* sm) {
#pragma unroll
  for (int m = 32; m; m >>= 1) v += __shfl_xor(v, m);
  int w = threadIdx.x >> 6;
  __syncthreads();
  if ((threadIdx.x & 63) == 0) sm[w] = v;
  __syncthreads();
  return sm[0] + sm[1] + sm[2] + sm[3];
}

__device__ __forceinline__ float blk_max256(float v, float* sm) {
#pragma unroll
  for (int m = 32; m; m >>= 1) v = fmaxf(v, __shfl_xor(v, m));
  int w = threadIdx.x >> 6;
  __syncthreads();
  if ((threadIdx.x & 63) == 0) sm[w] = v;
  __syncthreads();
  return fmaxf(fmaxf(sm[0], sm[1]), fmaxf(sm[2], sm[3]));
}

__device__ __forceinline__ float qdq(float v, float s) {
  // quantize-dequantize: clip(rint(v*s), -128, 127)/s  (rint = round-half-even)
  return fminf(fmaxf(rintf(v * s), -128.f), 127.f) / s;
}

// ---------------------------------------------------------------------------
// Weight quantization: mean(|w|) fixed-tree reduction + ternary quant.
// ---------------------------------------------------------------------------
__global__ __launch_bounds__(256) void wabs_stage1(
    const float* __restrict__ w0, const float* __restrict__ w1,
    const float* __restrict__ w2, const float* __restrict__ w3,
    const float* __restrict__ w4, const float* __restrict__ w5,
    float* __restrict__ part) {
  __shared__ float sm[4];
  const float* ws[6] = {w0, w1, w2, w3, w4, w5};
  const int ns[6] = {1048576, 1048576, 524288, 262144, 1048576, 1048576};
  int widx = blockIdx.x >> 6;
  int chunk = blockIdx.x & 63;
  const float* w = ws[widx];
  int n = ns[widx];
  float s = 0.f;
  for (int i = chunk * 256 + threadIdx.x; i < n; i += 64 * 256) s += fabsf(w[i]);
  s = blk_sum256(s, sm);
  if (threadIdx.x == 0) part[widx * 64 + chunk] = s;
}

__global__ void wabs_stage2(const float* __restrict__ part, float* __restrict__ scales) {
  int t = threadIdx.x;
  if (t < 6) {
    const int ns[6] = {1048576, 1048576, 524288, 262144, 1048576, 1048576};
    float s = 0.f;
    for (int i = 0; i < 64; ++i) s += part[t * 64 + i];
    float mean = s / (float)ns[t];
    scales[t] = fmaxf(mean, 1e-5f);  // invs = clip(mean|w|, 1e-5); w_scale s = 1/invs
  }
}

__global__ __launch_bounds__(256) void wquant(
    const float* __restrict__ w, const float* __restrict__ invs_ptr,
    float* __restrict__ out, int n) {
  float s = 1.0f / *invs_ptr;
  for (int i = blockIdx.x * 256 + threadIdx.x; i < n; i += gridDim.x * 256)
    out[i] = fminf(fmaxf(rintf(w[i] * s), -1.f), 1.f);  // ternary, undivided
}

// ---------------------------------------------------------------------------
// RMSNorm (+ optional act_quant) over rows of width 512.
// ---------------------------------------------------------------------------
__global__ __launch_bounds__(256) void rmsnorm_quant(
    const float* __restrict__ x, const float* __restrict__ w,
    float* __restrict__ out, int quant) {
  __shared__ float sm[4];
  int row = blockIdx.x, tid = threadIdx.x;
  const float* xr = x + (size_t)row * DD;
  float v0 = xr[tid], v1 = xr[tid + 256];
  float ss = blk_sum256(v0 * v0 + v1 * v1, sm);
  float scale = 1.0f / sqrtf(ss * (1.0f / DD) + 1e-6f);
  float y0 = v0 * scale * w[tid];
  float y1 = v1 * scale * w[tid + 256];
  if (quant) {
    float am = blk_max256(fmaxf(fabsf(y0), fabsf(y1)), sm);
    float s = 127.0f / fmaxf(am, 1e-5f);
    y0 = qdq(y0, s);
    y1 = qdq(y1, s);
  }
  out[(size_t)row * DD + tid] = y0;
  out[(size_t)row * DD + tid + 256] = y1;
}

// ---------------------------------------------------------------------------
// snake_beta + act_quant, in-place on rows of width 2048 (FFN hidden).
// ---------------------------------------------------------------------------
__global__ __launch_bounds__(256) void snake_quant(
    float* __restrict__ h, const float* __restrict__ la, const float* __restrict__ lb) {
  __shared__ float sm[4];
  int row = blockIdx.x, tid = threadIdx.x;
  float* hr = h + (size_t)row * 2048;
  float vals[8];
  float am = 0.f;
#pragma unroll
  for (int i = 0; i < 8; ++i) {
    int c = tid + (i << 8);
    float v = hr[c];
    float a = expf(la[c]);
    float bb = expf(lb[c]);
    float s = sinf(a * v);
    v = v + s * s / (bb + 1e-9f);
    vals[i] = v;
    am = fmaxf(am, fabsf(v));
  }
  am = blk_max256(am, sm);
  float s = 127.0f / fmaxf(am, 1e-5f);
#pragma unroll
  for (int i = 0; i < 8; ++i) hr[tid + (i << 8)] = qdq(vals[i], s);
}

// ---------------------------------------------------------------------------
// Generic fp32 GEMM:  out[M,N] = resid + rscale*( (A[M,K] @ B[N,K]^T)*wsc + bias )
// Tile 64x64, BK=16, 256 threads, 4x4 accum per thread, transposed LDS.
// Requires M%64==0, N%64==0, K%16==0.
// ---------------------------------------------------------------------------
__global__ __launch_bounds__(256) void gemm_f32(
    const float* __restrict__ A, const float* __restrict__ B,
    const float* __restrict__ bias, const float* __restrict__ wsp,
    const float* __restrict__ resid, float rscale,
    float* __restrict__ out, int M, int N, int K) {
  __shared__ __align__(16) float As[16][68];
  __shared__ __align__(16) float Bs[16][68];
  const int tid = threadIdx.x;
  const int m0 = blockIdx.y << 6;
  const int n0 = blockIdx.x << 6;
  const int rt = tid >> 4, ct = tid & 15;
  const int lr = tid >> 2, lc = (tid & 3) << 2;
  float acc[4][4] = {};
  const float* Aptr = A + (size_t)(m0 + lr) * K + lc;
  const float* Bptr = B + (size_t)(n0 + lr) * K + lc;
  for (int k0 = 0; k0 < K; k0 += 16) {
    float4 av = *reinterpret_cast<const float4*>(Aptr + k0);
    float4 bv = *reinterpret_cast<const float4*>(Bptr + k0);
    __syncthreads();
    As[lc + 0][lr] = av.x; As[lc + 1][lr] = av.y;
    As[lc + 2][lr] = av.z; As[lc + 3][lr] = av.w;
    Bs[lc + 0][lr] = bv.x; Bs[lc + 1][lr] = bv.y;
    Bs[lc + 2][lr] = bv.z; Bs[lc + 3][lr] = bv.w;
    __syncthreads();
#pragma unroll
    for (int kk = 0; kk < 16; ++kk) {
      const float4 a4 = *reinterpret_cast<const float4*>(&As[kk][rt << 2]);
      const float4 b4 = *reinterpret_cast<const float4*>(&Bs[kk][ct << 2]);
      float am[4] = {a4.x, a4.y, a4.z, a4.w};
      float bn[4] = {b4.x, b4.y, b4.z, b4.w};
#pragma unroll
      for (int i = 0; i < 4; ++i)
#pragma unroll
        for (int j = 0; j < 4; ++j) acc[i][j] = fmaf(am[i], bn[j], acc[i][j]);
    }
  }
  const float wsc = wsp ? *wsp : 1.0f;
  float bias4[4] = {0.f, 0.f, 0.f, 0.f};
  if (bias) {
    const float4 b4 = *reinterpret_cast<const float4*>(&bias[n0 + (ct << 2)]);
    bias4[0] = b4.x; bias4[1] = b4.y; bias4[2] = b4.z; bias4[3] = b4.w;
  }
#pragma unroll
  for (int i = 0; i < 4; ++i) {
    const size_t ob = (size_t)(m0 + (rt << 2) + i) * N + n0 + (ct << 2);
    float4 r4 = make_float4(0.f, 0.f, 0.f, 0.f);
    if (resid) r4 = *reinterpret_cast<const float4*>(&resid[ob]);
    float4 o4;
    o4.x = r4.x + rscale * (acc[i][0] * wsc + bias4[0]);
    o4.y = r4.y + rscale * (acc[i][1] * wsc + bias4[1]);
    o4.z = r4.z + rscale * (acc[i][2] * wsc + bias4[2]);
    o4.w = r4.w + rscale * (acc[i][3] * wsc + bias4[3]);
    *reinterpret_cast<float4*>(&out[ob]) = o4;
  }
}

// ---------------------------------------------------------------------------
// Flash attention, fp32. qkv [8192,1536] (q|k|v each 512 = 8 heads x 64).
// Grid (32 q-tiles, 32 b*h). Block 256. Online softmax, full (non-causal).
// out [8192,512].
// ---------------------------------------------------------------------------
__global__ __launch_bounds__(256) void attn_f32(
    const float* __restrict__ qkv, float* __restrict__ out) {
  __shared__ __align__(16) float Qs[64][68];
  __shared__ __align__(16) float Ks[64][68];
  __shared__ __align__(16) float Vs[64][68];
  __shared__ __align__(16) float Ps[64][68];
  const int tid = threadIdx.x;
  const int bh = blockIdx.y;
  const int b = bh >> 3, h = bh & 7;
  const int q0 = blockIdx.x << 6;
  const float* qptr = qkv + (size_t)(b * 2048) * 1536 + h * 64;
#pragma unroll
  for (int i = 0; i < 4; ++i) {
    int idx = tid + (i << 8);
    int r = idx >> 4, c = (idx & 15) << 2;
    *reinterpret_cast<float4*>(&Qs[r][c]) =
        *reinterpret_cast<const float4*>(&qptr[(size_t)(q0 + r) * 1536 + c]);
  }
  const int rt = tid >> 4, ct = tid & 15;
  float m_run[4], l_run[4], O[4][4];
#pragma unroll
  for (int i = 0; i < 4; ++i) {
    m_run[i] = -INFINITY;
    l_run[i] = 0.f;
#pragma unroll
    for (int j = 0; j < 4; ++j) O[i][j] = 0.f;
  }
  for (int kt = 0; kt < 32; ++kt) {
    const int k0 = kt << 6;
    __syncthreads();  // previous iteration finished reading Ks/Vs/Ps
#pragma unroll
    for (int i = 0; i < 4; ++i) {
      int idx = tid + (i << 8);
      int r = idx >> 4, c = (idx & 15) << 2;
      *reinterpret_cast<float4*>(&Ks[r][c]) =
          *reinterpret_cast<const float4*>(&qptr[512 + (size_t)(k0 + r) * 1536 + c]);
      *reinterpret_cast<float4*>(&Vs[r][c]) =
          *reinterpret_cast<const float4*>(&qptr[1024 + (size_t)(k0 + r) * 1536 + c]);
    }
    __syncthreads();
    float S[4][4] = {};
#pragma unroll
    for (int d4 = 0; d4 < 64; d4 += 4) {
      float4 qv[4], kv[4];
#pragma unroll
      for (int i = 0; i < 4; ++i) qv[i] = *reinterpret_cast<const float4*>(&Qs[(rt << 2) + i][d4]);
#pragma unroll
      for (int j = 0; j < 4; ++j) kv[j] = *reinterpret_cast<const float4*>(&Ks[(ct << 2) + j][d4]);
#pragma unroll
      for (int i = 0; i < 4; ++i)
#pragma unroll
        for (int j = 0; j < 4; ++j)
          S[i][j] += qv[i].x * kv[j].x + qv[i].y * kv[j].y + qv[i].z * kv[j].z + qv[i].w * kv[j].w;
    }
#pragma unroll
    for (int i = 0; i < 4; ++i) {
#pragma unroll
      for (int j = 0; j < 4; ++j) S[i][j] *= 0.125f;
      float mt = fmaxf(fmaxf(S[i][0], S[i][1]), fmaxf(S[i][2], S[i][3]));
#pragma unroll
      for (int msk = 1; msk < 16; msk <<= 1) mt = fmaxf(mt, __shfl_xor(mt, msk));
      float mn = fmaxf(m_run[i], mt);
      float corr = expf(m_run[i] - mn);  // -inf -> 0 on first tile
      m_run[i] = mn;
      float ls = 0.f;
#pragma unroll
      for (int j = 0; j < 4; ++j) {
        S[i][j] = expf(S[i][j] - mn);
        ls += S[i][j];
      }
#pragma unroll
      for (int msk = 1; msk < 16; msk <<= 1) ls += __shfl_xor(ls, msk);
      l_run[i] = l_run[i] * corr + ls;
#pragma unroll
      for (int j = 0; j < 4; ++j) O[i][j] *= corr;
      *reinterpret_cast<float4*>(&Ps[(rt << 2) + i][ct << 2]) =
          make_float4(S[i][0], S[i][1], S[i][2], S[i][3]);
    }
    __syncthreads();
#pragma unroll
    for (int kk = 0; kk < 64; kk += 4) {
      float4 pv[4], vv[4];
#pragma unroll
      for (int i = 0; i < 4; ++i) pv[i] = *reinterpret_cast<const float4*>(&Ps[(rt << 2) + i][kk]);
#pragma unroll
      for (int z = 0; z < 4; ++z) vv[z] = *reinterpret_cast<const float4*>(&Vs[kk + z][ct << 2]);
#pragma unroll
      for (int i = 0; i < 4; ++i) {
        O[i][0] += pv[i].x * vv[0].x + pv[i].y * vv[1].x + pv[i].z * vv[2].x + pv[i].w * vv[3].x;
        O[i][1] += pv[i].x * vv[0].y + pv[i].y * vv[1].y + pv[i].z * vv[2].y + pv[i].w * vv[3].y;
        O[i][2] += pv[i].x * vv[0].z + pv[i].y * vv[1].z + pv[i].z * vv[2].z + pv[i].w * vv[3].z;
        O[i][3] += pv[i].x * vv[0].w + pv[i].y * vv[1].w + pv[i].z * vv[2].w + pv[i].w * vv[3].w;
      }
    }
  }
#pragma unroll
  for (int i = 0; i < 4; ++i) {
    int q = q0 + (rt << 2) + i;
    float inv = 1.0f / l_run[i];
    size_t ob = (size_t)(b * 2048 + q) * 512 + h * 64 + (ct << 2);
    *reinterpret_cast<float4*>(&out[ob]) =
        make_float4(O[i][0] * inv, O[i][1] * inv, O[i][2] * inv, O[i][3] * inv);
  }
}

// ---------------------------------------------------------------------------
// GLU: out[m,d] = a * sigmoid(g), a=in[m,d], g=in[m,512+d]; in rows width 1024.
// ---------------------------------------------------------------------------
__global__ __launch_bounds__(256) void glu_kernel(
    const float* __restrict__ in, float* __restrict__ out) {
  int idx = blockIdx.x * 256 + threadIdx.x;  // 0 .. 8192*512-1
  int m = idx >> 9, d = idx & 511;
  float a = in[(size_t)m * 1024 + d];
  float g = in[(size_t)m * 1024 + 512 + d];
  out[idx] = a * (1.0f / (1.0f + expf(-g)));
}

// ---------------------------------------------------------------------------
// Depthwise conv (K=31, pad 15) + batchnorm + snake_beta + act_quant.
// in/out [8192,512] (row = b*2048+t). Block per (b,t), 2 channels/thread.
// ---------------------------------------------------------------------------
__global__ __launch_bounds__(256) void dwconv_bn_snake_quant(
    const float* __restrict__ in, const float* __restrict__ dww,
    const float* __restrict__ dwb, const float* __restrict__ bng,
    const float* __restrict__ bnb, const float* __restrict__ bnm,
    const float* __restrict__ bnv, const float* __restrict__ la,
    const float* __restrict__ lb, float* __restrict__ out) {
  __shared__ float sm[4];
  int t = blockIdx.x & 2047;
  int b = blockIdx.x >> 11;
  const float* base = in + (size_t)b * 2048 * 512;
  float vals[2];
  float am = 0.f;
#pragma unroll
  for (int i = 0; i < 2; ++i) {
    int d = threadIdx.x + (i << 8);
    float acc = dwb[d];
#pragma unroll
    for (int k = 0; k < 31; ++k) {
      int tt = t + k - 15;
      if (tt >= 0 && tt < 2048) acc += base[(size_t)tt * 512 + d] * dww[d * 31 + k];
    }
    acc = (acc - bnm[d]) * (1.0f / sqrtf(bnv[d] + 1e-5f)) * bng[d] + bnb[d];
    float a = expf(la[d]);
    float bbv = expf(lb[d]);
    float sn = sinf(a * acc);
    acc = acc + sn * sn / (bbv + 1e-9f);
    vals[i] = acc;
    am = fmaxf(am, fabsf(acc));
  }
  am = blk_max256(am, sm);
  float s = 127.0f / fmaxf(am, 1e-5f);
  size_t ob = (size_t)blockIdx.x * 512;
#pragma unroll
  for (int i = 0; i < 2; ++i) {
    int d = threadIdx.x + (i << 8);
    out[ob + d] = qdq(vals[i], s);
  }
}

// ---------------------------------------------------------------------------
extern "C" void kernel_launch(void* const* d_in, const int* in_sizes, int n_in,
                              void* d_out, int out_size, void* d_ws, size_t ws_size,
                              hipStream_t stream) {
  const float* x_in = (const float*)d_in[0];
  const float* ff1_norm_w = (const float*)d_in[1];
  const float* ff1_w1 = (const float*)d_in[2];
  const float* ff1_a = (const float*)d_in[3];
  const float* ff1_b = (const float*)d_in[4];
  const float* ff1_w2 = (const float*)d_in[5];
  const float* attn_norm_w = (const float*)d_in[6];
  const float* in_proj_w = (const float*)d_in[7];
  const float* in_proj_b = (const float*)d_in[8];
  const float* out_proj_w = (const float*)d_in[9];
  const float* out_proj_b = (const float*)d_in[10];
  const float* conv_norm_w = (const float*)d_in[11];
  const float* pw1_w = (const float*)d_in[12];
  const float* dw_w = (const float*)d_in[13];
  const float* dw_b = (const float*)d_in[14];
  const float* bn_g = (const float*)d_in[15];
  const float* bn_b = (const float*)d_in[16];
  const float* bn_m = (const float*)d_in[17];
  const float* bn_v = (const float*)d_in[18];
  const float* snake_a = (const float*)d_in[19];
  const float* snake_b = (const float*)d_in[20];
  const float* pw2_w = (const float*)d_in[21];
  const float* ff2_norm_w = (const float*)d_in[22];
  const float* ff2_w1 = (const float*)d_in[23];
  const float* ff2_a = (const float*)d_in[24];
  const float* ff2_b = (const float*)d_in[25];
  const float* ff2_w2 = (const float*)d_in[26];
  const float* final_norm_w = (const float*)d_in[27];
  float* out = (float*)d_out;

  char* ws = (char*)d_ws;
  float* x_cur = (float*)(ws + 0);                    // 8192*512 f32
  float* buf1 = (float*)(ws + 16777216);              // 8192*2048 f32
  float* buf2 = (float*)(ws + 83886080);              // 8192*512 f32
  float* wq = (float*)(ws + 100663296);               // 4,980,736 f32 ternary
  float* scales = (float*)(ws + 120586240);           // 6 f32 (invs)
  float* partials = (float*)(ws + 120586496);         // 6*64 f32

  float* wq_w1 = wq + 0;
  float* wq_w2 = wq + 1048576;
  float* wq_p1 = wq + 2097152;
  float* wq_p2 = wq + 2621440;
  float* wq_f21 = wq + 2883584;
  float* wq_f22 = wq + 3932160;

  // --- weight quantization (deterministic two-stage) ---
  wabs_stage1<<<384, 256, 0, stream>>>(ff1_w1, ff1_w2, pw1_w, pw2_w, ff2_w1, ff2_w2, partials);
  wabs_stage2<<<1, 64, 0, stream>>>(partials, scales);
  wquant<<<512, 256, 0, stream>>>(ff1_w1, scales + 0, wq_w1, 1048576);
  wquant<<<512, 256, 0, stream>>>(ff1_w2, scales + 1, wq_w2, 1048576);
  wquant<<<512, 256, 0, stream>>>(pw1_w, scales + 2, wq_p1, 524288);
  wquant<<<512, 256, 0, stream>>>(pw2_w, scales + 3, wq_p2, 262144);
  wquant<<<512, 256, 0, stream>>>(ff2_w1, scales + 4, wq_f21, 1048576);
  wquant<<<512, 256, 0, stream>>>(ff2_w2, scales + 5, wq_f22, 1048576);

  // --- FFN1: x_cur = x + 0.5*ffn(x) ---
  rmsnorm_quant<<<MM, 256, 0, stream>>>(x_in, ff1_norm_w, buf2, 1);
  gemm_f32<<<dim3(2048 / 64, MM / 64), 256, 0, stream>>>(
      buf2, wq_w1, nullptr, scales + 0, nullptr, 1.0f, buf1, MM, 2048, 512);
  snake_quant<<<MM, 256, 0, stream>>>(buf1, ff1_a, ff1_b);
  gemm_f32<<<dim3(512 / 64, MM / 64), 256, 0, stream>>>(
      buf1, wq_w2, nullptr, scales + 1, x_in, 0.5f, x_cur, MM, 512, 2048);

  // --- MHA: x_cur += mha(x_cur) ---
  rmsnorm_quant<<<MM, 256, 0, stream>>>(x_cur, attn_norm_w, buf2, 0);
  gemm_f32<<<dim3(1536 / 64, MM / 64), 256, 0, stream>>>(
      buf2, in_proj_w, in_proj_b, nullptr, nullptr, 1.0f, buf1, MM, 1536, 512);
  attn_f32<<<dim3(32, 32), 256, 0, stream>>>(buf1, buf2);
  gemm_f32<<<dim3(512 / 64, MM / 64), 256, 0, stream>>>(
      buf2, out_proj_w, out_proj_b, nullptr, x_cur, 1.0f, x_cur, MM, 512, 512);

  // --- conv branch: x_cur += conv(x_cur) ---
  rmsnorm_quant<<<MM, 256, 0, stream>>>(x_cur, conv_norm_w, buf2, 1);
  gemm_f32<<<dim3(1024 / 64, MM / 64), 256, 0, stream>>>(
      buf2, wq_p1, nullptr, scales + 2, nullptr, 1.0f, buf1, MM, 1024, 512);
  glu_kernel<<<16384, 256, 0, stream>>>(buf1, buf2);
  dwconv_bn_snake_quant<<<MM, 256, 0, stream>>>(
      buf2, dw_w, dw_b, bn_g, bn_b, bn_m, bn_v, snake_a, snake_b, buf1);
  gemm_f32<<<dim3(512 / 64, MM / 64), 256, 0, stream>>>(
      buf1, wq_p2, nullptr, scales + 3, x_cur, 1.0f, x_cur, MM, 512, 512);

  // --- FFN2: x_cur += 0.5*ffn(x_cur) ---
  rmsnorm_quant<<<MM, 256, 0, stream>>>(x_cur, ff2_norm_w, buf2, 1);
  gemm_f32<<<dim3(2048 / 64, MM / 64), 256, 0, stream>>>(
      buf2, wq_f21, nullptr, scales + 4, nullptr, 1.0f, buf1, MM, 2048, 512);
  snake_quant<<<MM, 256, 0, stream>>>(buf1, ff2_a, ff2_b);
  gemm_f32<<<dim3(512 / 64, MM / 64), 256, 0, stream>>>(
      buf1, wq_f22, nullptr, scales + 5, x_cur, 0.5f, x_cur, MM, 512, 2048);

  // --- final rmsnorm -> out ---
  rmsnorm_quant<<<MM, 256, 0, stream>>>(x_cur, final_norm_w, out, 0);
}

// Round 2
// 541.729 us; speedup vs baseline: 5.9609x; 5.9609x over previous
//
#include <hip/hip_runtime.h>
#include <math.h>

// ---------------------------------------------------------------------------
// ConformerBlock MFMA implementation.
// B=4, T=2048, D=512, H=8, hd=64, K=31.  M = B*T = 8192.
// Bitlinear GEMMs: int8 MFMA (exact). Attention/projections: bf16 MFMA.
// ---------------------------------------------------------------------------

typedef int   v4i __attribute__((ext_vector_type(4)));
typedef float v4f __attribute__((ext_vector_type(4)));
typedef short v8s __attribute__((ext_vector_type(8)));
typedef unsigned short u16;

#define GLOAD_LDS(g, l) __builtin_amdgcn_global_load_lds( \
    (const __attribute__((address_space(1))) void*)(g),   \
    (__attribute__((address_space(3))) void*)(l), 16, 0, 0)

__device__ __forceinline__ float blk_sum256(float v, float* sm) {
#pragma unroll
  for (int m = 32; m; m >>= 1) v += __shfl_xor(v, m);
  int w = threadIdx.x >> 6;
  __syncthreads();
  if ((threadIdx.x & 63) == 0) sm[w] = v;
  __syncthreads();
  return sm[0] + sm[1] + sm[2] + sm[3];
}

__device__ __forceinline__ float blk_max256(float v, float* sm) {
#pragma unroll
  for (int m = 32; m; m >>= 1) v = fmaxf(v, __shfl_xor(v, m));
  int w = threadIdx.x >> 6;
  __syncthreads();
  if ((threadIdx.x & 63) == 0) sm[w] = v;
  __syncthreads();
  return fmaxf(fmaxf(sm[0], sm[1]), fmaxf(sm[2], sm[3]));
}

__device__ __forceinline__ u16 f2bf(float f) {
  union { float f; unsigned u; } x;
  x.f = f;
  unsigned r = x.u + 0x7fffu + ((x.u >> 16) & 1u);
  return (u16)(r >> 16);
}

// ---------------------------------------------------------------------------
// Weight absmean (deterministic two-stage) + quantizers.
// ---------------------------------------------------------------------------
__global__ __launch_bounds__(256) void wabs_stage1(
    const float* __restrict__ w0, const float* __restrict__ w1,
    const float* __restrict__ w2, const float* __restrict__ w3,
    const float* __restrict__ w4, const float* __restrict__ w5,
    float* __restrict__ part) {
  __shared__ float sm[4];
  const float* ws[6] = {w0, w1, w2, w3, w4, w5};
  const int ns[6] = {1048576, 1048576, 524288, 262144, 1048576, 1048576};
  int widx = blockIdx.x >> 6;
  int chunk = blockIdx.x & 63;
  const float* w = ws[widx];
  int n = ns[widx];
  float s = 0.f;
  for (int i = chunk * 256 + threadIdx.x; i < n; i += 64 * 256) s += fabsf(w[i]);
  s = blk_sum256(s, sm);
  if (threadIdx.x == 0) part[widx * 64 + chunk] = s;
}

__global__ void wabs_stage2(const float* __restrict__ part, float* __restrict__ scales) {
  int t = threadIdx.x;
  if (t < 6) {
    const int ns[6] = {1048576, 1048576, 524288, 262144, 1048576, 1048576};
    float s = 0.f;
    for (int i = 0; i < 64; ++i) s += part[t * 64 + i];
    scales[t] = fmaxf(s / (float)ns[t], 1e-5f);  // wsc = clip(mean|w|,1e-5)
  }
}

__global__ __launch_bounds__(256) void wquant8(
    const float* __restrict__ w, const float* __restrict__ invs_ptr,
    signed char* __restrict__ out, int n) {
  float s = 1.0f / *invs_ptr;
  for (int i = blockIdx.x * 256 + threadIdx.x; i < n; i += gridDim.x * 256) {
    float t = fminf(fmaxf(rintf(w[i] * s), -1.f), 1.f);
    out[i] = (signed char)(int)t;
  }
}

__global__ __launch_bounds__(256) void wcvt_bf16(
    const float* __restrict__ w, u16* __restrict__ o, int n) {
  for (int i = blockIdx.x * 256 + threadIdx.x; i < n; i += gridDim.x * 256)
    o[i] = f2bf(w[i]);
}

// ---------------------------------------------------------------------------
// RMSNorm: mode 0 = f32 out, 1 = int8-quant out + dq, 2 = bf16 out.
// ---------------------------------------------------------------------------
__global__ __launch_bounds__(256) void rmsnorm_multi(
    const float* __restrict__ x, const float* __restrict__ w, int mode,
    float* __restrict__ outf, signed char* __restrict__ out8,
    u16* __restrict__ outb, float* __restrict__ dq) {
  __shared__ float sm[4];
  int row = blockIdx.x, tid = threadIdx.x;
  const float* xr = x + (size_t)row * 512;
  float v0 = xr[tid], v1 = xr[tid + 256];
  float ss = blk_sum256(v0 * v0 + v1 * v1, sm);
  float sc = 1.0f / sqrtf(ss * (1.0f / 512.0f) + 1e-6f);
  float y0 = v0 * sc * w[tid];
  float y1 = v1 * sc * w[tid + 256];
  size_t o = (size_t)row * 512 + tid;
  if (mode == 0) {
    outf[o] = y0; outf[o + 256] = y1;
  } else if (mode == 1) {
    float am = blk_max256(fmaxf(fabsf(y0), fabsf(y1)), sm);
    float amc = fmaxf(am, 1e-5f);
    float s = 127.0f / amc;
    out8[o] = (signed char)(int)rintf(y0 * s);
    out8[o + 256] = (signed char)(int)rintf(y1 * s);
    if (tid == 0) dq[row] = amc * (1.0f / 127.0f);
  } else {
    outb[o] = f2bf(y0); outb[o + 256] = f2bf(y1);
  }
}

// ---------------------------------------------------------------------------
// snake_beta + int8 act-quant over rows of 2048.
// ---------------------------------------------------------------------------
__global__ __launch_bounds__(256) void snake_q8(
    const float* __restrict__ h, const float* __restrict__ la, const float* __restrict__ lb,
    signed char* __restrict__ out, float* __restrict__ dq) {
  __shared__ float sm[4];
  int row = blockIdx.x, tid = threadIdx.x;
  const float* hr = h + (size_t)row * 2048;
  float vals[8];
  float am = 0.f;
#pragma unroll
  for (int i = 0; i < 8; ++i) {
    int c = tid + (i << 8);
    float v = hr[c];
    float sa = __expf(la[c]);
    float sib = 1.0f / (__expf(lb[c]) + 1e-9f);
    float s = __sinf(sa * v);
    v += s * s * sib;
    vals[i] = v;
    am = fmaxf(am, fabsf(v));
  }
  am = blk_max256(am, sm);
  float amc = fmaxf(am, 1e-5f);
  float s = 127.0f / amc;
  signed char* orow = out + (size_t)row * 2048;
#pragma unroll
  for (int i = 0; i < 8; ++i) orow[tid + (i << 8)] = (signed char)(int)rintf(vals[i] * s);
  if (tid == 0) dq[row] = amc * (1.0f / 127.0f);
}

// ---------------------------------------------------------------------------
// Per-token int8 quant of a [M,512] f32 buffer.
// ---------------------------------------------------------------------------
__global__ __launch_bounds__(256) void rowquant512(
    const float* __restrict__ in, signed char* __restrict__ out, float* __restrict__ dq) {
  __shared__ float sm[4];
  int row = blockIdx.x, tid = threadIdx.x;
  const float* xr = in + (size_t)row * 512;
  float v0 = xr[tid], v1 = xr[tid + 256];
  float am = blk_max256(fmaxf(fabsf(v0), fabsf(v1)), sm);
  float amc = fmaxf(am, 1e-5f);
  float s = 127.0f / amc;
  size_t o = (size_t)row * 512 + tid;
  out[o] = (signed char)(int)rintf(v0 * s);
  out[o + 256] = (signed char)(int)rintf(v1 * s);
  if (tid == 0) dq[row] = amc * (1.0f / 127.0f);
}

// ---------------------------------------------------------------------------
// int8 GEMM: out[M,N] = resid + rscale*( (A i8[M,K] @ B i8[N,K]^T) * wsc * dq[m] )
// 128x128 tile, BK=64, 4 waves (2x2), each wave 64x64 via 16x16x64 i8 MFMA.
// ---------------------------------------------------------------------------
__global__ __launch_bounds__(256) void gemm_i8(
    const signed char* __restrict__ A, const signed char* __restrict__ B,
    const float* __restrict__ wsp, const float* __restrict__ adq,
    const float* __restrict__ resid, float rscale,
    float* __restrict__ out, int N, int K) {
  __shared__ signed char As[8192];
  __shared__ signed char Bs[8192];
  const int tid = threadIdx.x;
  const int m0 = blockIdx.y << 7;
  const int n0 = blockIdx.x << 7;
  const int lane = tid & 63;
  const int wv = tid >> 6;
  const int wr = (wv >> 1) << 6, wc = (wv & 1) << 6;
  const int r15 = lane & 15, khi = lane >> 4;
  const int srow = tid >> 2;
  const int sslot = (tid & 3) ^ ((srow >> 1) & 3);
  const signed char* Ag = A + (size_t)(m0 + srow) * K + sslot * 16;
  const signed char* Bg = B + (size_t)(n0 + srow) * K + sslot * 16;
  const size_t half = (size_t)64 * K;

  int aoff[4], boff[4];
#pragma unroll
  for (int i = 0; i < 4; ++i) {
    int r = wr + i * 16 + r15;
    aoff[i] = r * 64 + ((khi ^ ((r >> 1) & 3)) << 4);
    int c = wc + i * 16 + r15;
    boff[i] = c * 64 + ((khi ^ ((c >> 1) & 3)) << 4);
  }
  v4i acc[4][4] = {};
  for (int k0 = 0; k0 < K; k0 += 64) {
    __syncthreads();
    GLOAD_LDS(Ag + k0, As + tid * 16);
    GLOAD_LDS(Ag + half + k0, As + 4096 + tid * 16);
    GLOAD_LDS(Bg + k0, Bs + tid * 16);
    GLOAD_LDS(Bg + half + k0, Bs + 4096 + tid * 16);
    __syncthreads();
    v4i a[4], b[4];
#pragma unroll
    for (int i = 0; i < 4; ++i) a[i] = *(const v4i*)(As + aoff[i]);
#pragma unroll
    for (int j = 0; j < 4; ++j) b[j] = *(const v4i*)(Bs + boff[j]);
#pragma unroll
    for (int i = 0; i < 4; ++i)
#pragma unroll
      for (int j = 0; j < 4; ++j)
        acc[i][j] = __builtin_amdgcn_mfma_i32_16x16x64_i8(a[i], b[j], acc[i][j], 0, 0, 0);
  }
  const float wsc = *wsp;
#pragma unroll
  for (int i = 0; i < 4; ++i) {
    int rb = m0 + wr + i * 16 + (khi << 2);
    float dqv[4];
#pragma unroll
    for (int rr = 0; rr < 4; ++rr) dqv[rr] = adq[rb + rr] * wsc;
#pragma unroll
    for (int j = 0; j < 4; ++j) {
      int col = n0 + wc + j * 16 + r15;
#pragma unroll
      for (int rr = 0; rr < 4; ++rr) {
        size_t idx = (size_t)(rb + rr) * N + col;
        float v = (float)acc[i][j][rr] * dqv[rr];
        out[idx] = resid ? fmaf(rscale, v, resid[idx]) : v;
      }
    }
  }
}

// ---------------------------------------------------------------------------
// bf16 GEMM: acc = A bf16[M,K] @ B bf16[N,K]^T + bias.
// outb != null: write bf16. else: outf = resid + acc.
// ---------------------------------------------------------------------------
__global__ __launch_bounds__(256) void gemm_bf16(
    const u16* __restrict__ A, const u16* __restrict__ B,
    const float* __restrict__ bias, const float* __restrict__ resid,
    float* __restrict__ outf, u16* __restrict__ outb, int N, int K) {
  __shared__ signed char As[8192];
  __shared__ signed char Bs[8192];
  const int tid = threadIdx.x;
  const int m0 = blockIdx.y << 7;
  const int n0 = blockIdx.x << 7;
  const int lane = tid & 63;
  const int wv = tid >> 6;
  const int wr = (wv >> 1) << 6, wc = (wv & 1) << 6;
  const int r15 = lane & 15, khi = lane >> 4;
  const int srow = tid >> 2;
  const int sslot = (tid & 3) ^ ((srow >> 1) & 3);
  const int K2 = K * 2;
  const signed char* Ag = (const signed char*)A + (size_t)(m0 + srow) * K2 + sslot * 16;
  const signed char* Bg = (const signed char*)B + (size_t)(n0 + srow) * K2 + sslot * 16;
  const size_t half = (size_t)64 * K2;

  int aoff[4], boff[4];
#pragma unroll
  for (int i = 0; i < 4; ++i) {
    int r = wr + i * 16 + r15;
    aoff[i] = r * 64 + ((khi ^ ((r >> 1) & 3)) << 4);
    int c = wc + i * 16 + r15;
    boff[i] = c * 64 + ((khi ^ ((c >> 1) & 3)) << 4);
  }
  v4f acc[4][4] = {};
  for (int kb = 0; kb < K2; kb += 64) {
    __syncthreads();
    GLOAD_LDS(Ag + kb, As + tid * 16);
    GLOAD_LDS(Ag + half + kb, As + 4096 + tid * 16);
    GLOAD_LDS(Bg + kb, Bs + tid * 16);
    GLOAD_LDS(Bg + half + kb, Bs + 4096 + tid * 16);
    __syncthreads();
    v8s a[4], b[4];
#pragma unroll
    for (int i = 0; i < 4; ++i) a[i] = *(const v8s*)(As + aoff[i]);
#pragma unroll
    for (int j = 0; j < 4; ++j) b[j] = *(const v8s*)(Bs + boff[j]);
#pragma unroll
    for (int i = 0; i < 4; ++i)
#pragma unroll
      for (int j = 0; j < 4; ++j)
        acc[i][j] = __builtin_amdgcn_mfma_f32_16x16x32_bf16(a[i], b[j], acc[i][j], 0, 0, 0);
  }
#pragma unroll
  for (int i = 0; i < 4; ++i) {
    int rb = m0 + wr + i * 16 + (khi << 2);
#pragma unroll
    for (int j = 0; j < 4; ++j) {
      int col = n0 + wc + j * 16 + r15;
      float bv = bias[col];
#pragma unroll
      for (int rr = 0; rr < 4; ++rr) {
        size_t idx = (size_t)(rb + rr) * N + col;
        float v = acc[i][j][rr] + bv;
        if (outb) outb[idx] = f2bf(v);
        else outf[idx] = resid[idx] + v;
      }
    }
  }
}

// ---------------------------------------------------------------------------
// Flash attention, bf16 MFMA. qkv bf16 [8192,1536] (q|k|v, head h at h*64).
// Block: 64 q-rows, 4 waves (16 q-rows each). K-tiles of 64. out bf16 [8192,512].
// ---------------------------------------------------------------------------
__global__ __launch_bounds__(256) void attn_bf16(
    const u16* __restrict__ qkv, u16* __restrict__ outp) {
  __shared__ u16 Vt[4096];        // V^T [d][k] swizzled
  __shared__ u16 Pl[4096];        // per-wave P [16 q][64 k] swizzled
  const int tid = threadIdx.x;
  const int lane = tid & 63;
  const int wv = tid >> 6;
  const int b = blockIdx.y >> 3, h = blockIdx.y & 7;
  const int q0 = blockIdx.x << 6;
  const int r15 = lane & 15, khi = lane >> 4;
  const u16* base = qkv + (size_t)(b * 2048) * 1536 + h * 64;
  u16* plw = Pl + wv * 1024;

  v8s qf[2];
  {
    const u16* qp = base + (size_t)(q0 + wv * 16 + r15) * 1536;
    qf[0] = *(const v8s*)(qp + khi * 8);
    qf[1] = *(const v8s*)(qp + 32 + khi * 8);
  }
  v4f o[4] = {};
  float mr[4], lr[4];
#pragma unroll
  for (int r = 0; r < 4; ++r) { mr[r] = -INFINITY; lr[r] = 0.f; }

  for (int k0 = 0; k0 < 2048; k0 += 64) {
    __syncthreads();  // prior PV done reading Vt
    {
      int kv = tid >> 2;
      const u16* vp = base + 1024 + (size_t)(k0 + kv) * 1536;
#pragma unroll
      for (int hf = 0; hf < 2; ++hf) {
        int ds = (tid & 3) + hf * 4;
        v8s vvx = *(const v8s*)(vp + ds * 8);
#pragma unroll
        for (int j = 0; j < 8; ++j) {
          int d = ds * 8 + j;
          Vt[(d * 128 + ((kv * 2) ^ ((d & 7) << 4))) >> 1] = ((u16*)&vvx)[j];
        }
      }
    }
    __syncthreads();

    // S = Q K^T
    v4f sv[4] = {};
    const u16* kp = base + 512 + (size_t)k0 * 1536;
#pragma unroll
    for (int j = 0; j < 4; ++j) {
      const u16* kr = kp + (size_t)(j * 16 + r15) * 1536;
      v8s kf0 = *(const v8s*)(kr + khi * 8);
      v8s kf1 = *(const v8s*)(kr + 32 + khi * 8);
      sv[j] = __builtin_amdgcn_mfma_f32_16x16x32_bf16(qf[0], kf0, sv[j], 0, 0, 0);
      sv[j] = __builtin_amdgcn_mfma_f32_16x16x32_bf16(qf[1], kf1, sv[j], 0, 0, 0);
    }
#pragma unroll
    for (int j = 0; j < 4; ++j) sv[j] *= 0.125f;

    // online softmax (rows q = khi*4 + r; cols spread over lanes r15 and j)
#pragma unroll
    for (int r = 0; r < 4; ++r) {
      float mx = fmaxf(fmaxf(sv[0][r], sv[1][r]), fmaxf(sv[2][r], sv[3][r]));
#pragma unroll
      for (int msk = 1; msk < 16; msk <<= 1) mx = fmaxf(mx, __shfl_xor(mx, msk));
      float mn = fmaxf(mr[r], mx);
      float corr = __expf(mr[r] - mn);
      mr[r] = mn;
      float ls = 0.f;
#pragma unroll
      for (int j = 0; j < 4; ++j) {
        float p = __expf(sv[j][r] - mn);
        sv[j][r] = p;
        ls += p;
      }
#pragma unroll
      for (int msk = 1; msk < 16; msk <<= 1) ls += __shfl_xor(ls, msk);
      lr[r] = lr[r] * corr + ls;
#pragma unroll
      for (int dj = 0; dj < 4; ++dj) o[dj][r] *= corr;
      int q = (khi << 2) + r;
      int swz = (q & 7) << 4;
#pragma unroll
      for (int j = 0; j < 4; ++j) {
        int k = j * 16 + r15;
        plw[(q * 128 + ((k * 2) ^ swz)) >> 1] = f2bf(sv[j][r]);
      }
    }

    // PV
    int swq = (r15 & 7) << 4;
    v8s pf0 = *(const v8s*)&plw[(r15 * 128 + ((khi * 16) ^ swq)) >> 1];
    v8s pf1 = *(const v8s*)&plw[(r15 * 128 + ((64 + khi * 16) ^ swq)) >> 1];
#pragma unroll
    for (int dj = 0; dj < 4; ++dj) {
      int d = dj * 16 + r15;
      int sb = d * 128, swd = (d & 7) << 4;
      v8s vf0 = *(const v8s*)&Vt[(sb + ((khi * 16) ^ swd)) >> 1];
      v8s vf1 = *(const v8s*)&Vt[(sb + ((64 + khi * 16) ^ swd)) >> 1];
      o[dj] = __builtin_amdgcn_mfma_f32_16x16x32_bf16(pf0, vf0, o[dj], 0, 0, 0);
      o[dj] = __builtin_amdgcn_mfma_f32_16x16x32_bf16(pf1, vf1, o[dj], 0, 0, 0);
    }
  }
#pragma unroll
  for (int dj = 0; dj < 4; ++dj)
#pragma unroll
    for (int r = 0; r < 4; ++r) {
      int q = q0 + wv * 16 + (khi << 2) + r;
      int d = dj * 16 + r15;
      outp[(size_t)(b * 2048 + q) * 512 + h * 64 + d] = f2bf(o[dj][r] / lr[r]);
    }
}

// ---------------------------------------------------------------------------
// Fused GLU + depthwise conv(K=31) + BN + snake. In: g3out f32 [8192,1024]
// (a|g). Out: f32 [8192,512]. Block: (chgroup 64, t-tile 128, batch).
// ---------------------------------------------------------------------------
__global__ __launch_bounds__(256) void dwconv_fused(
    const float* __restrict__ g3, const float* __restrict__ dww,
    const float* __restrict__ dwb, const float* __restrict__ bng,
    const float* __restrict__ bnb, const float* __restrict__ bnm,
    const float* __restrict__ bnv, const float* __restrict__ la,
    const float* __restrict__ lb, float* __restrict__ outp) {
  __shared__ float IN[160 * 64];
  __shared__ float WT[1984];
  __shared__ float PRM[4][64];
  const int tid = threadIdx.x;
  const int cg = blockIdx.x << 6;
  const int t0 = blockIdx.y << 7;
  const int bb = blockIdx.z;

  if (tid < 64) {
    int c = cg + tid;
    float sc = bng[c] / sqrtf(bnv[c] + 1e-5f);
    PRM[0][tid] = sc;
    PRM[1][tid] = (dwb[c] - bnm[c]) * sc + bnb[c];
    PRM[2][tid] = __expf(la[c]);
    PRM[3][tid] = 1.0f / (__expf(lb[c]) + 1e-9f);
  }
  for (int i = tid; i < 1984; i += 256) WT[i] = dww[cg * 31 + i];

#pragma unroll
  for (int p = 0; p < 10; ++p) {
    int r = p * 16 + (tid >> 4);
    int t = t0 - 16 + r;
    float4 hv = make_float4(0.f, 0.f, 0.f, 0.f);
    if (t >= 0 && t < 2048) {
      const float* rp = g3 + ((size_t)(bb * 2048 + t)) * 1024 + cg + ((tid & 15) << 2);
      float4 a4 = *reinterpret_cast<const float4*>(rp);
      float4 g4 = *reinterpret_cast<const float4*>(rp + 512);
      hv.x = a4.x / (1.f + __expf(-g4.x));
      hv.y = a4.y / (1.f + __expf(-g4.y));
      hv.z = a4.z / (1.f + __expf(-g4.z));
      hv.w = a4.w / (1.f + __expf(-g4.w));
    }
    *reinterpret_cast<float4*>(&IN[r * 64 + ((tid & 15) << 2)]) = hv;
  }
  __syncthreads();

  const int ch = tid & 63;
  const int tg = tid >> 6;
  const float sc = PRM[0][ch], sh = PRM[1][ch], sa = PRM[2][ch], sib = PRM[3][ch];
  float w[31];
#pragma unroll
  for (int k = 0; k < 31; ++k) w[k] = WT[ch * 31 + k];

  for (int pass = 0; pass < 4; ++pass) {
    int tl = pass * 32 + tg * 8;
    float x[38];
#pragma unroll
    for (int i = 0; i < 38; ++i) x[i] = IN[(tl + 1 + i) * 64 + ch];
    float acc[8] = {0.f, 0.f, 0.f, 0.f, 0.f, 0.f, 0.f, 0.f};
#pragma unroll
    for (int k = 0; k < 31; ++k)
#pragma unroll
      for (int j = 0; j < 8; ++j) acc[j] = fmaf(x[k + j], w[k], acc[j]);
#pragma unroll
    for (int j = 0; j < 8; ++j) {
      float v = acc[j] * sc + sh;
      float s = __sinf(sa * v);
      v += s * s * sib;
      outp[((size_t)(bb * 2048 + t0 + tl + j)) * 512 + cg + ch] = v;
    }
  }
}

// ---------------------------------------------------------------------------
extern "C" void kernel_launch(void* const* d_in, const int* in_sizes, int n_in,
                              void* d_out, int out_size, void* d_ws, size_t ws_size,
                              hipStream_t stream) {
  const float* x_in = (const float*)d_in[0];
  const float* ff1_norm_w = (const float*)d_in[1];
  const float* ff1_w1 = (const float*)d_in[2];
  const float* ff1_a = (const float*)d_in[3];
  const float* ff1_b = (const float*)d_in[4];
  const float* ff1_w2 = (const float*)d_in[5];
  const float* attn_norm_w = (const float*)d_in[6];
  const float* in_proj_w = (const float*)d_in[7];
  const float* in_proj_b = (const float*)d_in[8];
  const float* out_proj_w = (const float*)d_in[9];
  const float* out_proj_b = (const float*)d_in[10];
  const float* conv_norm_w = (const float*)d_in[11];
  const float* pw1_w = (const float*)d_in[12];
  const float* dw_w = (const float*)d_in[13];
  const float* dw_b = (const float*)d_in[14];
  const float* bn_g = (const float*)d_in[15];
  const float* bn_b = (const float*)d_in[16];
  const float* bn_m = (const float*)d_in[17];
  const float* bn_v = (const float*)d_in[18];
  const float* snake_a = (const float*)d_in[19];
  const float* snake_b = (const float*)d_in[20];
  const float* pw2_w = (const float*)d_in[21];
  const float* ff2_norm_w = (const float*)d_in[22];
  const float* ff2_w1 = (const float*)d_in[23];
  const float* ff2_a = (const float*)d_in[24];
  const float* ff2_b = (const float*)d_in[25];
  const float* ff2_w2 = (const float*)d_in[26];
  const float* final_norm_w = (const float*)d_in[27];
  float* out = (float*)d_out;

  char* ws = (char*)d_ws;
  float* x_cur = (float*)(ws + 0);                     // 16 MiB
  char* arena = ws + 16777216;                         // 64 MiB
  float* arena_f = (float*)arena;
  u16* qkv = (u16*)arena;
  u16* attno = (u16*)(arena + 33554432);
  float* convout = (float*)(arena + 50331648);
  signed char* a8a = (signed char*)(ws + 83886080);    // 4 MiB
  signed char* a8b = (signed char*)(ws + 88080384);    // 16 MiB
  u16* xnb = (u16*)(ws + 104857600);                   // 8 MiB
  signed char* wq = (signed char*)(ws + 113246208);    // 4.75 MiB
  signed char* wq_w1 = wq;
  signed char* wq_w2 = wq + 1048576;
  signed char* wq_p1 = wq + 2097152;
  signed char* wq_p2 = wq + 2621440;
  signed char* wq_f21 = wq + 2883584;
  signed char* wq_f22 = wq + 3932160;
  u16* wb = (u16*)(ws + 118226944);                    // 2 MiB
  u16* wb_ip = wb;                  // 786432 elems
  u16* wb_op = wb + 786432;         // 262144 elems
  float* scales = (float*)(ws + 120324096);
  float* partials = (float*)(ws + 120324352);
  float* ascale = (float*)(ws + 120325888);            // 8192 f32

  // --- weight prep ---
  wabs_stage1<<<384, 256, 0, stream>>>(ff1_w1, ff1_w2, pw1_w, pw2_w, ff2_w1, ff2_w2, partials);
  wabs_stage2<<<1, 64, 0, stream>>>(partials, scales);
  wquant8<<<512, 256, 0, stream>>>(ff1_w1, scales + 0, wq_w1, 1048576);
  wquant8<<<512, 256, 0, stream>>>(ff1_w2, scales + 1, wq_w2, 1048576);
  wquant8<<<512, 256, 0, stream>>>(pw1_w, scales + 2, wq_p1, 524288);
  wquant8<<<512, 256, 0, stream>>>(pw2_w, scales + 3, wq_p2, 262144);
  wquant8<<<512, 256, 0, stream>>>(ff2_w1, scales + 4, wq_f21, 1048576);
  wquant8<<<512, 256, 0, stream>>>(ff2_w2, scales + 5, wq_f22, 1048576);
  wcvt_bf16<<<768, 256, 0, stream>>>(in_proj_w, wb_ip, 786432);
  wcvt_bf16<<<256, 256, 0, stream>>>(out_proj_w, wb_op, 262144);

  // --- FFN1: x_cur = x + 0.5*ffn(x) ---
  rmsnorm_multi<<<8192, 256, 0, stream>>>(x_in, ff1_norm_w, 1, nullptr, a8a, nullptr, ascale);
  gemm_i8<<<dim3(16, 64), 256, 0, stream>>>(a8a, wq_w1, scales + 0, ascale, nullptr, 1.0f,
                                            arena_f, 2048, 512);
  snake_q8<<<8192, 256, 0, stream>>>(arena_f, ff1_a, ff1_b, a8b, ascale);
  gemm_i8<<<dim3(4, 64), 256, 0, stream>>>(a8b, wq_w2, scales + 1, ascale, x_in, 0.5f,
                                           x_cur, 512, 2048);

  // --- MHA: x_cur += mha(x_cur) ---
  rmsnorm_multi<<<8192, 256, 0, stream>>>(x_cur, attn_norm_w, 2, nullptr, nullptr, xnb, nullptr);
  gemm_bf16<<<dim3(12, 64), 256, 0, stream>>>(xnb, wb_ip, in_proj_b, nullptr, nullptr, qkv,
                                              1536, 512);
  attn_bf16<<<dim3(32, 32), 256, 0, stream>>>(qkv, attno);
  gemm_bf16<<<dim3(4, 64), 256, 0, stream>>>(attno, wb_op, out_proj_b, x_cur, x_cur, nullptr,
                                             512, 512);

  // --- conv branch: x_cur += conv(x_cur) ---
  rmsnorm_multi<<<8192, 256, 0, stream>>>(x_cur, conv_norm_w, 1, nullptr, a8a, nullptr, ascale);
  gemm_i8<<<dim3(8, 64), 256, 0, stream>>>(a8a, wq_p1, scales + 2, ascale, nullptr, 1.0f,
                                           arena_f, 1024, 512);
  dwconv_fused<<<dim3(8, 16, 4), 256, 0, stream>>>(arena_f, dw_w, dw_b, bn_g, bn_b, bn_m, bn_v,
                                                   snake_a, snake_b, convout);
  rowquant512<<<8192, 256, 0, stream>>>(convout, a8a, ascale);
  gemm_i8<<<dim3(4, 64), 256, 0, stream>>>(a8a, wq_p2, scales + 3, ascale, x_cur, 1.0f,
                                           x_cur, 512, 512);

  // --- FFN2: x_cur += 0.5*ffn(x_cur) ---
  rmsnorm_multi<<<8192, 256, 0, stream>>>(x_cur, ff2_norm_w, 1, nullptr, a8a, nullptr, ascale);
  gemm_i8<<<dim3(16, 64), 256, 0, stream>>>(a8a, wq_f21, scales + 4, ascale, nullptr, 1.0f,
                                            arena_f, 2048, 512);
  snake_q8<<<8192, 256, 0, stream>>>(arena_f, ff2_a, ff2_b, a8b, ascale);
  gemm_i8<<<dim3(4, 64), 256, 0, stream>>>(a8b, wq_f22, scales + 5, ascale, x_cur, 0.5f,
                                           x_cur, 512, 2048);

  // --- final rmsnorm -> out ---
  rmsnorm_multi<<<8192, 256, 0, stream>>>(x_cur, final_norm_w, 0, out, nullptr, nullptr, nullptr);
}

// Round 3
// 506.836 us; speedup vs baseline: 6.3712x; 1.0688x over previous
//
#include <hip/hip_runtime.h>
#include <math.h>

// ---------------------------------------------------------------------------
// ConformerBlock MFMA implementation.
// B=4, T=2048, D=512, H=8, hd=64, K=31.  M = B*T = 8192.
// Bitlinear GEMMs: int8 MFMA (exact). Attention/projections: bf16 MFMA.
// Attention: swapped-operand 32x32 MFMA, LDS-free, V pre-transposed.
// ---------------------------------------------------------------------------

typedef int   v4i __attribute__((ext_vector_type(4)));
typedef float v4f __attribute__((ext_vector_type(4)));
typedef float v16f __attribute__((ext_vector_type(16)));
typedef short v8s __attribute__((ext_vector_type(8)));
typedef unsigned short u16;

#define GLOAD_LDS(g, l) __builtin_amdgcn_global_load_lds( \
    (const __attribute__((address_space(1))) void*)(g),   \
    (__attribute__((address_space(3))) void*)(l), 16, 0, 0)

__device__ __forceinline__ float blk_sum256(float v, float* sm) {
#pragma unroll
  for (int m = 32; m; m >>= 1) v += __shfl_xor(v, m);
  int w = threadIdx.x >> 6;
  __syncthreads();
  if ((threadIdx.x & 63) == 0) sm[w] = v;
  __syncthreads();
  return sm[0] + sm[1] + sm[2] + sm[3];
}

__device__ __forceinline__ float blk_max256(float v, float* sm) {
#pragma unroll
  for (int m = 32; m; m >>= 1) v = fmaxf(v, __shfl_xor(v, m));
  int w = threadIdx.x >> 6;
  __syncthreads();
  if ((threadIdx.x & 63) == 0) sm[w] = v;
  __syncthreads();
  return fmaxf(fmaxf(sm[0], sm[1]), fmaxf(sm[2], sm[3]));
}

__device__ __forceinline__ u16 f2bf(float f) {
  union { float f; unsigned u; } x;
  x.f = f;
  unsigned r = x.u + 0x7fffu + ((x.u >> 16) & 1u);
  return (u16)(r >> 16);
}

// ---------------------------------------------------------------------------
// Weight absmean (deterministic two-stage) + quantizers.
// ---------------------------------------------------------------------------
__global__ __launch_bounds__(256) void wabs_stage1(
    const float* __restrict__ w0, const float* __restrict__ w1,
    const float* __restrict__ w2, const float* __restrict__ w3,
    const float* __restrict__ w4, const float* __restrict__ w5,
    float* __restrict__ part) {
  __shared__ float sm[4];
  const float* ws[6] = {w0, w1, w2, w3, w4, w5};
  const int ns[6] = {1048576, 1048576, 524288, 262144, 1048576, 1048576};
  int widx = blockIdx.x >> 6;
  int chunk = blockIdx.x & 63;
  const float* w = ws[widx];
  int n = ns[widx];
  float s = 0.f;
  for (int i = chunk * 256 + threadIdx.x; i < n; i += 64 * 256) s += fabsf(w[i]);
  s = blk_sum256(s, sm);
  if (threadIdx.x == 0) part[widx * 64 + chunk] = s;
}

__global__ void wabs_stage2(const float* __restrict__ part, float* __restrict__ scales) {
  int t = threadIdx.x;
  if (t < 6) {
    const int ns[6] = {1048576, 1048576, 524288, 262144, 1048576, 1048576};
    float s = 0.f;
    for (int i = 0; i < 64; ++i) s += part[t * 64 + i];
    scales[t] = fmaxf(s / (float)ns[t], 1e-5f);  // wsc = clip(mean|w|,1e-5)
  }
}

__global__ __launch_bounds__(256) void wquant8(
    const float* __restrict__ w, const float* __restrict__ invs_ptr,
    signed char* __restrict__ out, int n) {
  float s = 1.0f / *invs_ptr;
  for (int i = blockIdx.x * 256 + threadIdx.x; i < n; i += gridDim.x * 256) {
    float t = fminf(fmaxf(rintf(w[i] * s), -1.f), 1.f);
    out[i] = (signed char)(int)t;
  }
}

__global__ __launch_bounds__(256) void wcvt_bf16(
    const float* __restrict__ w, u16* __restrict__ o, int n) {
  for (int i = blockIdx.x * 256 + threadIdx.x; i < n; i += gridDim.x * 256)
    o[i] = f2bf(w[i]);
}

// ---------------------------------------------------------------------------
// RMSNorm: mode 0 = f32 out, 1 = int8-quant out + dq, 2 = bf16 out.
// ---------------------------------------------------------------------------
__global__ __launch_bounds__(256) void rmsnorm_multi(
    const float* __restrict__ x, const float* __restrict__ w, int mode,
    float* __restrict__ outf, signed char* __restrict__ out8,
    u16* __restrict__ outb, float* __restrict__ dq) {
  __shared__ float sm[4];
  int row = blockIdx.x, tid = threadIdx.x;
  const float* xr = x + (size_t)row * 512;
  float v0 = xr[tid], v1 = xr[tid + 256];
  float ss = blk_sum256(v0 * v0 + v1 * v1, sm);
  float sc = 1.0f / sqrtf(ss * (1.0f / 512.0f) + 1e-6f);
  float y0 = v0 * sc * w[tid];
  float y1 = v1 * sc * w[tid + 256];
  size_t o = (size_t)row * 512 + tid;
  if (mode == 0) {
    outf[o] = y0; outf[o + 256] = y1;
  } else if (mode == 1) {
    float am = blk_max256(fmaxf(fabsf(y0), fabsf(y1)), sm);
    float amc = fmaxf(am, 1e-5f);
    float s = 127.0f / amc;
    out8[o] = (signed char)(int)rintf(y0 * s);
    out8[o + 256] = (signed char)(int)rintf(y1 * s);
    if (tid == 0) dq[row] = amc * (1.0f / 127.0f);
  } else {
    outb[o] = f2bf(y0); outb[o + 256] = f2bf(y1);
  }
}

// ---------------------------------------------------------------------------
// snake_beta + int8 act-quant over rows of 2048.
// ---------------------------------------------------------------------------
__global__ __launch_bounds__(256) void snake_q8(
    const float* __restrict__ h, const float* __restrict__ la, const float* __restrict__ lb,
    signed char* __restrict__ out, float* __restrict__ dq) {
  __shared__ float sm[4];
  int row = blockIdx.x, tid = threadIdx.x;
  const float* hr = h + (size_t)row * 2048;
  float vals[8];
  float am = 0.f;
#pragma unroll
  for (int i = 0; i < 8; ++i) {
    int c = tid + (i << 8);
    float v = hr[c];
    float sa = __expf(la[c]);
    float sib = 1.0f / (__expf(lb[c]) + 1e-9f);
    float s = __sinf(sa * v);
    v += s * s * sib;
    vals[i] = v;
    am = fmaxf(am, fabsf(v));
  }
  am = blk_max256(am, sm);
  float amc = fmaxf(am, 1e-5f);
  float s = 127.0f / amc;
  signed char* orow = out + (size_t)row * 2048;
#pragma unroll
  for (int i = 0; i < 8; ++i) orow[tid + (i << 8)] = (signed char)(int)rintf(vals[i] * s);
  if (tid == 0) dq[row] = amc * (1.0f / 127.0f);
}

// ---------------------------------------------------------------------------
// Per-token int8 quant of a [M,512] f32 buffer.
// ---------------------------------------------------------------------------
__global__ __launch_bounds__(256) void rowquant512(
    const float* __restrict__ in, signed char* __restrict__ out, float* __restrict__ dq) {
  __shared__ float sm[4];
  int row = blockIdx.x, tid = threadIdx.x;
  const float* xr = in + (size_t)row * 512;
  float v0 = xr[tid], v1 = xr[tid + 256];
  float am = blk_max256(fmaxf(fabsf(v0), fabsf(v1)), sm);
  float amc = fmaxf(am, 1e-5f);
  float s = 127.0f / amc;
  size_t o = (size_t)row * 512 + tid;
  out[o] = (signed char)(int)rintf(v0 * s);
  out[o + 256] = (signed char)(int)rintf(v1 * s);
  if (tid == 0) dq[row] = amc * (1.0f / 127.0f);
}

// ---------------------------------------------------------------------------
// int8 GEMM: out[M,N] = resid + rscale*( (A i8[M,K] @ B i8[N,K]^T) * wsc * dq[m] )
// 128x128 tile, BK=64, 4 waves (2x2), each wave 64x64 via 16x16x64 i8 MFMA.
// ---------------------------------------------------------------------------
__global__ __launch_bounds__(256) void gemm_i8(
    const signed char* __restrict__ A, const signed char* __restrict__ B,
    const float* __restrict__ wsp, const float* __restrict__ adq,
    const float* __restrict__ resid, float rscale,
    float* __restrict__ out, int N, int K) {
  __shared__ signed char As[8192];
  __shared__ signed char Bs[8192];
  const int tid = threadIdx.x;
  const int m0 = blockIdx.y << 7;
  const int n0 = blockIdx.x << 7;
  const int lane = tid & 63;
  const int wv = tid >> 6;
  const int wr = (wv >> 1) << 6, wc = (wv & 1) << 6;
  const int r15 = lane & 15, khi = lane >> 4;
  const int srow = tid >> 2;
  const int sslot = (tid & 3) ^ ((srow >> 1) & 3);
  const signed char* Ag = A + (size_t)(m0 + srow) * K + sslot * 16;
  const signed char* Bg = B + (size_t)(n0 + srow) * K + sslot * 16;
  const size_t half = (size_t)64 * K;

  int aoff[4], boff[4];
#pragma unroll
  for (int i = 0; i < 4; ++i) {
    int r = wr + i * 16 + r15;
    aoff[i] = r * 64 + ((khi ^ ((r >> 1) & 3)) << 4);
    int c = wc + i * 16 + r15;
    boff[i] = c * 64 + ((khi ^ ((c >> 1) & 3)) << 4);
  }
  v4i acc[4][4] = {};
  for (int k0 = 0; k0 < K; k0 += 64) {
    __syncthreads();
    GLOAD_LDS(Ag + k0, As + tid * 16);
    GLOAD_LDS(Ag + half + k0, As + 4096 + tid * 16);
    GLOAD_LDS(Bg + k0, Bs + tid * 16);
    GLOAD_LDS(Bg + half + k0, Bs + 4096 + tid * 16);
    __syncthreads();
    v4i a[4], b[4];
#pragma unroll
    for (int i = 0; i < 4; ++i) a[i] = *(const v4i*)(As + aoff[i]);
#pragma unroll
    for (int j = 0; j < 4; ++j) b[j] = *(const v4i*)(Bs + boff[j]);
#pragma unroll
    for (int i = 0; i < 4; ++i)
#pragma unroll
      for (int j = 0; j < 4; ++j)
        acc[i][j] = __builtin_amdgcn_mfma_i32_16x16x64_i8(a[i], b[j], acc[i][j], 0, 0, 0);
  }
  const float wsc = *wsp;
#pragma unroll
  for (int i = 0; i < 4; ++i) {
    int rb = m0 + wr + i * 16 + (khi << 2);
    float dqv[4];
#pragma unroll
    for (int rr = 0; rr < 4; ++rr) dqv[rr] = adq[rb + rr] * wsc;
#pragma unroll
    for (int j = 0; j < 4; ++j) {
      int col = n0 + wc + j * 16 + r15;
#pragma unroll
      for (int rr = 0; rr < 4; ++rr) {
        size_t idx = (size_t)(rb + rr) * N + col;
        float v = (float)acc[i][j][rr] * dqv[rr];
        out[idx] = resid ? fmaf(rscale, v, resid[idx]) : v;
      }
    }
  }
}

// ---------------------------------------------------------------------------
// bf16 GEMM: acc = A bf16[M,K] @ B bf16[N,K]^T + bias.
// outb != null: write bf16. else: outf = resid + acc.
// ---------------------------------------------------------------------------
__global__ __launch_bounds__(256) void gemm_bf16(
    const u16* __restrict__ A, const u16* __restrict__ B,
    const float* __restrict__ bias, const float* __restrict__ resid,
    float* __restrict__ outf, u16* __restrict__ outb, int N, int K) {
  __shared__ signed char As[8192];
  __shared__ signed char Bs[8192];
  const int tid = threadIdx.x;
  const int m0 = blockIdx.y << 7;
  const int n0 = blockIdx.x << 7;
  const int lane = tid & 63;
  const int wv = tid >> 6;
  const int wr = (wv >> 1) << 6, wc = (wv & 1) << 6;
  const int r15 = lane & 15, khi = lane >> 4;
  const int srow = tid >> 2;
  const int sslot = (tid & 3) ^ ((srow >> 1) & 3);
  const int K2 = K * 2;
  const signed char* Ag = (const signed char*)A + (size_t)(m0 + srow) * K2 + sslot * 16;
  const signed char* Bg = (const signed char*)B + (size_t)(n0 + srow) * K2 + sslot * 16;
  const size_t half = (size_t)64 * K2;

  int aoff[4], boff[4];
#pragma unroll
  for (int i = 0; i < 4; ++i) {
    int r = wr + i * 16 + r15;
    aoff[i] = r * 64 + ((khi ^ ((r >> 1) & 3)) << 4);
    int c = wc + i * 16 + r15;
    boff[i] = c * 64 + ((khi ^ ((c >> 1) & 3)) << 4);
  }
  v4f acc[4][4] = {};
  for (int kb = 0; kb < K2; kb += 64) {
    __syncthreads();
    GLOAD_LDS(Ag + kb, As + tid * 16);
    GLOAD_LDS(Ag + half + kb, As + 4096 + tid * 16);
    GLOAD_LDS(Bg + kb, Bs + tid * 16);
    GLOAD_LDS(Bg + half + kb, Bs + 4096 + tid * 16);
    __syncthreads();
    v8s a[4], b[4];
#pragma unroll
    for (int i = 0; i < 4; ++i) a[i] = *(const v8s*)(As + aoff[i]);
#pragma unroll
    for (int j = 0; j < 4; ++j) b[j] = *(const v8s*)(Bs + boff[j]);
#pragma unroll
    for (int i = 0; i < 4; ++i)
#pragma unroll
      for (int j = 0; j < 4; ++j)
        acc[i][j] = __builtin_amdgcn_mfma_f32_16x16x32_bf16(a[i], b[j], acc[i][j], 0, 0, 0);
  }
#pragma unroll
  for (int i = 0; i < 4; ++i) {
    int rb = m0 + wr + i * 16 + (khi << 2);
#pragma unroll
    for (int j = 0; j < 4; ++j) {
      int col = n0 + wc + j * 16 + r15;
      float bv = bias[col];
#pragma unroll
      for (int rr = 0; rr < 4; ++rr) {
        size_t idx = (size_t)(rb + rr) * N + col;
        float v = acc[i][j][rr] + bv;
        if (outb) outb[idx] = f2bf(v);
        else outf[idx] = resid[idx] + v;
      }
    }
  }
}

// ---------------------------------------------------------------------------
// V transpose: vt[bh][d=64][t=2048] <- qkv[b*2048+t][1024 + h*64 + d].
// Block: (t-tile 128, bh). LDS tile padded to 136 u16/row.
// ---------------------------------------------------------------------------
__global__ __launch_bounds__(256) void vtrans(
    const u16* __restrict__ qkv, u16* __restrict__ vt) {
  __shared__ u16 L[64 * 136];
  const int tid = threadIdx.x;
  const int bh = blockIdx.y;
  const int b = bh >> 3, h = bh & 7;
  const int t0 = blockIdx.x << 7;
  {
    const int t = tid & 127;
    const int dbase = (tid >> 7) << 5;
    const u16* src = qkv + (size_t)(b * 2048 + t0 + t) * 1536 + 1024 + h * 64 + dbase;
#pragma unroll
    for (int i = 0; i < 4; ++i) {
      v8s v = *(const v8s*)(src + i * 8);
#pragma unroll
      for (int j = 0; j < 8; ++j) L[(dbase + i * 8 + j) * 136 + t] = ((const u16*)&v)[j];
    }
  }
  __syncthreads();
  {
    const int d = tid >> 2;
    const int tc = (tid & 3) << 5;
    u16* dst = vt + (size_t)bh * 131072 + (size_t)d * 2048 + t0 + tc;
#pragma unroll
    for (int i = 0; i < 4; ++i)
      *(v8s*)(dst + i * 8) = *(const v8s*)&L[d * 136 + tc + i * 8];
  }
}

// ---------------------------------------------------------------------------
// Flash attention, swapped-operand 32x32 bf16 MFMA, LDS-free.
// S^T = mfma(K, Q): lane holds col q = lane&31, rows k = crow(reg,hi).
// O^T = mfma(V^T, P^T): V^T read from vt. grid (16 qgroups, 32 bh), 4 waves.
// ---------------------------------------------------------------------------
__global__ __launch_bounds__(256) void attn32(
    const u16* __restrict__ qkv, const u16* __restrict__ vt, u16* __restrict__ outp) {
  const int tid = threadIdx.x;
  const int lane = tid & 63;
  const int wv = tid >> 6;
  const int l31 = lane & 31;
  const int hi = lane >> 5;
  const int bh = blockIdx.y;
  const int b = bh >> 3, h = bh & 7;
  const int q0 = (blockIdx.x * 4 + wv) << 5;
  const u16* base = qkv + (size_t)(b * 2048) * 1536 + h * 64;
  const u16* vbase = vt + (size_t)bh * 131072;

  // Q fragment (B-operand): col q = l31, k-dim d = ks*16 + hi*8 + j.
  v8s qf[4];
  {
    const u16* qp = base + (size_t)(q0 + l31) * 1536 + hi * 8;
#pragma unroll
    for (int ks = 0; ks < 4; ++ks) qf[ks] = *(const v8s*)(qp + ks * 16);
  }
  v16f o0 = {}, o1 = {};
  float m_run = -INFINITY, l_run = 0.f;

  const u16* kp = base + 512 + (size_t)l31 * 1536 + hi * 8;   // + t*32*1536 + ks*16
  const u16* vp = vbase + (size_t)l31 * 2048 + hi * 8;        // + dt*65536 + t*32 + ks2*16

  v8s kf[4], vf[4], kn[4], vn[4];
#pragma unroll
  for (int ks = 0; ks < 4; ++ks) kf[ks] = *(const v8s*)(kp + ks * 16);
  vf[0] = *(const v8s*)(vp);
  vf[1] = *(const v8s*)(vp + 16);
  vf[2] = *(const v8s*)(vp + 65536);
  vf[3] = *(const v8s*)(vp + 65536 + 16);

  const float C = 0.18033688011112042f;  // 0.125 * log2(e)

  for (int t = 0; t < 64; ++t) {
    // S^T = K · Q  (accumulate over d = 4 x 16)
    v16f sacc = {};
#pragma unroll
    for (int ks = 0; ks < 4; ++ks)
      sacc = __builtin_amdgcn_mfma_f32_32x32x16_bf16(kf[ks], qf[ks], sacc, 0, 0, 0);

    // prefetch next tile's K/V
    int tn = (t < 63) ? (t + 1) : 63;
    {
      const u16* kp2 = kp + (size_t)tn * (32 * 1536);
#pragma unroll
      for (int ks = 0; ks < 4; ++ks) kn[ks] = *(const v8s*)(kp2 + ks * 16);
      const u16* vp2 = vp + tn * 32;
      vn[0] = *(const v8s*)(vp2);
      vn[1] = *(const v8s*)(vp2 + 16);
      vn[2] = *(const v8s*)(vp2 + 65536);
      vn[3] = *(const v8s*)(vp2 + 65536 + 16);
    }

    // online softmax over k (16 regs in-lane + partner half via shfl_xor 32)
    float s[16];
#pragma unroll
    for (int r = 0; r < 16; ++r) s[r] = sacc[r];
    float mx = s[0];
#pragma unroll
    for (int r = 1; r < 16; ++r) mx = fmaxf(mx, s[r]);
    mx = fmaxf(mx, __shfl_xor(mx, 32));
    float mn = fmaxf(m_run, mx);
    float corr = exp2f((m_run - mn) * C);
    m_run = mn;
    float mnC = mn * C;
    float ls = 0.f;
#pragma unroll
    for (int r = 0; r < 16; ++r) {
      float p = exp2f(fmaf(s[r], C, -mnC));
      s[r] = p;
      ls += p;
    }
    ls += __shfl_xor(ls, 32);
    l_run = fmaf(l_run, corr, ls);
#pragma unroll
    for (int r = 0; r < 16; ++r) { o0[r] *= corr; o1[r] *= corr; }

    // pack P to bf16 pairs, assemble B-fragments (P^T, col q = l31)
    unsigned pk[8], px[8];
#pragma unroll
    for (int g = 0; g < 8; ++g) {
      unsigned u;
      asm("v_cvt_pk_bf16_f32 %0, %1, %2" : "=v"(u) : "v"(s[2 * g]), "v"(s[2 * g + 1]));
      pk[g] = u;
      px[g] = (unsigned)__shfl_xor((int)u, 32);
    }
    v4i w0, w1;
    w0[0] = hi ? px[2] : pk[0];
    w0[1] = hi ? px[3] : pk[1];
    w0[2] = hi ? pk[2] : px[0];
    w0[3] = hi ? pk[3] : px[1];
    w1[0] = hi ? px[6] : pk[4];
    w1[1] = hi ? px[7] : pk[5];
    w1[2] = hi ? pk[6] : px[4];
    w1[3] = hi ? pk[7] : px[5];
    v8s pf0 = *(v8s*)&w0;
    v8s pf1 = *(v8s*)&w1;

    // O^T += V^T · P^T
    o0 = __builtin_amdgcn_mfma_f32_32x32x16_bf16(vf[0], pf0, o0, 0, 0, 0);
    o0 = __builtin_amdgcn_mfma_f32_32x32x16_bf16(vf[1], pf1, o0, 0, 0, 0);
    o1 = __builtin_amdgcn_mfma_f32_32x32x16_bf16(vf[2], pf0, o1, 0, 0, 0);
    o1 = __builtin_amdgcn_mfma_f32_32x32x16_bf16(vf[3], pf1, o1, 0, 0, 0);

#pragma unroll
    for (int ks = 0; ks < 4; ++ks) { kf[ks] = kn[ks]; vf[ks] = vn[ks]; }
  }

  float inv = 1.0f / l_run;
  u16* orow = outp + (size_t)(b * 2048 + q0 + l31) * 512 + h * 64;
#pragma unroll
  for (int dt = 0; dt < 2; ++dt) {
#pragma unroll
    for (int g = 0; g < 8; ++g) {
      int d = dt * 32 + ((2 * g) & 3) + 8 * (g >> 1) + 4 * hi;
      float a = (dt ? o1[2 * g] : o0[2 * g]) * inv;
      float bv = (dt ? o1[2 * g + 1] : o0[2 * g + 1]) * inv;
      unsigned u;
      asm("v_cvt_pk_bf16_f32 %0, %1, %2" : "=v"(u) : "v"(a), "v"(bv));
      *(unsigned*)(orow + d) = u;
    }
  }
}

// ---------------------------------------------------------------------------
// Fused GLU + depthwise conv(K=31) + BN + snake. In: g3out f32 [8192,1024]
// (a|g). Out: f32 [8192,512]. Block: (chgroup 64, t-tile 128, batch).
// ---------------------------------------------------------------------------
__global__ __launch_bounds__(256) void dwconv_fused(
    const float* __restrict__ g3, const float* __restrict__ dww,
    const float* __restrict__ dwb, const float* __restrict__ bng,
    const float* __restrict__ bnb, const float* __restrict__ bnm,
    const float* __restrict__ bnv, const float* __restrict__ la,
    const float* __restrict__ lb, float* __restrict__ outp) {
  __shared__ float IN[160 * 64];
  __shared__ float WT[1984];
  __shared__ float PRM[4][64];
  const int tid = threadIdx.x;
  const int cg = blockIdx.x << 6;
  const int t0 = blockIdx.y << 7;
  const int bb = blockIdx.z;

  if (tid < 64) {
    int c = cg + tid;
    float sc = bng[c] / sqrtf(bnv[c] + 1e-5f);
    PRM[0][tid] = sc;
    PRM[1][tid] = (dwb[c] - bnm[c]) * sc + bnb[c];
    PRM[2][tid] = __expf(la[c]);
    PRM[3][tid] = 1.0f / (__expf(lb[c]) + 1e-9f);
  }
  for (int i = tid; i < 1984; i += 256) WT[i] = dww[cg * 31 + i];

#pragma unroll
  for (int p = 0; p < 10; ++p) {
    int r = p * 16 + (tid >> 4);
    int t = t0 - 16 + r;
    float4 hv = make_float4(0.f, 0.f, 0.f, 0.f);
    if (t >= 0 && t < 2048) {
      const float* rp = g3 + ((size_t)(bb * 2048 + t)) * 1024 + cg + ((tid & 15) << 2);
      float4 a4 = *reinterpret_cast<const float4*>(rp);
      float4 g4 = *reinterpret_cast<const float4*>(rp + 512);
      hv.x = a4.x / (1.f + __expf(-g4.x));
      hv.y = a4.y / (1.f + __expf(-g4.y));
      hv.z = a4.z / (1.f + __expf(-g4.z));
      hv.w = a4.w / (1.f + __expf(-g4.w));
    }
    *reinterpret_cast<float4*>(&IN[r * 64 + ((tid & 15) << 2)]) = hv;
  }
  __syncthreads();

  const int ch = tid & 63;
  const int tg = tid >> 6;
  const float sc = PRM[0][ch], sh = PRM[1][ch], sa = PRM[2][ch], sib = PRM[3][ch];
  float w[31];
#pragma unroll
  for (int k = 0; k < 31; ++k) w[k] = WT[ch * 31 + k];

  for (int pass = 0; pass < 4; ++pass) {
    int tl = pass * 32 + tg * 8;
    float x[38];
#pragma unroll
    for (int i = 0; i < 38; ++i) x[i] = IN[(tl + 1 + i) * 64 + ch];
    float acc[8] = {0.f, 0.f, 0.f, 0.f, 0.f, 0.f, 0.f, 0.f};
#pragma unroll
    for (int k = 0; k < 31; ++k)
#pragma unroll
      for (int j = 0; j < 8; ++j) acc[j] = fmaf(x[k + j], w[k], acc[j]);
#pragma unroll
    for (int j = 0; j < 8; ++j) {
      float v = acc[j] * sc + sh;
      float s = __sinf(sa * v);
      v += s * s * sib;
      outp[((size_t)(bb * 2048 + t0 + tl + j)) * 512 + cg + ch] = v;
    }
  }
}

// ---------------------------------------------------------------------------
extern "C" void kernel_launch(void* const* d_in, const int* in_sizes, int n_in,
                              void* d_out, int out_size, void* d_ws, size_t ws_size,
                              hipStream_t stream) {
  const float* x_in = (const float*)d_in[0];
  const float* ff1_norm_w = (const float*)d_in[1];
  const float* ff1_w1 = (const float*)d_in[2];
  const float* ff1_a = (const float*)d_in[3];
  const float* ff1_b = (const float*)d_in[4];
  const float* ff1_w2 = (const float*)d_in[5];
  const float* attn_norm_w = (const float*)d_in[6];
  const float* in_proj_w = (const float*)d_in[7];
  const float* in_proj_b = (const float*)d_in[8];
  const float* out_proj_w = (const float*)d_in[9];
  const float* out_proj_b = (const float*)d_in[10];
  const float* conv_norm_w = (const float*)d_in[11];
  const float* pw1_w = (const float*)d_in[12];
  const float* dw_w = (const float*)d_in[13];
  const float* dw_b = (const float*)d_in[14];
  const float* bn_g = (const float*)d_in[15];
  const float* bn_b = (const float*)d_in[16];
  const float* bn_m = (const float*)d_in[17];
  const float* bn_v = (const float*)d_in[18];
  const float* snake_a = (const float*)d_in[19];
  const float* snake_b = (const float*)d_in[20];
  const float* pw2_w = (const float*)d_in[21];
  const float* ff2_norm_w = (const float*)d_in[22];
  const float* ff2_w1 = (const float*)d_in[23];
  const float* ff2_a = (const float*)d_in[24];
  const float* ff2_b = (const float*)d_in[25];
  const float* ff2_w2 = (const float*)d_in[26];
  const float* final_norm_w = (const float*)d_in[27];
  float* out = (float*)d_out;

  char* ws = (char*)d_ws;
  float* x_cur = (float*)(ws + 0);                     // 16 MiB
  char* arena = ws + 16777216;                         // 64 MiB
  float* arena_f = (float*)arena;                      // FFN h / conv g3 (f32)
  u16* qkv = (u16*)arena;                              // 24 MiB (attn phase)
  u16* attno = (u16*)(arena + 27262976);               // 8 MiB
  u16* vt = (u16*)(arena + 37748736);                  // 8 MiB
  float* convout = (float*)(arena + 50331648);         // 16 MiB (conv phase)
  signed char* a8a = (signed char*)(ws + 83886080);    // 4 MiB
  signed char* a8b = (signed char*)(ws + 88080384);    // 16 MiB
  u16* xnb = (u16*)(ws + 104857600);                   // 8 MiB
  signed char* wq = (signed char*)(ws + 113246208);    // 4.75 MiB
  signed char* wq_w1 = wq;
  signed char* wq_w2 = wq + 1048576;
  signed char* wq_p1 = wq + 2097152;
  signed char* wq_p2 = wq + 2621440;
  signed char* wq_f21 = wq + 2883584;
  signed char* wq_f22 = wq + 3932160;
  u16* wb = (u16*)(ws + 118226944);                    // 2 MiB
  u16* wb_ip = wb;
  u16* wb_op = wb + 786432;
  float* scales = (float*)(ws + 120324096);
  float* partials = (float*)(ws + 120324352);
  float* ascale = (float*)(ws + 120325888);            // 8192 f32

  // --- weight prep ---
  wabs_stage1<<<384, 256, 0, stream>>>(ff1_w1, ff1_w2, pw1_w, pw2_w, ff2_w1, ff2_w2, partials);
  wabs_stage2<<<1, 64, 0, stream>>>(partials, scales);
  wquant8<<<512, 256, 0, stream>>>(ff1_w1, scales + 0, wq_w1, 1048576);
  wquant8<<<512, 256, 0, stream>>>(ff1_w2, scales + 1, wq_w2, 1048576);
  wquant8<<<512, 256, 0, stream>>>(pw1_w, scales + 2, wq_p1, 524288);
  wquant8<<<512, 256, 0, stream>>>(pw2_w, scales + 3, wq_p2, 262144);
  wquant8<<<512, 256, 0, stream>>>(ff2_w1, scales + 4, wq_f21, 1048576);
  wquant8<<<512, 256, 0, stream>>>(ff2_w2, scales + 5, wq_f22, 1048576);
  wcvt_bf16<<<768, 256, 0, stream>>>(in_proj_w, wb_ip, 786432);
  wcvt_bf16<<<256, 256, 0, stream>>>(out_proj_w, wb_op, 262144);

  // --- FFN1: x_cur = x + 0.5*ffn(x) ---
  rmsnorm_multi<<<8192, 256, 0, stream>>>(x_in, ff1_norm_w, 1, nullptr, a8a, nullptr, ascale);
  gemm_i8<<<dim3(16, 64), 256, 0, stream>>>(a8a, wq_w1, scales + 0, ascale, nullptr, 1.0f,
                                            arena_f, 2048, 512);
  snake_q8<<<8192, 256, 0, stream>>>(arena_f, ff1_a, ff1_b, a8b, ascale);
  gemm_i8<<<dim3(4, 64), 256, 0, stream>>>(a8b, wq_w2, scales + 1, ascale, x_in, 0.5f,
                                           x_cur, 512, 2048);

  // --- MHA: x_cur += mha(x_cur) ---
  rmsnorm_multi<<<8192, 256, 0, stream>>>(x_cur, attn_norm_w, 2, nullptr, nullptr, xnb, nullptr);
  gemm_bf16<<<dim3(12, 64), 256, 0, stream>>>(xnb, wb_ip, in_proj_b, nullptr, nullptr, qkv,
                                              1536, 512);
  vtrans<<<dim3(16, 32), 256, 0, stream>>>(qkv, vt);
  attn32<<<dim3(16, 32), 256, 0, stream>>>(qkv, vt, attno);
  gemm_bf16<<<dim3(4, 64), 256, 0, stream>>>(attno, wb_op, out_proj_b, x_cur, x_cur, nullptr,
                                             512, 512);

  // --- conv branch: x_cur += conv(x_cur) ---
  rmsnorm_multi<<<8192, 256, 0, stream>>>(x_cur, conv_norm_w, 1, nullptr, a8a, nullptr, ascale);
  gemm_i8<<<dim3(8, 64), 256, 0, stream>>>(a8a, wq_p1, scales + 2, ascale, nullptr, 1.0f,
                                           arena_f, 1024, 512);
  dwconv_fused<<<dim3(8, 16, 4), 256, 0, stream>>>(arena_f, dw_w, dw_b, bn_g, bn_b, bn_m, bn_v,
                                                   snake_a, snake_b, convout);
  rowquant512<<<8192, 256, 0, stream>>>(convout, a8a, ascale);
  gemm_i8<<<dim3(4, 64), 256, 0, stream>>>(a8a, wq_p2, scales + 3, ascale, x_cur, 1.0f,
                                           x_cur, 512, 512);

  // --- FFN2: x_cur += 0.5*ffn(x_cur) ---
  rmsnorm_multi<<<8192, 256, 0, stream>>>(x_cur, ff2_norm_w, 1, nullptr, a8a, nullptr, ascale);
  gemm_i8<<<dim3(16, 64), 256, 0, stream>>>(a8a, wq_f21, scales + 4, ascale, nullptr, 1.0f,
                                            arena_f, 2048, 512);
  snake_q8<<<8192, 256, 0, stream>>>(arena_f, ff2_a, ff2_b, a8b, ascale);
  gemm_i8<<<dim3(4, 64), 256, 0, stream>>>(a8b, wq_f22, scales + 5, ascale, x_cur, 0.5f,
                                           x_cur, 512, 2048);

  // --- final rmsnorm -> out ---
  rmsnorm_multi<<<8192, 256, 0, stream>>>(x_cur, final_norm_w, 0, out, nullptr, nullptr, nullptr);
}

// Round 5
// 436.516 us; speedup vs baseline: 7.3976x; 1.1611x over previous
//
#include <hip/hip_runtime.h>
#include <math.h>

// ---------------------------------------------------------------------------
// ConformerBlock MFMA implementation.
// B=4, T=2048, D=512, H=8, hd=64, K=31.  M = B*T = 8192.
// Bitlinear GEMMs: int8 MFMA (exact). Attention/projections: bf16 MFMA.
// Attention: swapped-operand 32x32 MFMA, LDS-free, k-split x2 + merge.
// ---------------------------------------------------------------------------

typedef int   v4i __attribute__((ext_vector_type(4)));
typedef float v4f __attribute__((ext_vector_type(4)));
typedef float v16f __attribute__((ext_vector_type(16)));
typedef short v8s __attribute__((ext_vector_type(8)));
typedef unsigned short u16;

#define GLOAD_LDS(g, l) __builtin_amdgcn_global_load_lds( \
    (const __attribute__((address_space(1))) void*)(g),   \
    (__attribute__((address_space(3))) void*)(l), 16, 0, 0)

__device__ __forceinline__ float blk_sum256(float v, float* sm) {
#pragma unroll
  for (int m = 32; m; m >>= 1) v += __shfl_xor(v, m);
  int w = threadIdx.x >> 6;
  __syncthreads();
  if ((threadIdx.x & 63) == 0) sm[w] = v;
  __syncthreads();
  return sm[0] + sm[1] + sm[2] + sm[3];
}

__device__ __forceinline__ float blk_max256(float v, float* sm) {
#pragma unroll
  for (int m = 32; m; m >>= 1) v = fmaxf(v, __shfl_xor(v, m));
  int w = threadIdx.x >> 6;
  __syncthreads();
  if ((threadIdx.x & 63) == 0) sm[w] = v;
  __syncthreads();
  return fmaxf(fmaxf(sm[0], sm[1]), fmaxf(sm[2], sm[3]));
}

__device__ __forceinline__ u16 f2bf(float f) {
  union { float f; unsigned u; } x;
  x.f = f;
  unsigned r = x.u + 0x7fffu + ((x.u >> 16) & 1u);
  return (u16)(r >> 16);
}

__device__ __forceinline__ float bf2f(u16 u) {
  union { unsigned u; float f; } x;
  x.u = ((unsigned)u) << 16;
  return x.f;
}

// ---------------------------------------------------------------------------
// Weight absmean (deterministic two-stage) + quantizers.
// ---------------------------------------------------------------------------
__global__ __launch_bounds__(256) void wabs_stage1(
    const float* __restrict__ w0, const float* __restrict__ w1,
    const float* __restrict__ w2, const float* __restrict__ w3,
    const float* __restrict__ w4, const float* __restrict__ w5,
    float* __restrict__ part) {
  __shared__ float sm[4];
  const float* ws[6] = {w0, w1, w2, w3, w4, w5};
  const int ns[6] = {1048576, 1048576, 524288, 262144, 1048576, 1048576};
  int widx = blockIdx.x >> 6;
  int chunk = blockIdx.x & 63;
  const float* w = ws[widx];
  int n = ns[widx];
  float s = 0.f;
  for (int i = chunk * 256 + threadIdx.x; i < n; i += 64 * 256) s += fabsf(w[i]);
  s = blk_sum256(s, sm);
  if (threadIdx.x == 0) part[widx * 64 + chunk] = s;
}

__global__ void wabs_stage2(const float* __restrict__ part, float* __restrict__ scales) {
  int t = threadIdx.x;
  if (t < 6) {
    const int ns[6] = {1048576, 1048576, 524288, 262144, 1048576, 1048576};
    float s = 0.f;
    for (int i = 0; i < 64; ++i) s += part[t * 64 + i];
    scales[t] = fmaxf(s / (float)ns[t], 1e-5f);  // wsc = clip(mean|w|,1e-5)
  }
}

__global__ __launch_bounds__(256) void wquant_all(
    const float* __restrict__ w0, const float* __restrict__ w1,
    const float* __restrict__ w2, const float* __restrict__ w3,
    const float* __restrict__ w4, const float* __restrict__ w5,
    const float* __restrict__ scales, signed char* __restrict__ out) {
  const float* ws[6] = {w0, w1, w2, w3, w4, w5};
  const int ns[6] = {1048576, 1048576, 524288, 262144, 1048576, 1048576};
  const int offs[6] = {0, 1048576, 2097152, 2621440, 2883584, 3932160};
  int widx = blockIdx.y;
  const float* w = ws[widx];
  int n = ns[widx];
  signed char* o = out + offs[widx];
  float s = 1.0f / scales[widx];
  for (int i = blockIdx.x * 256 + threadIdx.x; i < n; i += 128 * 256)
    o[i] = (signed char)(int)fminf(fmaxf(rintf(w[i] * s), -1.f), 1.f);
}

__global__ __launch_bounds__(256) void wcvt2(
    const float* __restrict__ ip, const float* __restrict__ op, u16* __restrict__ wb) {
  int i = blockIdx.x * 256 + threadIdx.x;  // 1048576 total
  if (i < 786432) wb[i] = f2bf(ip[i]);
  else wb[i] = f2bf(op[i - 786432]);
}

// snake tables: exp(la), 1/(exp(lb)+1e-9) for ff1 and ff2 (2048 each).
__global__ void prep_tables(
    const float* __restrict__ a1, const float* __restrict__ b1,
    const float* __restrict__ a2, const float* __restrict__ b2,
    float* __restrict__ tabs) {
  int i = blockIdx.x * 256 + threadIdx.x;
  if (i < 2048) {
    tabs[i] = __expf(a1[i]);
    tabs[2048 + i] = 1.0f / (__expf(b1[i]) + 1e-9f);
    tabs[4096 + i] = __expf(a2[i]);
    tabs[6144 + i] = 1.0f / (__expf(b2[i]) + 1e-9f);
  }
}

// ---------------------------------------------------------------------------
// RMSNorm: mode 0 = f32 out, 1 = int8-quant out + dq, 2 = bf16 out.
// ---------------------------------------------------------------------------
__global__ __launch_bounds__(256) void rmsnorm_multi(
    const float* __restrict__ x, const float* __restrict__ w, int mode,
    float* __restrict__ outf, signed char* __restrict__ out8,
    u16* __restrict__ outb, float* __restrict__ dq) {
  __shared__ float sm[4];
  int row = blockIdx.x, tid = threadIdx.x;
  const float* xr = x + (size_t)row * 512;
  float v0 = xr[tid], v1 = xr[tid + 256];
  float ss = blk_sum256(v0 * v0 + v1 * v1, sm);
  float sc = 1.0f / sqrtf(ss * (1.0f / 512.0f) + 1e-6f);
  float y0 = v0 * sc * w[tid];
  float y1 = v1 * sc * w[tid + 256];
  size_t o = (size_t)row * 512 + tid;
  if (mode == 0) {
    outf[o] = y0; outf[o + 256] = y1;
  } else if (mode == 1) {
    float am = blk_max256(fmaxf(fabsf(y0), fabsf(y1)), sm);
    float amc = fmaxf(am, 1e-5f);
    float s = 127.0f / amc;
    out8[o] = (signed char)(int)rintf(y0 * s);
    out8[o + 256] = (signed char)(int)rintf(y1 * s);
    if (tid == 0) dq[row] = amc * (1.0f / 127.0f);
  } else {
    outb[o] = f2bf(y0); outb[o + 256] = f2bf(y1);
  }
}

// ---------------------------------------------------------------------------
// snake_beta + int8 act-quant over bf16 rows of 2048, with exp tables.
// ---------------------------------------------------------------------------
__global__ __launch_bounds__(256) void snake_q8(
    const u16* __restrict__ h, const float* __restrict__ ta, const float* __restrict__ tb,
    signed char* __restrict__ out, float* __restrict__ dq) {
  __shared__ float sm[4];
  int row = blockIdx.x, tid = threadIdx.x;
  const u16* hr = h + (size_t)row * 2048;
  int c0 = tid * 8;
  v8s hv = *(const v8s*)(hr + c0);
  float4 ta0 = *(const float4*)(ta + c0);
  float4 ta1 = *(const float4*)(ta + c0 + 4);
  float4 tb0 = *(const float4*)(tb + c0);
  float4 tb1 = *(const float4*)(tb + c0 + 4);
  float sa[8] = {ta0.x, ta0.y, ta0.z, ta0.w, ta1.x, ta1.y, ta1.z, ta1.w};
  float sib[8] = {tb0.x, tb0.y, tb0.z, tb0.w, tb1.x, tb1.y, tb1.z, tb1.w};
  float vals[8];
  float am = 0.f;
#pragma unroll
  for (int j = 0; j < 8; ++j) {
    float v = bf2f((u16)hv[j]);
    float s = __sinf(sa[j] * v);
    v += s * s * sib[j];
    vals[j] = v;
    am = fmaxf(am, fabsf(v));
  }
  am = blk_max256(am, sm);
  float amc = fmaxf(am, 1e-5f);
  float s = 127.0f / amc;
  unsigned long long pkt = 0;
#pragma unroll
  for (int j = 0; j < 8; ++j) {
    int q = (int)rintf(vals[j] * s);
    pkt |= ((unsigned long long)(unsigned char)(signed char)q) << (8 * j);
  }
  *(unsigned long long*)(out + (size_t)row * 2048 + c0) = pkt;
  if (tid == 0) dq[row] = amc * (1.0f / 127.0f);
}

// ---------------------------------------------------------------------------
// Per-token int8 quant of a [M,512] f32 buffer.
// ---------------------------------------------------------------------------
__global__ __launch_bounds__(256) void rowquant512(
    const float* __restrict__ in, signed char* __restrict__ out, float* __restrict__ dq) {
  __shared__ float sm[4];
  int row = blockIdx.x, tid = threadIdx.x;
  const float* xr = in + (size_t)row * 512;
  float v0 = xr[tid], v1 = xr[tid + 256];
  float am = blk_max256(fmaxf(fabsf(v0), fabsf(v1)), sm);
  float amc = fmaxf(am, 1e-5f);
  float s = 127.0f / amc;
  size_t o = (size_t)row * 512 + tid;
  out[o] = (signed char)(int)rintf(v0 * s);
  out[o + 256] = (signed char)(int)rintf(v1 * s);
  if (tid == 0) dq[row] = amc * (1.0f / 127.0f);
}

// ---------------------------------------------------------------------------
// int8 GEMM: acc = (A i8[M,K] @ B i8[N,K]^T) * wsc * dq[m].
// 128xBN tile, BK=64, 4 waves (2x2), JF = BN/32 j-frags per wave.
// OBF: write bf16; else f32 (+resid).
// ---------------------------------------------------------------------------
template <int BN, bool OBF>
__global__ __launch_bounds__(256) void gemm_i8_t(
    const signed char* __restrict__ A, const signed char* __restrict__ B,
    const float* __restrict__ wsp, const float* __restrict__ adq,
    const float* __restrict__ resid, float rscale,
    float* __restrict__ outf, u16* __restrict__ outb, int N, int K) {
  constexpr int JF = BN / 32;  // j-fragments per wave (wave covers 16*JF cols)
  __shared__ signed char As[8192];
  __shared__ signed char Bs[BN * 64];
  const int tid = threadIdx.x;
  const int m0 = blockIdx.y << 7;
  const int n0 = blockIdx.x * BN;
  const int lane = tid & 63;
  const int wv = tid >> 6;
  const int wr = (wv >> 1) << 6, wc = (wv & 1) * (16 * JF);
  const int r15 = lane & 15, khi = lane >> 4;
  const int srow = tid >> 2;
  const int sslot = (tid & 3) ^ ((srow >> 1) & 3);
  const signed char* Ag = A + (size_t)(m0 + srow) * K + sslot * 16;
  const signed char* Bg = B + (size_t)(n0 + srow) * K + sslot * 16;
  const size_t half = (size_t)64 * K;

  int aoff[4], boff[JF];
#pragma unroll
  for (int i = 0; i < 4; ++i) {
    int r = wr + i * 16 + r15;
    aoff[i] = r * 64 + ((khi ^ ((r >> 1) & 3)) << 4);
  }
#pragma unroll
  for (int j = 0; j < JF; ++j) {
    int c = wc + j * 16 + r15;
    boff[j] = c * 64 + ((khi ^ ((c >> 1) & 3)) << 4);
  }
  v4i acc[4][JF] = {};
  for (int k0 = 0; k0 < K; k0 += 64) {
    __syncthreads();
    GLOAD_LDS(Ag + k0, As + tid * 16);
    GLOAD_LDS(Ag + half + k0, As + 4096 + tid * 16);
    GLOAD_LDS(Bg + k0, Bs + tid * 16);
    if constexpr (BN == 128) GLOAD_LDS(Bg + half + k0, Bs + 4096 + tid * 16);
    __syncthreads();
    v4i a[4], b[JF];
#pragma unroll
    for (int i = 0; i < 4; ++i) a[i] = *(const v4i*)(As + aoff[i]);
#pragma unroll
    for (int j = 0; j < JF; ++j) b[j] = *(const v4i*)(Bs + boff[j]);
#pragma unroll
    for (int i = 0; i < 4; ++i)
#pragma unroll
      for (int j = 0; j < JF; ++j)
        acc[i][j] = __builtin_amdgcn_mfma_i32_16x16x64_i8(a[i], b[j], acc[i][j], 0, 0, 0);
  }
  const float wsc = *wsp;
#pragma unroll
  for (int i = 0; i < 4; ++i) {
    int rb = m0 + wr + i * 16 + (khi << 2);
    float dqv[4];
#pragma unroll
    for (int rr = 0; rr < 4; ++rr) dqv[rr] = adq[rb + rr] * wsc;
#pragma unroll
    for (int j = 0; j < JF; ++j) {
      int col = n0 + wc + j * 16 + r15;
#pragma unroll
      for (int rr = 0; rr < 4; ++rr) {
        size_t idx = (size_t)(rb + rr) * N + col;
        float v = (float)acc[i][j][rr] * dqv[rr];
        if constexpr (OBF) outb[idx] = f2bf(v);
        else outf[idx] = resid ? fmaf(rscale, v, resid[idx]) : v;
      }
    }
  }
}

// ---------------------------------------------------------------------------
// bf16 GEMM: acc = A bf16[M,K] @ B bf16[N,K]^T + bias. OBF: bf16 out, else
// f32 resid+acc.
// ---------------------------------------------------------------------------
template <int BN, bool OBF>
__global__ __launch_bounds__(256) void gemm_bf16_t(
    const u16* __restrict__ A, const u16* __restrict__ B,
    const float* __restrict__ bias, const float* __restrict__ resid,
    float* __restrict__ outf, u16* __restrict__ outb, int N, int K) {
  constexpr int JF = BN / 32;
  __shared__ signed char As[8192];
  __shared__ signed char Bs[BN * 64];
  const int tid = threadIdx.x;
  const int m0 = blockIdx.y << 7;
  const int n0 = blockIdx.x * BN;
  const int lane = tid & 63;
  const int wv = tid >> 6;
  const int wr = (wv >> 1) << 6, wc = (wv & 1) * (16 * JF);
  const int r15 = lane & 15, khi = lane >> 4;
  const int srow = tid >> 2;
  const int sslot = (tid & 3) ^ ((srow >> 1) & 3);
  const int K2 = K * 2;
  const signed char* Ag = (const signed char*)A + (size_t)(m0 + srow) * K2 + sslot * 16;
  const signed char* Bg = (const signed char*)B + (size_t)(n0 + srow) * K2 + sslot * 16;
  const size_t half = (size_t)64 * K2;

  int aoff[4], boff[JF];
#pragma unroll
  for (int i = 0; i < 4; ++i) {
    int r = wr + i * 16 + r15;
    aoff[i] = r * 64 + ((khi ^ ((r >> 1) & 3)) << 4);
  }
#pragma unroll
  for (int j = 0; j < JF; ++j) {
    int c = wc + j * 16 + r15;
    boff[j] = c * 64 + ((khi ^ ((c >> 1) & 3)) << 4);
  }
  v4f acc[4][JF] = {};
  for (int kb = 0; kb < K2; kb += 64) {
    __syncthreads();
    GLOAD_LDS(Ag + kb, As + tid * 16);
    GLOAD_LDS(Ag + half + kb, As + 4096 + tid * 16);
    GLOAD_LDS(Bg + kb, Bs + tid * 16);
    if constexpr (BN == 128) GLOAD_LDS(Bg + half + kb, Bs + 4096 + tid * 16);
    __syncthreads();
    v8s a[4], b[JF];
#pragma unroll
    for (int i = 0; i < 4; ++i) a[i] = *(const v8s*)(As + aoff[i]);
#pragma unroll
    for (int j = 0; j < JF; ++j) b[j] = *(const v8s*)(Bs + boff[j]);
#pragma unroll
    for (int i = 0; i < 4; ++i)
#pragma unroll
      for (int j = 0; j < JF; ++j)
        acc[i][j] = __builtin_amdgcn_mfma_f32_16x16x32_bf16(a[i], b[j], acc[i][j], 0, 0, 0);
  }
#pragma unroll
  for (int i = 0; i < 4; ++i) {
    int rb = m0 + wr + i * 16 + (khi << 2);
#pragma unroll
    for (int j = 0; j < JF; ++j) {
      int col = n0 + wc + j * 16 + r15;
      float bv = bias[col];
#pragma unroll
      for (int rr = 0; rr < 4; ++rr) {
        size_t idx = (size_t)(rb + rr) * N + col;
        float v = acc[i][j][rr] + bv;
        if constexpr (OBF) outb[idx] = f2bf(v);
        else outf[idx] = resid[idx] + v;
      }
    }
  }
}

// ---------------------------------------------------------------------------
// V transpose: vt[bh][d=64][t=2048] <- qkv[b*2048+t][1024 + h*64 + d].
// ---------------------------------------------------------------------------
__global__ __launch_bounds__(256) void vtrans(
    const u16* __restrict__ qkv, u16* __restrict__ vt) {
  __shared__ u16 L[64 * 136];
  const int tid = threadIdx.x;
  const int bh = blockIdx.y;
  const int b = bh >> 3, h = bh & 7;
  const int t0 = blockIdx.x << 7;
  {
    const int t = tid & 127;
    const int dbase = (tid >> 7) << 5;
    const u16* src = qkv + (size_t)(b * 2048 + t0 + t) * 1536 + 1024 + h * 64 + dbase;
#pragma unroll
    for (int i = 0; i < 4; ++i) {
      v8s v = *(const v8s*)(src + i * 8);
#pragma unroll
      for (int j = 0; j < 8; ++j) L[(dbase + i * 8 + j) * 136 + t] = ((const u16*)&v)[j];
    }
  }
  __syncthreads();
  {
    const int d = tid >> 2;
    const int tc = (tid & 3) << 5;
    u16* dst = vt + (size_t)bh * 131072 + (size_t)d * 2048 + t0 + tc;
#pragma unroll
    for (int i = 0; i < 4; ++i)
      *(v8s*)(dst + i * 8) = *(const v8s*)&L[d * 136 + tc + i * 8];
  }
}

// ---------------------------------------------------------------------------
// Flash attention, swapped-operand 32x32 bf16 MFMA, LDS-free, k-split x2.
// grid (16 qgroups, 32 bh, 2 k-halves), 4 waves. Writes normalized bf16
// partials + (m,l) per (z, row, head).
// ---------------------------------------------------------------------------
__global__ __launch_bounds__(256) void attn32(
    const u16* __restrict__ qkv, const u16* __restrict__ vt,
    u16* __restrict__ opart, float* __restrict__ ml) {
  const int tid = threadIdx.x;
  const int lane = tid & 63;
  const int wv = tid >> 6;
  const int l31 = lane & 31;
  const int hi = lane >> 5;
  const int bh = blockIdx.y;
  const int z = blockIdx.z;
  const int b = bh >> 3, h = bh & 7;
  const int q0 = (blockIdx.x * 4 + wv) << 5;
  const u16* base = qkv + (size_t)(b * 2048) * 1536 + h * 64;
  const u16* vbase = vt + (size_t)bh * 131072;

  v8s qf[4];
  {
    const u16* qp = base + (size_t)(q0 + l31) * 1536 + hi * 8;
#pragma unroll
    for (int ks = 0; ks < 4; ++ks) qf[ks] = *(const v8s*)(qp + ks * 16);
  }
  v16f o0 = {}, o1 = {};
  float m_run = -INFINITY, l_run = 0.f;

  const u16* kp = base + 512 + (size_t)l31 * 1536 + hi * 8 + (size_t)z * 1572864;
  const u16* vp = vbase + (size_t)l31 * 2048 + hi * 8 + z * 1024;

  v8s kf[4], vf[4], kn[4], vn[4];
#pragma unroll
  for (int ks = 0; ks < 4; ++ks) kf[ks] = *(const v8s*)(kp + ks * 16);
  vf[0] = *(const v8s*)(vp);
  vf[1] = *(const v8s*)(vp + 16);
  vf[2] = *(const v8s*)(vp + 65536);
  vf[3] = *(const v8s*)(vp + 65536 + 16);

  const float C = 0.18033688011112042f;  // 0.125 * log2(e)

  for (int t = 0; t < 32; ++t) {
    // S^T = K · Q  (accumulate over d = 4 x 16)
    v16f sacc = {};
#pragma unroll
    for (int ks = 0; ks < 4; ++ks)
      sacc = __builtin_amdgcn_mfma_f32_32x32x16_bf16(kf[ks], qf[ks], sacc, 0, 0, 0);

    // prefetch next tile's K/V
    int tn = (t < 31) ? (t + 1) : 31;
    {
      const u16* kp2 = kp + (size_t)tn * (32 * 1536);
#pragma unroll
      for (int ks = 0; ks < 4; ++ks) kn[ks] = *(const v8s*)(kp2 + ks * 16);
      const u16* vp2 = vp + tn * 32;
      vn[0] = *(const v8s*)(vp2);
      vn[1] = *(const v8s*)(vp2 + 16);
      vn[2] = *(const v8s*)(vp2 + 65536);
      vn[3] = *(const v8s*)(vp2 + 65536 + 16);
    }

    float s[16];
#pragma unroll
    for (int r = 0; r < 16; ++r) s[r] = sacc[r];
    float mx = s[0];
#pragma unroll
    for (int r = 1; r < 16; ++r) mx = fmaxf(mx, s[r]);
    mx = fmaxf(mx, __shfl_xor(mx, 32));
    // defer-max: rescale only when the bound would exceed 2^8
    if (__any((mx - m_run) * C > 8.0f)) {
      float mn = fmaxf(m_run, mx);
      float corr = exp2f((m_run - mn) * C);
      m_run = mn;
      l_run *= corr;
#pragma unroll
      for (int r = 0; r < 16; ++r) { o0[r] *= corr; o1[r] *= corr; }
    }
    float mnC = m_run * C;
    float ls = 0.f;
#pragma unroll
    for (int r = 0; r < 16; ++r) {
      float p = exp2f(fmaf(s[r], C, -mnC));
      s[r] = p;
      ls += p;
    }
    ls += __shfl_xor(ls, 32);
    l_run += ls;

    // pack P to bf16 pairs, assemble B-fragments (P^T, col q = l31)
    unsigned pk[8], px[8];
#pragma unroll
    for (int g = 0; g < 8; ++g) {
      unsigned u;
      asm("v_cvt_pk_bf16_f32 %0, %1, %2" : "=v"(u) : "v"(s[2 * g]), "v"(s[2 * g + 1]));
      pk[g] = u;
      px[g] = (unsigned)__shfl_xor((int)u, 32);
    }
    v4i w0, w1;
    w0[0] = hi ? px[2] : pk[0];
    w0[1] = hi ? px[3] : pk[1];
    w0[2] = hi ? pk[2] : px[0];
    w0[3] = hi ? pk[3] : px[1];
    w1[0] = hi ? px[6] : pk[4];
    w1[1] = hi ? px[7] : pk[5];
    w1[2] = hi ? pk[6] : px[4];
    w1[3] = hi ? pk[7] : px[5];
    v8s pf0 = *(v8s*)&w0;
    v8s pf1 = *(v8s*)&w1;

    // O^T += V^T · P^T
    o0 = __builtin_amdgcn_mfma_f32_32x32x16_bf16(vf[0], pf0, o0, 0, 0, 0);
    o0 = __builtin_amdgcn_mfma_f32_32x32x16_bf16(vf[1], pf1, o0, 0, 0, 0);
    o1 = __builtin_amdgcn_mfma_f32_32x32x16_bf16(vf[2], pf0, o1, 0, 0, 0);
    o1 = __builtin_amdgcn_mfma_f32_32x32x16_bf16(vf[3], pf1, o1, 0, 0, 0);

#pragma unroll
    for (int ks = 0; ks < 4; ++ks) { kf[ks] = kn[ks]; vf[ks] = vn[ks]; }
  }

  float inv = 1.0f / l_run;
  u16* orow = opart + (size_t)z * 4194304 + (size_t)(b * 2048 + q0 + l31) * 512 + h * 64;
#pragma unroll
  for (int dt = 0; dt < 2; ++dt) {
#pragma unroll
    for (int g = 0; g < 8; ++g) {
      int d = dt * 32 + ((2 * g) & 3) + 8 * (g >> 1) + 4 * hi;
      float a = (dt ? o1[2 * g] : o0[2 * g]) * inv;
      float bv = (dt ? o1[2 * g + 1] : o0[2 * g + 1]) * inv;
      unsigned u;
      asm("v_cvt_pk_bf16_f32 %0, %1, %2" : "=v"(u) : "v"(a), "v"(bv));
      *(unsigned*)(orow + d) = u;
    }
  }
  if (hi == 0) {
    size_t mi = ((size_t)(z * 8192 + b * 2048 + q0 + l31) * 8 + h) * 2;
    ml[mi] = m_run;
    ml[mi + 1] = l_run;
  }
}

// ---------------------------------------------------------------------------
// Merge the two k-halves: attno = w0*O0 + w1*O1 (flash combine).
// ---------------------------------------------------------------------------
__global__ __launch_bounds__(256) void attn_merge(
    const u16* __restrict__ opart, const float* __restrict__ ml,
    u16* __restrict__ attno) {
  __shared__ float w0s[8], w1s[8];
  const int r = blockIdx.x, tid = threadIdx.x;
  if (tid < 8) {
    const float C = 0.18033688011112042f;
    size_t i0 = ((size_t)r * 8 + tid) * 2;
    size_t i1 = ((size_t)(8192 + r) * 8 + tid) * 2;
    float m0 = ml[i0], l0 = ml[i0 + 1];
    float m1 = ml[i1], l1 = ml[i1 + 1];
    float M = fmaxf(m0, m1);
    float a0 = exp2f((m0 - M) * C) * l0;
    float a1 = exp2f((m1 - M) * C) * l1;
    float inv = 1.0f / (a0 + a1);
    w0s[tid] = a0 * inv;
    w1s[tid] = a1 * inv;
  }
  __syncthreads();
  int c = tid * 2;
  unsigned p0 = *(const unsigned*)(opart + (size_t)r * 512 + c);
  unsigned p1 = *(const unsigned*)(opart + 4194304 + (size_t)r * 512 + c);
  int hh = c >> 6;
  float w0 = w0s[hh], w1 = w1s[hh];
  float x0 = bf2f((u16)p0) * w0 + bf2f((u16)p1) * w1;
  float x1 = bf2f((u16)(p0 >> 16)) * w0 + bf2f((u16)(p1 >> 16)) * w1;
  unsigned u;
  asm("v_cvt_pk_bf16_f32 %0, %1, %2" : "=v"(u) : "v"(x0), "v"(x1));
  *(unsigned*)(attno + (size_t)r * 512 + c) = u;
}

// ---------------------------------------------------------------------------
// Fused GLU + depthwise conv(K=31) + BN + snake. In: g3 bf16 [8192,1024]
// (a|g). Out: f32 [8192,512]. Block: (chgroup 64, t-tile 128, batch).
// ---------------------------------------------------------------------------
__global__ __launch_bounds__(256) void dwconv_fused(
    const u16* __restrict__ g3, const float* __restrict__ dww,
    const float* __restrict__ dwb, const float* __restrict__ bng,
    const float* __restrict__ bnb, const float* __restrict__ bnm,
    const float* __restrict__ bnv, const float* __restrict__ la,
    const float* __restrict__ lb, float* __restrict__ outp) {
  __shared__ float IN[160 * 64];
  __shared__ float WT[1984];
  __shared__ float PRM[4][64];
  const int tid = threadIdx.x;
  const int cg = blockIdx.x << 6;
  const int t0 = blockIdx.y << 7;
  const int bb = blockIdx.z;

  if (tid < 64) {
    int c = cg + tid;
    float sc = bng[c] / sqrtf(bnv[c] + 1e-5f);
    PRM[0][tid] = sc;
    PRM[1][tid] = (dwb[c] - bnm[c]) * sc + bnb[c];
    PRM[2][tid] = __expf(la[c]);
    PRM[3][tid] = 1.0f / (__expf(lb[c]) + 1e-9f);
  }
  for (int i = tid; i < 1984; i += 256) WT[i] = dww[cg * 31 + i];

#pragma unroll
  for (int p = 0; p < 5; ++p) {
    int r = p * 32 + (tid >> 3);
    int t = t0 - 16 + r;
    int c8 = (tid & 7) << 3;
    float4 lo = make_float4(0.f, 0.f, 0.f, 0.f);
    float4 hv = make_float4(0.f, 0.f, 0.f, 0.f);
    if (t >= 0 && t < 2048) {
      const u16* rp = g3 + ((size_t)(bb * 2048 + t)) * 1024 + cg + c8;
      v8s a8 = *(const v8s*)rp;
      v8s g8 = *(const v8s*)(rp + 512);
      float va[8];
#pragma unroll
      for (int j = 0; j < 8; ++j) {
        float fa = bf2f((u16)a8[j]);
        float fg = bf2f((u16)g8[j]);
        va[j] = fa / (1.f + __expf(-fg));
      }
      lo = make_float4(va[0], va[1], va[2], va[3]);
      hv = make_float4(va[4], va[5], va[6], va[7]);
    }
    *(float4*)&IN[r * 64 + c8] = lo;
    *(float4*)&IN[r * 64 + c8 + 4] = hv;
  }
  __syncthreads();

  const int ch = tid & 63;
  const int tg = tid >> 6;
  const float sc = PRM[0][ch], sh = PRM[1][ch], sa = PRM[2][ch], sib = PRM[3][ch];
  float w[31];
#pragma unroll
  for (int k = 0; k < 31; ++k) w[k] = WT[ch * 31 + k];

  for (int pass = 0; pass < 4; ++pass) {
    int tl = pass * 32 + tg * 8;
    float x[38];
#pragma unroll
    for (int i = 0; i < 38; ++i) x[i] = IN[(tl + 1 + i) * 64 + ch];
    float acc[8] = {0.f, 0.f, 0.f, 0.f, 0.f, 0.f, 0.f, 0.f};
#pragma unroll
    for (int k = 0; k < 31; ++k)
#pragma unroll
      for (int j = 0; j < 8; ++j) acc[j] = fmaf(x[k + j], w[k], acc[j]);
#pragma unroll
    for (int j = 0; j < 8; ++j) {
      float v = acc[j] * sc + sh;
      float s = __sinf(sa * v);
      v += s * s * sib;
      outp[((size_t)(bb * 2048 + t0 + tl + j)) * 512 + cg + ch] = v;
    }
  }
}

// ---------------------------------------------------------------------------
extern "C" void kernel_launch(void* const* d_in, const int* in_sizes, int n_in,
                              void* d_out, int out_size, void* d_ws, size_t ws_size,
                              hipStream_t stream) {
  const float* x_in = (const float*)d_in[0];
  const float* ff1_norm_w = (const float*)d_in[1];
  const float* ff1_w1 = (const float*)d_in[2];
  const float* ff1_a = (const float*)d_in[3];
  const float* ff1_b = (const float*)d_in[4];
  const float* ff1_w2 = (const float*)d_in[5];
  const float* attn_norm_w = (const float*)d_in[6];
  const float* in_proj_w = (const float*)d_in[7];
  const float* in_proj_b = (const float*)d_in[8];
  const float* out_proj_w = (const float*)d_in[9];
  const float* out_proj_b = (const float*)d_in[10];
  const float* conv_norm_w = (const float*)d_in[11];
  const float* pw1_w = (const float*)d_in[12];
  const float* dw_w = (const float*)d_in[13];
  const float* dw_b = (const float*)d_in[14];
  const float* bn_g = (const float*)d_in[15];
  const float* bn_b = (const float*)d_in[16];
  const float* bn_m = (const float*)d_in[17];
  const float* bn_v = (const float*)d_in[18];
  const float* snake_a = (const float*)d_in[19];
  const float* snake_b = (const float*)d_in[20];
  const float* pw2_w = (const float*)d_in[21];
  const float* ff2_norm_w = (const float*)d_in[22];
  const float* ff2_w1 = (const float*)d_in[23];
  const float* ff2_a = (const float*)d_in[24];
  const float* ff2_b = (const float*)d_in[25];
  const float* ff2_w2 = (const float*)d_in[26];
  const float* final_norm_w = (const float*)d_in[27];
  float* out = (float*)d_out;

  char* ws = (char*)d_ws;
  float* x_cur = (float*)(ws + 0);                     // 16 MiB
  char* arena = ws + 16777216;                         // 64 MiB
  // attn phase:
  u16* qkv = (u16*)arena;                              // 24 MiB
  u16* attno = (u16*)(arena + 25165824);               // 8 MiB
  u16* vt = (u16*)(arena + 33554432);                  // 8 MiB
  u16* opart = (u16*)(arena + 41943040);               // 16 MiB
  float* ml = (float*)(arena + 58720256);              // 2 MiB
  // FFN phase:
  u16* h_b = (u16*)arena;                              // 32 MiB
  // conv phase:
  u16* g3b = (u16*)arena;                              // 16 MiB
  float* convout = (float*)(arena + 33554432);         // 16 MiB
  signed char* a8a = (signed char*)(ws + 83886080);    // 4 MiB
  signed char* a8b = (signed char*)(ws + 88080384);    // 16 MiB
  u16* xnb = (u16*)(ws + 104857600);                   // 8 MiB
  signed char* wq = (signed char*)(ws + 113246208);    // 4.75 MiB
  signed char* wq_w1 = wq;
  signed char* wq_w2 = wq + 1048576;
  signed char* wq_p1 = wq + 2097152;
  signed char* wq_p2 = wq + 2621440;
  signed char* wq_f21 = wq + 2883584;
  signed char* wq_f22 = wq + 3932160;
  u16* wb = (u16*)(ws + 118226944);                    // 2 MiB
  u16* wb_ip = wb;
  u16* wb_op = wb + 786432;
  float* scales = (float*)(ws + 120324096);
  float* partials = (float*)(ws + 120324352);
  float* ascale = (float*)(ws + 120325888);            // 32 KiB
  float* tabs = (float*)(ws + 120358912);              // 32 KiB

  // --- weight prep ---
  wabs_stage1<<<384, 256, 0, stream>>>(ff1_w1, ff1_w2, pw1_w, pw2_w, ff2_w1, ff2_w2, partials);
  wabs_stage2<<<1, 64, 0, stream>>>(partials, scales);
  wquant_all<<<dim3(128, 6), 256, 0, stream>>>(ff1_w1, ff1_w2, pw1_w, pw2_w, ff2_w1, ff2_w2,
                                               scales, wq);
  wcvt2<<<4096, 256, 0, stream>>>(in_proj_w, out_proj_w, wb);
  prep_tables<<<8, 256, 0, stream>>>(ff1_a, ff1_b, ff2_a, ff2_b, tabs);

  // --- FFN1: x_cur = x + 0.5*ffn(x) ---
  rmsnorm_multi<<<8192, 256, 0, stream>>>(x_in, ff1_norm_w, 1, nullptr, a8a, nullptr, ascale);
  gemm_i8_t<128, true><<<dim3(16, 64), 256, 0, stream>>>(
      a8a, wq_w1, scales + 0, ascale, nullptr, 1.0f, nullptr, h_b, 2048, 512);
  snake_q8<<<8192, 256, 0, stream>>>(h_b, tabs, tabs + 2048, a8b, ascale);
  gemm_i8_t<64, false><<<dim3(8, 64), 256, 0, stream>>>(
      a8b, wq_w2, scales + 1, ascale, x_in, 0.5f, x_cur, nullptr, 512, 2048);

  // --- MHA: x_cur += mha(x_cur) ---
  rmsnorm_multi<<<8192, 256, 0, stream>>>(x_cur, attn_norm_w, 2, nullptr, nullptr, xnb, nullptr);
  gemm_bf16_t<128, true><<<dim3(12, 64), 256, 0, stream>>>(
      xnb, wb_ip, in_proj_b, nullptr, nullptr, qkv, 1536, 512);
  vtrans<<<dim3(16, 32), 256, 0, stream>>>(qkv, vt);
  attn32<<<dim3(16, 32, 2), 256, 0, stream>>>(qkv, vt, opart, ml);
  attn_merge<<<8192, 256, 0, stream>>>(opart, ml, attno);
  gemm_bf16_t<64, false><<<dim3(8, 64), 256, 0, stream>>>(
      attno, wb_op, out_proj_b, x_cur, x_cur, nullptr, 512, 512);

  // --- conv branch: x_cur += conv(x_cur) ---
  rmsnorm_multi<<<8192, 256, 0, stream>>>(x_cur, conv_norm_w, 1, nullptr, a8a, nullptr, ascale);
  gemm_i8_t<128, true><<<dim3(8, 64), 256, 0, stream>>>(
      a8a, wq_p1, scales + 2, ascale, nullptr, 1.0f, nullptr, g3b, 1024, 512);
  dwconv_fused<<<dim3(8, 16, 4), 256, 0, stream>>>(g3b, dw_w, dw_b, bn_g, bn_b, bn_m, bn_v,
                                                   snake_a, snake_b, convout);
  rowquant512<<<8192, 256, 0, stream>>>(convout, a8a, ascale);
  gemm_i8_t<64, false><<<dim3(8, 64), 256, 0, stream>>>(
      a8a, wq_p2, scales + 3, ascale, x_cur, 1.0f, x_cur, nullptr, 512, 512);

  // --- FFN2: x_cur += 0.5*ffn(x_cur) ---
  rmsnorm_multi<<<8192, 256, 0, stream>>>(x_cur, ff2_norm_w, 1, nullptr, a8a, nullptr, ascale);
  gemm_i8_t<128, true><<<dim3(16, 64), 256, 0, stream>>>(
      a8a, wq_f21, scales + 4, ascale, nullptr, 1.0f, nullptr, h_b, 2048, 512);
  snake_q8<<<8192, 256, 0, stream>>>(h_b, tabs + 4096, tabs + 6144, a8b, ascale);
  gemm_i8_t<64, false><<<dim3(8, 64), 256, 0, stream>>>(
      a8b, wq_f22, scales + 5, ascale, x_cur, 0.5f, x_cur, nullptr, 512, 2048);

  // --- final rmsnorm -> out ---
  rmsnorm_multi<<<8192, 256, 0, stream>>>(x_cur, final_norm_w, 0, out, nullptr, nullptr, nullptr);
}

// Round 6
// 389.486 us; speedup vs baseline: 8.2909x; 1.1207x over previous
//
#include <hip/hip_runtime.h>
#include <math.h>

// ---------------------------------------------------------------------------
// ConformerBlock MFMA implementation.
// B=4, T=2048, D=512, H=8, hd=64, K=31.  M = B*T = 8192.
// Bitlinear GEMMs: int8 MFMA (exact). Attention/projections: bf16 MFMA.
// Attention: swapped-operand 32x32 MFMA, fragment-packed K/V (coalesced),
// k-split x2 + flash merge.
// ---------------------------------------------------------------------------

typedef int   v4i __attribute__((ext_vector_type(4)));
typedef float v4f __attribute__((ext_vector_type(4)));
typedef float v16f __attribute__((ext_vector_type(16)));
typedef short v8s __attribute__((ext_vector_type(8)));
typedef unsigned short u16;

#define GLOAD_LDS(g, l) __builtin_amdgcn_global_load_lds( \
    (const __attribute__((address_space(1))) void*)(g),   \
    (__attribute__((address_space(3))) void*)(l), 16, 0, 0)

__device__ __forceinline__ float blk_sum256(float v, float* sm) {
#pragma unroll
  for (int m = 32; m; m >>= 1) v += __shfl_xor(v, m);
  int w = threadIdx.x >> 6;
  __syncthreads();
  if ((threadIdx.x & 63) == 0) sm[w] = v;
  __syncthreads();
  return sm[0] + sm[1] + sm[2] + sm[3];
}

__device__ __forceinline__ float blk_max256(float v, float* sm) {
#pragma unroll
  for (int m = 32; m; m >>= 1) v = fmaxf(v, __shfl_xor(v, m));
  int w = threadIdx.x >> 6;
  __syncthreads();
  if ((threadIdx.x & 63) == 0) sm[w] = v;
  __syncthreads();
  return fmaxf(fmaxf(sm[0], sm[1]), fmaxf(sm[2], sm[3]));
}

__device__ __forceinline__ u16 f2bf(float f) {
  union { float f; unsigned u; } x;
  x.f = f;
  unsigned r = x.u + 0x7fffu + ((x.u >> 16) & 1u);
  return (u16)(r >> 16);
}

__device__ __forceinline__ float bf2f(u16 u) {
  union { unsigned u; float f; } x;
  x.u = ((unsigned)u) << 16;
  return x.f;
}

// ---------------------------------------------------------------------------
// Weight absmean (deterministic two-stage) + quantizers.
// ---------------------------------------------------------------------------
__global__ __launch_bounds__(256) void wabs_stage1(
    const float* __restrict__ w0, const float* __restrict__ w1,
    const float* __restrict__ w2, const float* __restrict__ w3,
    const float* __restrict__ w4, const float* __restrict__ w5,
    float* __restrict__ part) {
  __shared__ float sm[4];
  const float* ws[6] = {w0, w1, w2, w3, w4, w5};
  const int ns[6] = {1048576, 1048576, 524288, 262144, 1048576, 1048576};
  int widx = blockIdx.x >> 6;
  int chunk = blockIdx.x & 63;
  const float* w = ws[widx];
  int n = ns[widx];
  float s = 0.f;
  for (int i = chunk * 256 + threadIdx.x; i < n; i += 64 * 256) s += fabsf(w[i]);
  s = blk_sum256(s, sm);
  if (threadIdx.x == 0) part[widx * 64 + chunk] = s;
}

__global__ void wabs_stage2(const float* __restrict__ part, float* __restrict__ scales) {
  int t = threadIdx.x;
  if (t < 6) {
    const int ns[6] = {1048576, 1048576, 524288, 262144, 1048576, 1048576};
    float s = 0.f;
    for (int i = 0; i < 64; ++i) s += part[t * 64 + i];
    scales[t] = fmaxf(s / (float)ns[t], 1e-5f);  // wsc = clip(mean|w|,1e-5)
  }
}

__global__ __launch_bounds__(256) void wquant_all(
    const float* __restrict__ w0, const float* __restrict__ w1,
    const float* __restrict__ w2, const float* __restrict__ w3,
    const float* __restrict__ w4, const float* __restrict__ w5,
    const float* __restrict__ scales, signed char* __restrict__ out) {
  const float* ws[6] = {w0, w1, w2, w3, w4, w5};
  const int ns[6] = {1048576, 1048576, 524288, 262144, 1048576, 1048576};
  const int offs[6] = {0, 1048576, 2097152, 2621440, 2883584, 3932160};
  int widx = blockIdx.y;
  const float* w = ws[widx];
  int n = ns[widx];
  signed char* o = out + offs[widx];
  float s = 1.0f / scales[widx];
  for (int i = blockIdx.x * 256 + threadIdx.x; i < n; i += 128 * 256)
    o[i] = (signed char)(int)fminf(fmaxf(rintf(w[i] * s), -1.f), 1.f);
}

__global__ __launch_bounds__(256) void wcvt2(
    const float* __restrict__ ip, const float* __restrict__ op, u16* __restrict__ wb) {
  int i = blockIdx.x * 256 + threadIdx.x;  // 1048576 total
  if (i < 786432) wb[i] = f2bf(ip[i]);
  else wb[i] = f2bf(op[i - 786432]);
}

// snake tables: exp(la), 1/(exp(lb)+1e-9) for ff1 and ff2 (2048 each).
__global__ void prep_tables(
    const float* __restrict__ a1, const float* __restrict__ b1,
    const float* __restrict__ a2, const float* __restrict__ b2,
    float* __restrict__ tabs) {
  int i = blockIdx.x * 256 + threadIdx.x;
  if (i < 2048) {
    tabs[i] = __expf(a1[i]);
    tabs[2048 + i] = 1.0f / (__expf(b1[i]) + 1e-9f);
    tabs[4096 + i] = __expf(a2[i]);
    tabs[6144 + i] = 1.0f / (__expf(b2[i]) + 1e-9f);
  }
}

// ---------------------------------------------------------------------------
// RMSNorm: mode 0 = f32 out, 1 = int8-quant out + dq, 2 = bf16 out.
// ---------------------------------------------------------------------------
__global__ __launch_bounds__(256) void rmsnorm_multi(
    const float* __restrict__ x, const float* __restrict__ w, int mode,
    float* __restrict__ outf, signed char* __restrict__ out8,
    u16* __restrict__ outb, float* __restrict__ dq) {
  __shared__ float sm[4];
  int row = blockIdx.x, tid = threadIdx.x;
  const float* xr = x + (size_t)row * 512;
  float v0 = xr[tid], v1 = xr[tid + 256];
  float ss = blk_sum256(v0 * v0 + v1 * v1, sm);
  float sc = 1.0f / sqrtf(ss * (1.0f / 512.0f) + 1e-6f);
  float y0 = v0 * sc * w[tid];
  float y1 = v1 * sc * w[tid + 256];
  size_t o = (size_t)row * 512 + tid;
  if (mode == 0) {
    outf[o] = y0; outf[o + 256] = y1;
  } else if (mode == 1) {
    float am = blk_max256(fmaxf(fabsf(y0), fabsf(y1)), sm);
    float amc = fmaxf(am, 1e-5f);
    float s = 127.0f / amc;
    out8[o] = (signed char)(int)rintf(y0 * s);
    out8[o + 256] = (signed char)(int)rintf(y1 * s);
    if (tid == 0) dq[row] = amc * (1.0f / 127.0f);
  } else {
    outb[o] = f2bf(y0); outb[o + 256] = f2bf(y1);
  }
}

// ---------------------------------------------------------------------------
// snake_beta + int8 act-quant over bf16 rows of 2048, with exp tables.
// ---------------------------------------------------------------------------
__global__ __launch_bounds__(256) void snake_q8(
    const u16* __restrict__ h, const float* __restrict__ ta, const float* __restrict__ tb,
    signed char* __restrict__ out, float* __restrict__ dq) {
  __shared__ float sm[4];
  int row = blockIdx.x, tid = threadIdx.x;
  const u16* hr = h + (size_t)row * 2048;
  int c0 = tid * 8;
  v8s hv = *(const v8s*)(hr + c0);
  float4 ta0 = *(const float4*)(ta + c0);
  float4 ta1 = *(const float4*)(ta + c0 + 4);
  float4 tb0 = *(const float4*)(tb + c0);
  float4 tb1 = *(const float4*)(tb + c0 + 4);
  float sa[8] = {ta0.x, ta0.y, ta0.z, ta0.w, ta1.x, ta1.y, ta1.z, ta1.w};
  float sib[8] = {tb0.x, tb0.y, tb0.z, tb0.w, tb1.x, tb1.y, tb1.z, tb1.w};
  float vals[8];
  float am = 0.f;
#pragma unroll
  for (int j = 0; j < 8; ++j) {
    float v = bf2f((u16)hv[j]);
    float s = __sinf(sa[j] * v);
    v += s * s * sib[j];
    vals[j] = v;
    am = fmaxf(am, fabsf(v));
  }
  am = blk_max256(am, sm);
  float amc = fmaxf(am, 1e-5f);
  float s = 127.0f / amc;
  unsigned long long pkt = 0;
#pragma unroll
  for (int j = 0; j < 8; ++j) {
    int q = (int)rintf(vals[j] * s);
    pkt |= ((unsigned long long)(unsigned char)(signed char)q) << (8 * j);
  }
  *(unsigned long long*)(out + (size_t)row * 2048 + c0) = pkt;
  if (tid == 0) dq[row] = amc * (1.0f / 127.0f);
}

// ---------------------------------------------------------------------------
// Per-token int8 quant of a [M,512] f32 buffer.
// ---------------------------------------------------------------------------
__global__ __launch_bounds__(256) void rowquant512(
    const float* __restrict__ in, signed char* __restrict__ out, float* __restrict__ dq) {
  __shared__ float sm[4];
  int row = blockIdx.x, tid = threadIdx.x;
  const float* xr = in + (size_t)row * 512;
  float v0 = xr[tid], v1 = xr[tid + 256];
  float am = blk_max256(fmaxf(fabsf(v0), fabsf(v1)), sm);
  float amc = fmaxf(am, 1e-5f);
  float s = 127.0f / amc;
  size_t o = (size_t)row * 512 + tid;
  out[o] = (signed char)(int)rintf(v0 * s);
  out[o + 256] = (signed char)(int)rintf(v1 * s);
  if (tid == 0) dq[row] = amc * (1.0f / 127.0f);
}

// ---------------------------------------------------------------------------
// int8 GEMM: acc = (A i8[M,K] @ B i8[N,K]^T) * wsc * dq[m].
// 128xBN tile, BK=64, 4 waves (2x2), JF = BN/32 j-frags per wave.
// OBF: write bf16; else f32 (+resid).
// ---------------------------------------------------------------------------
template <int BN, bool OBF>
__global__ __launch_bounds__(256) void gemm_i8_t(
    const signed char* __restrict__ A, const signed char* __restrict__ B,
    const float* __restrict__ wsp, const float* __restrict__ adq,
    const float* __restrict__ resid, float rscale,
    float* __restrict__ outf, u16* __restrict__ outb, int N, int K) {
  constexpr int JF = BN / 32;  // j-fragments per wave (wave covers 16*JF cols)
  __shared__ signed char As[8192];
  __shared__ signed char Bs[BN * 64];
  const int tid = threadIdx.x;
  const int m0 = blockIdx.y << 7;
  const int n0 = blockIdx.x * BN;
  const int lane = tid & 63;
  const int wv = tid >> 6;
  const int wr = (wv >> 1) << 6, wc = (wv & 1) * (16 * JF);
  const int r15 = lane & 15, khi = lane >> 4;
  const int srow = tid >> 2;
  const int sslot = (tid & 3) ^ ((srow >> 1) & 3);
  const signed char* Ag = A + (size_t)(m0 + srow) * K + sslot * 16;
  const signed char* Bg = B + (size_t)(n0 + srow) * K + sslot * 16;
  const size_t half = (size_t)64 * K;

  int aoff[4], boff[JF];
#pragma unroll
  for (int i = 0; i < 4; ++i) {
    int r = wr + i * 16 + r15;
    aoff[i] = r * 64 + ((khi ^ ((r >> 1) & 3)) << 4);
  }
#pragma unroll
  for (int j = 0; j < JF; ++j) {
    int c = wc + j * 16 + r15;
    boff[j] = c * 64 + ((khi ^ ((c >> 1) & 3)) << 4);
  }
  v4i acc[4][JF] = {};
  for (int k0 = 0; k0 < K; k0 += 64) {
    __syncthreads();
    GLOAD_LDS(Ag + k0, As + tid * 16);
    GLOAD_LDS(Ag + half + k0, As + 4096 + tid * 16);
    GLOAD_LDS(Bg + k0, Bs + tid * 16);
    if constexpr (BN == 128) GLOAD_LDS(Bg + half + k0, Bs + 4096 + tid * 16);
    __syncthreads();
    v4i a[4], b[JF];
#pragma unroll
    for (int i = 0; i < 4; ++i) a[i] = *(const v4i*)(As + aoff[i]);
#pragma unroll
    for (int j = 0; j < JF; ++j) b[j] = *(const v4i*)(Bs + boff[j]);
#pragma unroll
    for (int i = 0; i < 4; ++i)
#pragma unroll
      for (int j = 0; j < JF; ++j)
        acc[i][j] = __builtin_amdgcn_mfma_i32_16x16x64_i8(a[i], b[j], acc[i][j], 0, 0, 0);
  }
  const float wsc = *wsp;
#pragma unroll
  for (int i = 0; i < 4; ++i) {
    int rb = m0 + wr + i * 16 + (khi << 2);
    float dqv[4];
#pragma unroll
    for (int rr = 0; rr < 4; ++rr) dqv[rr] = adq[rb + rr] * wsc;
#pragma unroll
    for (int j = 0; j < JF; ++j) {
      int col = n0 + wc + j * 16 + r15;
#pragma unroll
      for (int rr = 0; rr < 4; ++rr) {
        size_t idx = (size_t)(rb + rr) * N + col;
        float v = (float)acc[i][j][rr] * dqv[rr];
        if constexpr (OBF) outb[idx] = f2bf(v);
        else outf[idx] = resid ? fmaf(rscale, v, resid[idx]) : v;
      }
    }
  }
}

// ---------------------------------------------------------------------------
// bf16 GEMM: acc = A bf16[M,K] @ B bf16[N,K]^T + bias. OBF: bf16 out, else
// f32 resid+acc.
// ---------------------------------------------------------------------------
template <int BN, bool OBF>
__global__ __launch_bounds__(256) void gemm_bf16_t(
    const u16* __restrict__ A, const u16* __restrict__ B,
    const float* __restrict__ bias, const float* __restrict__ resid,
    float* __restrict__ outf, u16* __restrict__ outb, int N, int K) {
  constexpr int JF = BN / 32;
  __shared__ signed char As[8192];
  __shared__ signed char Bs[BN * 64];
  const int tid = threadIdx.x;
  const int m0 = blockIdx.y << 7;
  const int n0 = blockIdx.x * BN;
  const int lane = tid & 63;
  const int wv = tid >> 6;
  const int wr = (wv >> 1) << 6, wc = (wv & 1) * (16 * JF);
  const int r15 = lane & 15, khi = lane >> 4;
  const int srow = tid >> 2;
  const int sslot = (tid & 3) ^ ((srow >> 1) & 3);
  const int K2 = K * 2;
  const signed char* Ag = (const signed char*)A + (size_t)(m0 + srow) * K2 + sslot * 16;
  const signed char* Bg = (const signed char*)B + (size_t)(n0 + srow) * K2 + sslot * 16;
  const size_t half = (size_t)64 * K2;

  int aoff[4], boff[JF];
#pragma unroll
  for (int i = 0; i < 4; ++i) {
    int r = wr + i * 16 + r15;
    aoff[i] = r * 64 + ((khi ^ ((r >> 1) & 3)) << 4);
  }
#pragma unroll
  for (int j = 0; j < JF; ++j) {
    int c = wc + j * 16 + r15;
    boff[j] = c * 64 + ((khi ^ ((c >> 1) & 3)) << 4);
  }
  v4f acc[4][JF] = {};
  for (int kb = 0; kb < K2; kb += 64) {
    __syncthreads();
    GLOAD_LDS(Ag + kb, As + tid * 16);
    GLOAD_LDS(Ag + half + kb, As + 4096 + tid * 16);
    GLOAD_LDS(Bg + kb, Bs + tid * 16);
    if constexpr (BN == 128) GLOAD_LDS(Bg + half + kb, Bs + 4096 + tid * 16);
    __syncthreads();
    v8s a[4], b[JF];
#pragma unroll
    for (int i = 0; i < 4; ++i) a[i] = *(const v8s*)(As + aoff[i]);
#pragma unroll
    for (int j = 0; j < JF; ++j) b[j] = *(const v8s*)(Bs + boff[j]);
#pragma unroll
    for (int i = 0; i < 4; ++i)
#pragma unroll
      for (int j = 0; j < JF; ++j)
        acc[i][j] = __builtin_amdgcn_mfma_f32_16x16x32_bf16(a[i], b[j], acc[i][j], 0, 0, 0);
  }
#pragma unroll
  for (int i = 0; i < 4; ++i) {
    int rb = m0 + wr + i * 16 + (khi << 2);
#pragma unroll
    for (int j = 0; j < JF; ++j) {
      int col = n0 + wc + j * 16 + r15;
      float bv = bias[col];
#pragma unroll
      for (int rr = 0; rr < 4; ++rr) {
        size_t idx = (size_t)(rb + rr) * N + col;
        float v = acc[i][j][rr] + bv;
        if constexpr (OBF) outb[idx] = f2bf(v);
        else outf[idx] = resid[idx] + v;
      }
    }
  }
}

// ---------------------------------------------------------------------------
// V transpose: vt[bh][d=64][t=2048] <- qkv[b*2048+t][1024 + h*64 + d].
// ---------------------------------------------------------------------------
__global__ __launch_bounds__(256) void vtrans(
    const u16* __restrict__ qkv, u16* __restrict__ vt) {
  __shared__ u16 L[64 * 136];
  const int tid = threadIdx.x;
  const int bh = blockIdx.y;
  const int b = bh >> 3, h = bh & 7;
  const int t0 = blockIdx.x << 7;
  {
    const int t = tid & 127;
    const int dbase = (tid >> 7) << 5;
    const u16* src = qkv + (size_t)(b * 2048 + t0 + t) * 1536 + 1024 + h * 64 + dbase;
#pragma unroll
    for (int i = 0; i < 4; ++i) {
      v8s v = *(const v8s*)(src + i * 8);
#pragma unroll
      for (int j = 0; j < 8; ++j) L[(dbase + i * 8 + j) * 136 + t] = ((const u16*)&v)[j];
    }
  }
  __syncthreads();
  {
    const int d = tid >> 2;
    const int tc = (tid & 3) << 5;
    u16* dst = vt + (size_t)bh * 131072 + (size_t)d * 2048 + t0 + tc;
#pragma unroll
    for (int i = 0; i < 4; ++i)
      *(v8s*)(dst + i * 8) = *(const v8s*)&L[d * 136 + tc + i * 8];
  }
}

// ---------------------------------------------------------------------------
// KV fragment pack: kv[bh][tile(64)][frag(8)][lane(64)] 16B chunks.
// frag 0..3 = K fragments ks; frag 4..7 = V^T fragments (vf0..3).
// Each chunk is exactly the v8s the MFMA lane consumes -> attn loads become
// lane*16B coalesced bursts.
// ---------------------------------------------------------------------------
__global__ __launch_bounds__(256) void kvpack(
    const u16* __restrict__ qkv, const u16* __restrict__ vt, u16* __restrict__ kv) {
  const int tid = threadIdx.x;
  const int tile = blockIdx.x;  // 0..63
  const int bh = blockIdx.y;    // 0..31
  const int b = bh >> 3, h = bh & 7;
  u16* outb = kv + ((size_t)(bh * 64 + tile)) * 4096;
  const int lane = tid & 63, f = tid >> 6;  // f in 0..3
  const int l31 = lane & 31, hi = lane >> 5;
  {  // K fragment ks = f
    const u16* src = qkv + (size_t)(b * 2048 + tile * 32 + l31) * 1536 + 512 + h * 64 + f * 16 + hi * 8;
    *(v8s*)(outb + (size_t)f * 512 + lane * 8) = *(const v8s*)src;
  }
  {  // V fragment fv = f
    int d = l31 + ((f >> 1) << 5);
    int toff = ((f & 1) << 4) + hi * 8;
    const u16* src = vt + (size_t)bh * 131072 + (size_t)d * 2048 + tile * 32 + toff;
    *(v8s*)(outb + (size_t)(4 + f) * 512 + lane * 8) = *(const v8s*)src;
  }
}

// ---------------------------------------------------------------------------
// Flash attention, swapped-operand 32x32 bf16 MFMA, fragment-packed K/V,
// k-split x2. grid (16 qgroups, 32 bh, 2 k-halves), 4 waves. Writes
// normalized bf16 partials + (m,l) per (z, row, head).
// ---------------------------------------------------------------------------
__global__ __launch_bounds__(256) void attn32(
    const u16* __restrict__ qkv, const u16* __restrict__ kv,
    u16* __restrict__ opart, float* __restrict__ ml) {
  const int tid = threadIdx.x;
  const int lane = tid & 63;
  const int wv = tid >> 6;
  const int l31 = lane & 31;
  const int hi = lane >> 5;
  const int bh = blockIdx.y;
  const int z = blockIdx.z;
  const int b = bh >> 3, h = bh & 7;
  const int q0 = (blockIdx.x * 4 + wv) << 5;

  v8s qf[4];
  {
    const u16* qp = qkv + (size_t)(b * 2048 + q0 + l31) * 1536 + h * 64 + hi * 8;
#pragma unroll
    for (int ks = 0; ks < 4; ++ks) qf[ks] = *(const v8s*)(qp + ks * 16);
  }
  v16f o0 = {}, o1 = {};
  float m_run = -INFINITY, l_run = 0.f;

  // fragment-packed base: per tile 4096 u16 (8KB); K frags at 0..3, V at 4..7.
  const u16* kvb = kv + ((size_t)(bh * 64 + z * 32)) * 4096 + lane * 8;

  v8s kf[4], vf[4], kn[4], vn[4];
#pragma unroll
  for (int ks = 0; ks < 4; ++ks) kf[ks] = *(const v8s*)(kvb + ks * 512);
#pragma unroll
  for (int j = 0; j < 4; ++j) vf[j] = *(const v8s*)(kvb + (4 + j) * 512);

  const float C = 0.18033688011112042f;  // 0.125 * log2(e)

  for (int t = 0; t < 32; ++t) {
    // S^T = K · Q  (accumulate over d = 4 x 16)
    v16f sacc = {};
#pragma unroll
    for (int ks = 0; ks < 4; ++ks)
      sacc = __builtin_amdgcn_mfma_f32_32x32x16_bf16(kf[ks], qf[ks], sacc, 0, 0, 0);

    // prefetch next tile's K/V (coalesced 1KB bursts)
    int tn = (t < 31) ? (t + 1) : 31;
    {
      const u16* kvt = kvb + (size_t)tn * 4096;
#pragma unroll
      for (int ks = 0; ks < 4; ++ks) kn[ks] = *(const v8s*)(kvt + ks * 512);
#pragma unroll
      for (int j = 0; j < 4; ++j) vn[j] = *(const v8s*)(kvt + (4 + j) * 512);
    }

    float s[16];
#pragma unroll
    for (int r = 0; r < 16; ++r) s[r] = sacc[r];
    float mx = s[0];
#pragma unroll
    for (int r = 1; r < 16; ++r) mx = fmaxf(mx, s[r]);
    mx = fmaxf(mx, __shfl_xor(mx, 32));
    // defer-max: rescale only when the bound would exceed 2^8
    if (__any((mx - m_run) * C > 8.0f)) {
      float mn = fmaxf(m_run, mx);
      float corr = exp2f((m_run - mn) * C);
      m_run = mn;
      l_run *= corr;
#pragma unroll
      for (int r = 0; r < 16; ++r) { o0[r] *= corr; o1[r] *= corr; }
    }
    float mnC = m_run * C;
    float ls = 0.f;
#pragma unroll
    for (int r = 0; r < 16; ++r) {
      float p = exp2f(fmaf(s[r], C, -mnC));
      s[r] = p;
      ls += p;
    }
    ls += __shfl_xor(ls, 32);
    l_run += ls;

    // pack P to bf16 pairs, assemble B-fragments (P^T, col q = l31)
    unsigned pk[8], px[8];
#pragma unroll
    for (int g = 0; g < 8; ++g) {
      unsigned u;
      asm("v_cvt_pk_bf16_f32 %0, %1, %2" : "=v"(u) : "v"(s[2 * g]), "v"(s[2 * g + 1]));
      pk[g] = u;
      px[g] = (unsigned)__shfl_xor((int)u, 32);
    }
    v4i w0, w1;
    w0[0] = hi ? px[2] : pk[0];
    w0[1] = hi ? px[3] : pk[1];
    w0[2] = hi ? pk[2] : px[0];
    w0[3] = hi ? pk[3] : px[1];
    w1[0] = hi ? px[6] : pk[4];
    w1[1] = hi ? px[7] : pk[5];
    w1[2] = hi ? pk[6] : px[4];
    w1[3] = hi ? pk[7] : px[5];
    v8s pf0 = *(v8s*)&w0;
    v8s pf1 = *(v8s*)&w1;

    // O^T += V^T · P^T
    o0 = __builtin_amdgcn_mfma_f32_32x32x16_bf16(vf[0], pf0, o0, 0, 0, 0);
    o0 = __builtin_amdgcn_mfma_f32_32x32x16_bf16(vf[1], pf1, o0, 0, 0, 0);
    o1 = __builtin_amdgcn_mfma_f32_32x32x16_bf16(vf[2], pf0, o1, 0, 0, 0);
    o1 = __builtin_amdgcn_mfma_f32_32x32x16_bf16(vf[3], pf1, o1, 0, 0, 0);

#pragma unroll
    for (int ks = 0; ks < 4; ++ks) { kf[ks] = kn[ks]; vf[ks] = vn[ks]; }
  }

  float inv = 1.0f / l_run;
  u16* orow = opart + (size_t)z * 4194304 + (size_t)(b * 2048 + q0 + l31) * 512 + h * 64;
#pragma unroll
  for (int dt = 0; dt < 2; ++dt) {
#pragma unroll
    for (int g = 0; g < 8; ++g) {
      int d = dt * 32 + ((2 * g) & 3) + 8 * (g >> 1) + 4 * hi;
      float a = (dt ? o1[2 * g] : o0[2 * g]) * inv;
      float bv = (dt ? o1[2 * g + 1] : o0[2 * g + 1]) * inv;
      unsigned u;
      asm("v_cvt_pk_bf16_f32 %0, %1, %2" : "=v"(u) : "v"(a), "v"(bv));
      *(unsigned*)(orow + d) = u;
    }
  }
  if (hi == 0) {
    size_t mi = ((size_t)(z * 8192 + b * 2048 + q0 + l31) * 8 + h) * 2;
    ml[mi] = m_run;
    ml[mi + 1] = l_run;
  }
}

// ---------------------------------------------------------------------------
// Merge the two k-halves: attno = w0*O0 + w1*O1 (flash combine).
// ---------------------------------------------------------------------------
__global__ __launch_bounds__(256) void attn_merge(
    const u16* __restrict__ opart, const float* __restrict__ ml,
    u16* __restrict__ attno) {
  __shared__ float w0s[8], w1s[8];
  const int r = blockIdx.x, tid = threadIdx.x;
  if (tid < 8) {
    const float C = 0.18033688011112042f;
    size_t i0 = ((size_t)r * 8 + tid) * 2;
    size_t i1 = ((size_t)(8192 + r) * 8 + tid) * 2;
    float m0 = ml[i0], l0 = ml[i0 + 1];
    float m1 = ml[i1], l1 = ml[i1 + 1];
    float M = fmaxf(m0, m1);
    float a0 = exp2f((m0 - M) * C) * l0;
    float a1 = exp2f((m1 - M) * C) * l1;
    float inv = 1.0f / (a0 + a1);
    w0s[tid] = a0 * inv;
    w1s[tid] = a1 * inv;
  }
  __syncthreads();
  int c = tid * 2;
  unsigned p0 = *(const unsigned*)(opart + (size_t)r * 512 + c);
  unsigned p1 = *(const unsigned*)(opart + 4194304 + (size_t)r * 512 + c);
  int hh = c >> 6;
  float w0 = w0s[hh], w1 = w1s[hh];
  float x0 = bf2f((u16)p0) * w0 + bf2f((u16)p1) * w1;
  float x1 = bf2f((u16)(p0 >> 16)) * w0 + bf2f((u16)(p1 >> 16)) * w1;
  unsigned u;
  asm("v_cvt_pk_bf16_f32 %0, %1, %2" : "=v"(u) : "v"(x0), "v"(x1));
  *(unsigned*)(attno + (size_t)r * 512 + c) = u;
}

// ---------------------------------------------------------------------------
// Fused GLU + depthwise conv(K=31) + BN + snake. In: g3 bf16 [8192,1024]
// (a|g). Out: f32 [8192,512]. Block: (chgroup 64, t-tile 128, batch).
// ---------------------------------------------------------------------------
__global__ __launch_bounds__(256) void dwconv_fused(
    const u16* __restrict__ g3, const float* __restrict__ dww,
    const float* __restrict__ dwb, const float* __restrict__ bng,
    const float* __restrict__ bnb, const float* __restrict__ bnm,
    const float* __restrict__ bnv, const float* __restrict__ la,
    const float* __restrict__ lb, float* __restrict__ outp) {
  __shared__ float IN[160 * 64];
  __shared__ float WT[1984];
  __shared__ float PRM[4][64];
  const int tid = threadIdx.x;
  const int cg = blockIdx.x << 6;
  const int t0 = blockIdx.y << 7;
  const int bb = blockIdx.z;

  if (tid < 64) {
    int c = cg + tid;
    float sc = bng[c] / sqrtf(bnv[c] + 1e-5f);
    PRM[0][tid] = sc;
    PRM[1][tid] = (dwb[c] - bnm[c]) * sc + bnb[c];
    PRM[2][tid] = __expf(la[c]);
    PRM[3][tid] = 1.0f / (__expf(lb[c]) + 1e-9f);
  }
  for (int i = tid; i < 1984; i += 256) WT[i] = dww[cg * 31 + i];

#pragma unroll
  for (int p = 0; p < 5; ++p) {
    int r = p * 32 + (tid >> 3);
    int t = t0 - 16 + r;
    int c8 = (tid & 7) << 3;
    float4 lo = make_float4(0.f, 0.f, 0.f, 0.f);
    float4 hv = make_float4(0.f, 0.f, 0.f, 0.f);
    if (t >= 0 && t < 2048) {
      const u16* rp = g3 + ((size_t)(bb * 2048 + t)) * 1024 + cg + c8;
      v8s a8 = *(const v8s*)rp;
      v8s g8 = *(const v8s*)(rp + 512);
      float va[8];
#pragma unroll
      for (int j = 0; j < 8; ++j) {
        float fa = bf2f((u16)a8[j]);
        float fg = bf2f((u16)g8[j]);
        va[j] = fa / (1.f + __expf(-fg));
      }
      lo = make_float4(va[0], va[1], va[2], va[3]);
      hv = make_float4(va[4], va[5], va[6], va[7]);
    }
    *(float4*)&IN[r * 64 + c8] = lo;
    *(float4*)&IN[r * 64 + c8 + 4] = hv;
  }
  __syncthreads();

  const int ch = tid & 63;
  const int tg = tid >> 6;
  const float sc = PRM[0][ch], sh = PRM[1][ch], sa = PRM[2][ch], sib = PRM[3][ch];
  float w[31];
#pragma unroll
  for (int k = 0; k < 31; ++k) w[k] = WT[ch * 31 + k];

  for (int pass = 0; pass < 4; ++pass) {
    int tl = pass * 32 + tg * 8;
    float x[38];
#pragma unroll
    for (int i = 0; i < 38; ++i) x[i] = IN[(tl + 1 + i) * 64 + ch];
    float acc[8] = {0.f, 0.f, 0.f, 0.f, 0.f, 0.f, 0.f, 0.f};
#pragma unroll
    for (int k = 0; k < 31; ++k)
#pragma unroll
      for (int j = 0; j < 8; ++j) acc[j] = fmaf(x[k + j], w[k], acc[j]);
#pragma unroll
    for (int j = 0; j < 8; ++j) {
      float v = acc[j] * sc + sh;
      float s = __sinf(sa * v);
      v += s * s * sib;
      outp[((size_t)(bb * 2048 + t0 + tl + j)) * 512 + cg + ch] = v;
    }
  }
}

// ---------------------------------------------------------------------------
extern "C" void kernel_launch(void* const* d_in, const int* in_sizes, int n_in,
                              void* d_out, int out_size, void* d_ws, size_t ws_size,
                              hipStream_t stream) {
  const float* x_in = (const float*)d_in[0];
  const float* ff1_norm_w = (const float*)d_in[1];
  const float* ff1_w1 = (const float*)d_in[2];
  const float* ff1_a = (const float*)d_in[3];
  const float* ff1_b = (const float*)d_in[4];
  const float* ff1_w2 = (const float*)d_in[5];
  const float* attn_norm_w = (const float*)d_in[6];
  const float* in_proj_w = (const float*)d_in[7];
  const float* in_proj_b = (const float*)d_in[8];
  const float* out_proj_w = (const float*)d_in[9];
  const float* out_proj_b = (const float*)d_in[10];
  const float* conv_norm_w = (const float*)d_in[11];
  const float* pw1_w = (const float*)d_in[12];
  const float* dw_w = (const float*)d_in[13];
  const float* dw_b = (const float*)d_in[14];
  const float* bn_g = (const float*)d_in[15];
  const float* bn_b = (const float*)d_in[16];
  const float* bn_m = (const float*)d_in[17];
  const float* bn_v = (const float*)d_in[18];
  const float* snake_a = (const float*)d_in[19];
  const float* snake_b = (const float*)d_in[20];
  const float* pw2_w = (const float*)d_in[21];
  const float* ff2_norm_w = (const float*)d_in[22];
  const float* ff2_w1 = (const float*)d_in[23];
  const float* ff2_a = (const float*)d_in[24];
  const float* ff2_b = (const float*)d_in[25];
  const float* ff2_w2 = (const float*)d_in[26];
  const float* final_norm_w = (const float*)d_in[27];
  float* out = (float*)d_out;

  char* ws = (char*)d_ws;
  float* x_cur = (float*)(ws + 0);                     // 16 MiB
  char* arena = ws + 16777216;                         // 64 MiB
  // attn phase:
  u16* qkv = (u16*)arena;                              // 24 MiB
  u16* attno = (u16*)(arena + 25165824);               // 8 MiB
  u16* vt = (u16*)(arena + 33554432);                  // 8 MiB
  u16* opart = (u16*)(arena + 41943040);               // 16 MiB
  float* ml = (float*)(arena + 58720256);              // 2 MiB
  // FFN phase:
  u16* h_b = (u16*)arena;                              // 32 MiB
  // conv phase:
  u16* g3b = (u16*)arena;                              // 16 MiB
  float* convout = (float*)(arena + 33554432);         // 16 MiB
  signed char* a8a = (signed char*)(ws + 83886080);    // 4 MiB
  signed char* a8b = (signed char*)(ws + 88080384);    // 16 MiB
  u16* kvp = (u16*)(ws + 88080384);                    // 16 MiB (attn phase; aliases a8b)
  u16* xnb = (u16*)(ws + 104857600);                   // 8 MiB
  signed char* wq = (signed char*)(ws + 113246208);    // 4.75 MiB
  signed char* wq_w1 = wq;
  signed char* wq_w2 = wq + 1048576;
  signed char* wq_p1 = wq + 2097152;
  signed char* wq_p2 = wq + 2621440;
  signed char* wq_f21 = wq + 2883584;
  signed char* wq_f22 = wq + 3932160;
  u16* wb = (u16*)(ws + 118226944);                    // 2 MiB
  u16* wb_ip = wb;
  u16* wb_op = wb + 786432;
  float* scales = (float*)(ws + 120324096);
  float* partials = (float*)(ws + 120324352);
  float* ascale = (float*)(ws + 120325888);            // 32 KiB
  float* tabs = (float*)(ws + 120358912);              // 32 KiB

  // --- weight prep ---
  wabs_stage1<<<384, 256, 0, stream>>>(ff1_w1, ff1_w2, pw1_w, pw2_w, ff2_w1, ff2_w2, partials);
  wabs_stage2<<<1, 64, 0, stream>>>(partials, scales);
  wquant_all<<<dim3(128, 6), 256, 0, stream>>>(ff1_w1, ff1_w2, pw1_w, pw2_w, ff2_w1, ff2_w2,
                                               scales, wq);
  wcvt2<<<4096, 256, 0, stream>>>(in_proj_w, out_proj_w, wb);
  prep_tables<<<8, 256, 0, stream>>>(ff1_a, ff1_b, ff2_a, ff2_b, tabs);

  // --- FFN1: x_cur = x + 0.5*ffn(x) ---
  rmsnorm_multi<<<8192, 256, 0, stream>>>(x_in, ff1_norm_w, 1, nullptr, a8a, nullptr, ascale);
  gemm_i8_t<128, true><<<dim3(16, 64), 256, 0, stream>>>(
      a8a, wq_w1, scales + 0, ascale, nullptr, 1.0f, nullptr, h_b, 2048, 512);
  snake_q8<<<8192, 256, 0, stream>>>(h_b, tabs, tabs + 2048, a8b, ascale);
  gemm_i8_t<64, false><<<dim3(8, 64), 256, 0, stream>>>(
      a8b, wq_w2, scales + 1, ascale, x_in, 0.5f, x_cur, nullptr, 512, 2048);

  // --- MHA: x_cur += mha(x_cur) ---
  rmsnorm_multi<<<8192, 256, 0, stream>>>(x_cur, attn_norm_w, 2, nullptr, nullptr, xnb, nullptr);
  gemm_bf16_t<128, true><<<dim3(12, 64), 256, 0, stream>>>(
      xnb, wb_ip, in_proj_b, nullptr, nullptr, qkv, 1536, 512);
  vtrans<<<dim3(16, 32), 256, 0, stream>>>(qkv, vt);
  kvpack<<<dim3(64, 32), 256, 0, stream>>>(qkv, vt, kvp);
  attn32<<<dim3(16, 32, 2), 256, 0, stream>>>(qkv, kvp, opart, ml);
  attn_merge<<<8192, 256, 0, stream>>>(opart, ml, attno);
  gemm_bf16_t<64, false><<<dim3(8, 64), 256, 0, stream>>>(
      attno, wb_op, out_proj_b, x_cur, x_cur, nullptr, 512, 512);

  // --- conv branch: x_cur += conv(x_cur) ---
  rmsnorm_multi<<<8192, 256, 0, stream>>>(x_cur, conv_norm_w, 1, nullptr, a8a, nullptr, ascale);
  gemm_i8_t<128, true><<<dim3(8, 64), 256, 0, stream>>>(
      a8a, wq_p1, scales + 2, ascale, nullptr, 1.0f, nullptr, g3b, 1024, 512);
  dwconv_fused<<<dim3(8, 16, 4), 256, 0, stream>>>(g3b, dw_w, dw_b, bn_g, bn_b, bn_m, bn_v,
                                                   snake_a, snake_b, convout);
  rowquant512<<<8192, 256, 0, stream>>>(convout, a8a, ascale);
  gemm_i8_t<64, false><<<dim3(8, 64), 256, 0, stream>>>(
      a8a, wq_p2, scales + 3, ascale, x_cur, 1.0f, x_cur, nullptr, 512, 512);

  // --- FFN2: x_cur += 0.5*ffn(x_cur) ---
  rmsnorm_multi<<<8192, 256, 0, stream>>>(x_cur, ff2_norm_w, 1, nullptr, a8a, nullptr, ascale);
  gemm_i8_t<128, true><<<dim3(16, 64), 256, 0, stream>>>(
      a8a, wq_f21, scales + 4, ascale, nullptr, 1.0f, nullptr, h_b, 2048, 512);
  snake_q8<<<8192, 256, 0, stream>>>(h_b, tabs + 4096, tabs + 6144, a8b, ascale);
  gemm_i8_t<64, false><<<dim3(8, 64), 256, 0, stream>>>(
      a8b, wq_f22, scales + 5, ascale, x_cur, 0.5f, x_cur, nullptr, 512, 2048);

  // --- final rmsnorm -> out ---
  rmsnorm_multi<<<8192, 256, 0, stream>>>(x_cur, final_norm_w, 0, out, nullptr, nullptr, nullptr);
}

// Round 7
// 385.246 us; speedup vs baseline: 8.3821x; 1.0110x over previous
//
#include <hip/hip_runtime.h>
#include <math.h>

// ---------------------------------------------------------------------------
// ConformerBlock MFMA implementation.
// B=4, T=2048, D=512, H=8, hd=64, K=31.  M = B*T = 8192.
// Bitlinear GEMMs: int8 MFMA (exact). Attention/projections: bf16 MFMA.
// Attention: swapped-operand 32x32 MFMA, fragment-packed Q/K/V (coalesced),
// MFMA-computed softmax denominator, k-split x2 + flash merge.
// ---------------------------------------------------------------------------

typedef int   v4i __attribute__((ext_vector_type(4)));
typedef float v4f __attribute__((ext_vector_type(4)));
typedef float v16f __attribute__((ext_vector_type(16)));
typedef short v8s __attribute__((ext_vector_type(8)));
typedef unsigned short u16;

#define GLOAD_LDS(g, l) __builtin_amdgcn_global_load_lds( \
    (const __attribute__((address_space(1))) void*)(g),   \
    (__attribute__((address_space(3))) void*)(l), 16, 0, 0)

__device__ __forceinline__ float blk_sum256(float v, float* sm) {
#pragma unroll
  for (int m = 32; m; m >>= 1) v += __shfl_xor(v, m);
  int w = threadIdx.x >> 6;
  __syncthreads();
  if ((threadIdx.x & 63) == 0) sm[w] = v;
  __syncthreads();
  return sm[0] + sm[1] + sm[2] + sm[3];
}

__device__ __forceinline__ float blk_max256(float v, float* sm) {
#pragma unroll
  for (int m = 32; m; m >>= 1) v = fmaxf(v, __shfl_xor(v, m));
  int w = threadIdx.x >> 6;
  __syncthreads();
  if ((threadIdx.x & 63) == 0) sm[w] = v;
  __syncthreads();
  return fmaxf(fmaxf(sm[0], sm[1]), fmaxf(sm[2], sm[3]));
}

__device__ __forceinline__ u16 f2bf(float f) {
  union { float f; unsigned u; } x;
  x.f = f;
  unsigned r = x.u + 0x7fffu + ((x.u >> 16) & 1u);
  return (u16)(r >> 16);
}

__device__ __forceinline__ float bf2f(u16 u) {
  union { unsigned u; float f; } x;
  x.u = ((unsigned)u) << 16;
  return x.f;
}

// ---------------------------------------------------------------------------
// Weight absmean (deterministic two-stage) + quantizers.
// ---------------------------------------------------------------------------
__global__ __launch_bounds__(256) void wabs_stage1(
    const float* __restrict__ w0, const float* __restrict__ w1,
    const float* __restrict__ w2, const float* __restrict__ w3,
    const float* __restrict__ w4, const float* __restrict__ w5,
    float* __restrict__ part) {
  __shared__ float sm[4];
  const float* ws[6] = {w0, w1, w2, w3, w4, w5};
  const int ns[6] = {1048576, 1048576, 524288, 262144, 1048576, 1048576};
  int widx = blockIdx.x >> 6;
  int chunk = blockIdx.x & 63;
  const float* w = ws[widx];
  int n = ns[widx];
  float s = 0.f;
  for (int i = chunk * 256 + threadIdx.x; i < n; i += 64 * 256) s += fabsf(w[i]);
  s = blk_sum256(s, sm);
  if (threadIdx.x == 0) part[widx * 64 + chunk] = s;
}

__global__ void wabs_stage2(const float* __restrict__ part, float* __restrict__ scales) {
  int t = threadIdx.x;
  if (t < 6) {
    const int ns[6] = {1048576, 1048576, 524288, 262144, 1048576, 1048576};
    float s = 0.f;
    for (int i = 0; i < 64; ++i) s += part[t * 64 + i];
    scales[t] = fmaxf(s / (float)ns[t], 1e-5f);  // wsc = clip(mean|w|,1e-5)
  }
}

__global__ __launch_bounds__(256) void wquant_all(
    const float* __restrict__ w0, const float* __restrict__ w1,
    const float* __restrict__ w2, const float* __restrict__ w3,
    const float* __restrict__ w4, const float* __restrict__ w5,
    const float* __restrict__ scales, signed char* __restrict__ out) {
  const float* ws[6] = {w0, w1, w2, w3, w4, w5};
  const int ns[6] = {1048576, 1048576, 524288, 262144, 1048576, 1048576};
  const int offs[6] = {0, 1048576, 2097152, 2621440, 2883584, 3932160};
  int widx = blockIdx.y;
  const float* w = ws[widx];
  int n = ns[widx];
  signed char* o = out + offs[widx];
  float s = 1.0f / scales[widx];
  for (int i = blockIdx.x * 256 + threadIdx.x; i < n; i += 128 * 256)
    o[i] = (signed char)(int)fminf(fmaxf(rintf(w[i] * s), -1.f), 1.f);
}

__global__ __launch_bounds__(256) void wcvt2(
    const float* __restrict__ ip, const float* __restrict__ op, u16* __restrict__ wb) {
  int i = blockIdx.x * 256 + threadIdx.x;  // 1048576 total
  if (i < 786432) wb[i] = f2bf(ip[i]);
  else wb[i] = f2bf(op[i - 786432]);
}

// snake tables: exp(la), 1/(exp(lb)+1e-9) for ff1 and ff2 (2048 each).
__global__ void prep_tables(
    const float* __restrict__ a1, const float* __restrict__ b1,
    const float* __restrict__ a2, const float* __restrict__ b2,
    float* __restrict__ tabs) {
  int i = blockIdx.x * 256 + threadIdx.x;
  if (i < 2048) {
    tabs[i] = __expf(a1[i]);
    tabs[2048 + i] = 1.0f / (__expf(b1[i]) + 1e-9f);
    tabs[4096 + i] = __expf(a2[i]);
    tabs[6144 + i] = 1.0f / (__expf(b2[i]) + 1e-9f);
  }
}

// ---------------------------------------------------------------------------
// RMSNorm: mode 0 = f32 out, 1 = int8-quant out + dq, 2 = bf16 out.
// ---------------------------------------------------------------------------
__global__ __launch_bounds__(256) void rmsnorm_multi(
    const float* __restrict__ x, const float* __restrict__ w, int mode,
    float* __restrict__ outf, signed char* __restrict__ out8,
    u16* __restrict__ outb, float* __restrict__ dq) {
  __shared__ float sm[4];
  int row = blockIdx.x, tid = threadIdx.x;
  const float* xr = x + (size_t)row * 512;
  float v0 = xr[tid], v1 = xr[tid + 256];
  float ss = blk_sum256(v0 * v0 + v1 * v1, sm);
  float sc = 1.0f / sqrtf(ss * (1.0f / 512.0f) + 1e-6f);
  float y0 = v0 * sc * w[tid];
  float y1 = v1 * sc * w[tid + 256];
  size_t o = (size_t)row * 512 + tid;
  if (mode == 0) {
    outf[o] = y0; outf[o + 256] = y1;
  } else if (mode == 1) {
    float am = blk_max256(fmaxf(fabsf(y0), fabsf(y1)), sm);
    float amc = fmaxf(am, 1e-5f);
    float s = 127.0f / amc;
    out8[o] = (signed char)(int)rintf(y0 * s);
    out8[o + 256] = (signed char)(int)rintf(y1 * s);
    if (tid == 0) dq[row] = amc * (1.0f / 127.0f);
  } else {
    outb[o] = f2bf(y0); outb[o + 256] = f2bf(y1);
  }
}

// ---------------------------------------------------------------------------
// snake_beta + int8 act-quant over bf16 rows of 2048, with exp tables.
// ---------------------------------------------------------------------------
__global__ __launch_bounds__(256) void snake_q8(
    const u16* __restrict__ h, const float* __restrict__ ta, const float* __restrict__ tb,
    signed char* __restrict__ out, float* __restrict__ dq) {
  __shared__ float sm[4];
  int row = blockIdx.x, tid = threadIdx.x;
  const u16* hr = h + (size_t)row * 2048;
  int c0 = tid * 8;
  v8s hv = *(const v8s*)(hr + c0);
  float4 ta0 = *(const float4*)(ta + c0);
  float4 ta1 = *(const float4*)(ta + c0 + 4);
  float4 tb0 = *(const float4*)(tb + c0);
  float4 tb1 = *(const float4*)(tb + c0 + 4);
  float sa[8] = {ta0.x, ta0.y, ta0.z, ta0.w, ta1.x, ta1.y, ta1.z, ta1.w};
  float sib[8] = {tb0.x, tb0.y, tb0.z, tb0.w, tb1.x, tb1.y, tb1.z, tb1.w};
  float vals[8];
  float am = 0.f;
#pragma unroll
  for (int j = 0; j < 8; ++j) {
    float v = bf2f((u16)hv[j]);
    float s = __sinf(sa[j] * v);
    v += s * s * sib[j];
    vals[j] = v;
    am = fmaxf(am, fabsf(v));
  }
  am = blk_max256(am, sm);
  float amc = fmaxf(am, 1e-5f);
  float s = 127.0f / amc;
  unsigned long long pkt = 0;
#pragma unroll
  for (int j = 0; j < 8; ++j) {
    int q = (int)rintf(vals[j] * s);
    pkt |= ((unsigned long long)(unsigned char)(signed char)q) << (8 * j);
  }
  *(unsigned long long*)(out + (size_t)row * 2048 + c0) = pkt;
  if (tid == 0) dq[row] = amc * (1.0f / 127.0f);
}

// ---------------------------------------------------------------------------
// Per-token int8 quant of a [M,512] bf16 buffer.
// ---------------------------------------------------------------------------
__global__ __launch_bounds__(256) void rowquant512_bf(
    const u16* __restrict__ in, signed char* __restrict__ out, float* __restrict__ dq) {
  __shared__ float sm[4];
  int row = blockIdx.x, tid = threadIdx.x;
  unsigned pv = *(const unsigned*)(in + (size_t)row * 512 + tid * 2);
  float v0 = bf2f((u16)pv), v1 = bf2f((u16)(pv >> 16));
  float am = blk_max256(fmaxf(fabsf(v0), fabsf(v1)), sm);
  float amc = fmaxf(am, 1e-5f);
  float s = 127.0f / amc;
  signed char q0 = (signed char)(int)rintf(v0 * s);
  signed char q1 = (signed char)(int)rintf(v1 * s);
  unsigned short pk = (unsigned short)((unsigned char)q0 | ((unsigned)(unsigned char)q1 << 8));
  *(unsigned short*)(out + (size_t)row * 512 + tid * 2) = pk;
  if (tid == 0) dq[row] = amc * (1.0f / 127.0f);
}

// ---------------------------------------------------------------------------
// int8 GEMM: acc = (A i8[M,K] @ B i8[N,K]^T) * wsc * dq[m].
// 128xBN tile, BK=64, 4 waves (2x2), JF = BN/32 j-frags per wave.
// OBF: write bf16; else f32 (+resid).
// ---------------------------------------------------------------------------
template <int BN, bool OBF>
__global__ __launch_bounds__(256) void gemm_i8_t(
    const signed char* __restrict__ A, const signed char* __restrict__ B,
    const float* __restrict__ wsp, const float* __restrict__ adq,
    const float* __restrict__ resid, float rscale,
    float* __restrict__ outf, u16* __restrict__ outb, int N, int K) {
  constexpr int JF = BN / 32;  // j-fragments per wave (wave covers 16*JF cols)
  __shared__ signed char As[8192];
  __shared__ signed char Bs[BN * 64];
  const int tid = threadIdx.x;
  const int m0 = blockIdx.y << 7;
  const int n0 = blockIdx.x * BN;
  const int lane = tid & 63;
  const int wv = tid >> 6;
  const int wr = (wv >> 1) << 6, wc = (wv & 1) * (16 * JF);
  const int r15 = lane & 15, khi = lane >> 4;
  const int srow = tid >> 2;
  const int sslot = (tid & 3) ^ ((srow >> 1) & 3);
  const signed char* Ag = A + (size_t)(m0 + srow) * K + sslot * 16;
  const signed char* Bg = B + (size_t)(n0 + srow) * K + sslot * 16;
  const size_t half = (size_t)64 * K;

  int aoff[4], boff[JF];
#pragma unroll
  for (int i = 0; i < 4; ++i) {
    int r = wr + i * 16 + r15;
    aoff[i] = r * 64 + ((khi ^ ((r >> 1) & 3)) << 4);
  }
#pragma unroll
  for (int j = 0; j < JF; ++j) {
    int c = wc + j * 16 + r15;
    boff[j] = c * 64 + ((khi ^ ((c >> 1) & 3)) << 4);
  }
  v4i acc[4][JF] = {};
  for (int k0 = 0; k0 < K; k0 += 64) {
    __syncthreads();
    GLOAD_LDS(Ag + k0, As + tid * 16);
    GLOAD_LDS(Ag + half + k0, As + 4096 + tid * 16);
    GLOAD_LDS(Bg + k0, Bs + tid * 16);
    if constexpr (BN == 128) GLOAD_LDS(Bg + half + k0, Bs + 4096 + tid * 16);
    __syncthreads();
    v4i a[4], b[JF];
#pragma unroll
    for (int i = 0; i < 4; ++i) a[i] = *(const v4i*)(As + aoff[i]);
#pragma unroll
    for (int j = 0; j < JF; ++j) b[j] = *(const v4i*)(Bs + boff[j]);
#pragma unroll
    for (int i = 0; i < 4; ++i)
#pragma unroll
      for (int j = 0; j < JF; ++j)
        acc[i][j] = __builtin_amdgcn_mfma_i32_16x16x64_i8(a[i], b[j], acc[i][j], 0, 0, 0);
  }
  const float wsc = *wsp;
#pragma unroll
  for (int i = 0; i < 4; ++i) {
    int rb = m0 + wr + i * 16 + (khi << 2);
    float dqv[4];
#pragma unroll
    for (int rr = 0; rr < 4; ++rr) dqv[rr] = adq[rb + rr] * wsc;
#pragma unroll
    for (int j = 0; j < JF; ++j) {
      int col = n0 + wc + j * 16 + r15;
#pragma unroll
      for (int rr = 0; rr < 4; ++rr) {
        size_t idx = (size_t)(rb + rr) * N + col;
        float v = (float)acc[i][j][rr] * dqv[rr];
        if constexpr (OBF) outb[idx] = f2bf(v);
        else outf[idx] = resid ? fmaf(rscale, v, resid[idx]) : v;
      }
    }
  }
}

// ---------------------------------------------------------------------------
// bf16 GEMM: acc = A bf16[M,K] @ B bf16[N,K]^T + bias. OBF: bf16 out, else
// f32 resid+acc.
// ---------------------------------------------------------------------------
template <int BN, bool OBF>
__global__ __launch_bounds__(256) void gemm_bf16_t(
    const u16* __restrict__ A, const u16* __restrict__ B,
    const float* __restrict__ bias, const float* __restrict__ resid,
    float* __restrict__ outf, u16* __restrict__ outb, int N, int K) {
  constexpr int JF = BN / 32;
  __shared__ signed char As[8192];
  __shared__ signed char Bs[BN * 64];
  const int tid = threadIdx.x;
  const int m0 = blockIdx.y << 7;
  const int n0 = blockIdx.x * BN;
  const int lane = tid & 63;
  const int wv = tid >> 6;
  const int wr = (wv >> 1) << 6, wc = (wv & 1) * (16 * JF);
  const int r15 = lane & 15, khi = lane >> 4;
  const int srow = tid >> 2;
  const int sslot = (tid & 3) ^ ((srow >> 1) & 3);
  const int K2 = K * 2;
  const signed char* Ag = (const signed char*)A + (size_t)(m0 + srow) * K2 + sslot * 16;
  const signed char* Bg = (const signed char*)B + (size_t)(n0 + srow) * K2 + sslot * 16;
  const size_t half = (size_t)64 * K2;

  int aoff[4], boff[JF];
#pragma unroll
  for (int i = 0; i < 4; ++i) {
    int r = wr + i * 16 + r15;
    aoff[i] = r * 64 + ((khi ^ ((r >> 1) & 3)) << 4);
  }
#pragma unroll
  for (int j = 0; j < JF; ++j) {
    int c = wc + j * 16 + r15;
    boff[j] = c * 64 + ((khi ^ ((c >> 1) & 3)) << 4);
  }
  v4f acc[4][JF] = {};
  for (int kb = 0; kb < K2; kb += 64) {
    __syncthreads();
    GLOAD_LDS(Ag + kb, As + tid * 16);
    GLOAD_LDS(Ag + half + kb, As + 4096 + tid * 16);
    GLOAD_LDS(Bg + kb, Bs + tid * 16);
    if constexpr (BN == 128) GLOAD_LDS(Bg + half + kb, Bs + 4096 + tid * 16);
    __syncthreads();
    v8s a[4], b[JF];
#pragma unroll
    for (int i = 0; i < 4; ++i) a[i] = *(const v8s*)(As + aoff[i]);
#pragma unroll
    for (int j = 0; j < JF; ++j) b[j] = *(const v8s*)(Bs + boff[j]);
#pragma unroll
    for (int i = 0; i < 4; ++i)
#pragma unroll
      for (int j = 0; j < JF; ++j)
        acc[i][j] = __builtin_amdgcn_mfma_f32_16x16x32_bf16(a[i], b[j], acc[i][j], 0, 0, 0);
  }
#pragma unroll
  for (int i = 0; i < 4; ++i) {
    int rb = m0 + wr + i * 16 + (khi << 2);
#pragma unroll
    for (int j = 0; j < JF; ++j) {
      int col = n0 + wc + j * 16 + r15;
      float bv = bias[col];
#pragma unroll
      for (int rr = 0; rr < 4; ++rr) {
        size_t idx = (size_t)(rb + rr) * N + col;
        float v = acc[i][j][rr] + bv;
        if constexpr (OBF) outb[idx] = f2bf(v);
        else outf[idx] = resid[idx] + v;
      }
    }
  }
}

// ---------------------------------------------------------------------------
// Q/K/V fragment pack: kvqp[bh][tile(64)][frag(12)][lane(64)] 16B chunks.
// frag 0..3 = K, 4..7 = V^T (via LDS transpose), 8..11 = Q.
// ---------------------------------------------------------------------------
__global__ __launch_bounds__(256) void kvqpack(
    const u16* __restrict__ qkv, u16* __restrict__ kvqp) {
  __shared__ u16 Lv[32 * 72];  // V rows [t=32][d=64] padded to 72
  const int tid = threadIdx.x;
  const int tile = blockIdx.x;  // 0..63
  const int bh = blockIdx.y;    // 0..31
  const int b = bh >> 3, h = bh & 7;
  u16* outb = kvqp + ((size_t)(bh * 64 + tile)) * 6144;
  const int lane = tid & 63, f = tid >> 6;  // f in 0..3
  const int l31 = lane & 31, hi = lane >> 5;

  // stage V rows into LDS (coalesced)
  {
    int r = tid >> 3, c = (tid & 7) << 3;
    const u16* src = qkv + (size_t)(b * 2048 + tile * 32 + r) * 1536 + 1024 + h * 64 + c;
    *(v8s*)(&Lv[r * 72 + c]) = *(const v8s*)src;
  }
  {  // Q fragment ks = f
    const u16* src = qkv + (size_t)(b * 2048 + tile * 32 + l31) * 1536 + h * 64 + f * 16 + hi * 8;
    *(v8s*)(outb + (size_t)(8 + f) * 512 + lane * 8) = *(const v8s*)src;
  }
  {  // K fragment ks = f
    const u16* src = qkv + (size_t)(b * 2048 + tile * 32 + l31) * 1536 + 512 + h * 64 + f * 16 + hi * 8;
    *(v8s*)(outb + (size_t)f * 512 + lane * 8) = *(const v8s*)src;
  }
  __syncthreads();
  {  // V^T fragment f: d = (f>>1)*32 + l31, t_off = (f&1)*16 + hi*8 + j
    int d = ((f >> 1) << 5) + l31;
    int tbase = ((f & 1) << 4) + hi * 8;
    v8s v;
#pragma unroll
    for (int j = 0; j < 8; ++j) v[j] = (short)Lv[(tbase + j) * 72 + d];
    *(v8s*)(outb + (size_t)(4 + f) * 512 + lane * 8) = v;
  }
}

// ---------------------------------------------------------------------------
// Flash attention, swapped-operand 32x32 bf16 MFMA, fragment-packed Q/K/V,
// k-split x2, MFMA l-sum. grid (16 qgroups, 32 bh, 2 k-halves), 4 waves.
// Writes normalized bf16 partials + (m,l) per (z, row, head).
// ---------------------------------------------------------------------------
__global__ __launch_bounds__(256) void attn32(
    const u16* __restrict__ kvqp, u16* __restrict__ opart, float* __restrict__ ml) {
  const int tid = threadIdx.x;
  const int lane = tid & 63;
  const int wv = tid >> 6;
  const int l31 = lane & 31;
  const int hi = lane >> 5;
  const int bh = blockIdx.y;
  const int z = blockIdx.z;
  const int b = bh >> 3, h = bh & 7;
  const int qt = blockIdx.x * 4 + wv;
  const int q0 = qt << 5;

  v8s qf[4];
  {
    const u16* qb = kvqp + ((size_t)(bh * 64 + qt)) * 6144 + lane * 8;
#pragma unroll
    for (int ks = 0; ks < 4; ++ks) qf[ks] = *(const v8s*)(qb + (8 + ks) * 512);
  }
  v16f o0 = {}, o1 = {}, lacc = {};
  float m_run = -INFINITY;

  const u16* kvb = kvqp + ((size_t)(bh * 64 + z * 32)) * 6144 + lane * 8;

  v8s kf[4], vf[4], kn[4], vn[4];
#pragma unroll
  for (int ks = 0; ks < 4; ++ks) kf[ks] = *(const v8s*)(kvb + ks * 512);
#pragma unroll
  for (int j = 0; j < 4; ++j) vf[j] = *(const v8s*)(kvb + (4 + j) * 512);

  v8s ones;
#pragma unroll
  for (int j = 0; j < 8; ++j) ones[j] = (short)0x3F80;  // bf16 1.0

  const float C = 0.18033688011112042f;  // 0.125 * log2(e)

  for (int t = 0; t < 32; ++t) {
    // S^T = K · Q
    __builtin_amdgcn_s_setprio(1);
    v16f sacc = {};
#pragma unroll
    for (int ks = 0; ks < 4; ++ks)
      sacc = __builtin_amdgcn_mfma_f32_32x32x16_bf16(kf[ks], qf[ks], sacc, 0, 0, 0);
    __builtin_amdgcn_s_setprio(0);

    // prefetch next tile (coalesced 1KB bursts)
    int tn = (t < 31) ? (t + 1) : 31;
    {
      const u16* kvt = kvb + (size_t)tn * 6144;
#pragma unroll
      for (int ks = 0; ks < 4; ++ks) kn[ks] = *(const v8s*)(kvt + ks * 512);
#pragma unroll
      for (int j = 0; j < 4; ++j) vn[j] = *(const v8s*)(kvt + (4 + j) * 512);
    }

    float s[16];
#pragma unroll
    for (int r = 0; r < 16; ++r) s[r] = sacc[r];
    // max via v_max3-friendly nesting
    float mx = fmaxf(fmaxf(s[0], s[1]), s[2]);
    mx = fmaxf(fmaxf(mx, s[3]), s[4]);
    mx = fmaxf(fmaxf(mx, s[5]), s[6]);
    mx = fmaxf(fmaxf(mx, s[7]), s[8]);
    mx = fmaxf(fmaxf(mx, s[9]), s[10]);
    mx = fmaxf(fmaxf(mx, s[11]), s[12]);
    mx = fmaxf(fmaxf(mx, s[13]), s[14]);
    mx = fmaxf(mx, s[15]);
    mx = fmaxf(mx, __shfl_xor(mx, 32));
    // defer-max: rescale only when the bound would exceed 2^8
    if (__any((mx - m_run) * C > 8.0f)) {
      float mn = fmaxf(m_run, mx);
      float corr = exp2f((m_run - mn) * C);
      m_run = mn;
      lacc[0] *= corr;
#pragma unroll
      for (int r = 0; r < 16; ++r) { o0[r] *= corr; o1[r] *= corr; }
    }
    float mnC = m_run * C;
#pragma unroll
    for (int r = 0; r < 16; ++r) s[r] = exp2f(fmaf(s[r], C, -mnC));

    // pack P to bf16 pairs, assemble B-fragments (P^T, col q = l31)
    unsigned pk[8], px[8];
#pragma unroll
    for (int g = 0; g < 8; ++g) {
      unsigned u;
      asm("v_cvt_pk_bf16_f32 %0, %1, %2" : "=v"(u) : "v"(s[2 * g]), "v"(s[2 * g + 1]));
      pk[g] = u;
      px[g] = (unsigned)__shfl_xor((int)u, 32);
    }
    v4i w0, w1;
    w0[0] = hi ? px[2] : pk[0];
    w0[1] = hi ? px[3] : pk[1];
    w0[2] = hi ? pk[2] : px[0];
    w0[3] = hi ? pk[3] : px[1];
    w1[0] = hi ? px[6] : pk[4];
    w1[1] = hi ? px[7] : pk[5];
    w1[2] = hi ? pk[6] : px[4];
    w1[3] = hi ? pk[7] : px[5];
    v8s pf0 = *(v8s*)&w0;
    v8s pf1 = *(v8s*)&w1;

    // O^T += V^T · P^T ; l += 1^T · P^T (MFMA on idle matrix pipe)
    __builtin_amdgcn_s_setprio(1);
    lacc = __builtin_amdgcn_mfma_f32_32x32x16_bf16(ones, pf0, lacc, 0, 0, 0);
    lacc = __builtin_amdgcn_mfma_f32_32x32x16_bf16(ones, pf1, lacc, 0, 0, 0);
    o0 = __builtin_amdgcn_mfma_f32_32x32x16_bf16(vf[0], pf0, o0, 0, 0, 0);
    o0 = __builtin_amdgcn_mfma_f32_32x32x16_bf16(vf[1], pf1, o0, 0, 0, 0);
    o1 = __builtin_amdgcn_mfma_f32_32x32x16_bf16(vf[2], pf0, o1, 0, 0, 0);
    o1 = __builtin_amdgcn_mfma_f32_32x32x16_bf16(vf[3], pf1, o1, 0, 0, 0);
    __builtin_amdgcn_s_setprio(0);

#pragma unroll
    for (int ks = 0; ks < 4; ++ks) { kf[ks] = kn[ks]; vf[ks] = vn[ks]; }
  }

  float l_run = lacc[0];
  float inv = 1.0f / l_run;
  u16* orow = opart + (size_t)z * 4194304 + (size_t)(b * 2048 + q0 + l31) * 512 + h * 64;
#pragma unroll
  for (int dt = 0; dt < 2; ++dt) {
#pragma unroll
    for (int g = 0; g < 8; ++g) {
      int d = dt * 32 + ((2 * g) & 3) + 8 * (g >> 1) + 4 * hi;
      float a = (dt ? o1[2 * g] : o0[2 * g]) * inv;
      float bv = (dt ? o1[2 * g + 1] : o0[2 * g + 1]) * inv;
      unsigned u;
      asm("v_cvt_pk_bf16_f32 %0, %1, %2" : "=v"(u) : "v"(a), "v"(bv));
      *(unsigned*)(orow + d) = u;
    }
  }
  if (hi == 0) {
    size_t mi = ((size_t)(z * 8192 + b * 2048 + q0 + l31) * 8 + h) * 2;
    ml[mi] = m_run;
    ml[mi + 1] = l_run;
  }
}

// ---------------------------------------------------------------------------
// Merge the two k-halves: attno = w0*O0 + w1*O1 (flash combine).
// ---------------------------------------------------------------------------
__global__ __launch_bounds__(256) void attn_merge(
    const u16* __restrict__ opart, const float* __restrict__ ml,
    u16* __restrict__ attno) {
  __shared__ float w0s[8], w1s[8];
  const int r = blockIdx.x, tid = threadIdx.x;
  if (tid < 8) {
    const float C = 0.18033688011112042f;
    size_t i0 = ((size_t)r * 8 + tid) * 2;
    size_t i1 = ((size_t)(8192 + r) * 8 + tid) * 2;
    float m0 = ml[i0], l0 = ml[i0 + 1];
    float m1 = ml[i1], l1 = ml[i1 + 1];
    float M = fmaxf(m0, m1);
    float a0 = exp2f((m0 - M) * C) * l0;
    float a1 = exp2f((m1 - M) * C) * l1;
    float inv = 1.0f / (a0 + a1);
    w0s[tid] = a0 * inv;
    w1s[tid] = a1 * inv;
  }
  __syncthreads();
  int c = tid * 2;
  unsigned p0 = *(const unsigned*)(opart + (size_t)r * 512 + c);
  unsigned p1 = *(const unsigned*)(opart + 4194304 + (size_t)r * 512 + c);
  int hh = c >> 6;
  float w0 = w0s[hh], w1 = w1s[hh];
  float x0 = bf2f((u16)p0) * w0 + bf2f((u16)p1) * w1;
  float x1 = bf2f((u16)(p0 >> 16)) * w0 + bf2f((u16)(p1 >> 16)) * w1;
  unsigned u;
  asm("v_cvt_pk_bf16_f32 %0, %1, %2" : "=v"(u) : "v"(x0), "v"(x1));
  *(unsigned*)(attno + (size_t)r * 512 + c) = u;
}

// ---------------------------------------------------------------------------
// Fused GLU + depthwise conv(K=31) + BN + snake. In: g3 bf16 [8192,1024]
// (a|g). Out: bf16 [8192,512]. Block: (chgroup 64, t-tile 128, batch).
// ---------------------------------------------------------------------------
__global__ __launch_bounds__(256) void dwconv_fused(
    const u16* __restrict__ g3, const float* __restrict__ dww,
    const float* __restrict__ dwb, const float* __restrict__ bng,
    const float* __restrict__ bnb, const float* __restrict__ bnm,
    const float* __restrict__ bnv, const float* __restrict__ la,
    const float* __restrict__ lb, u16* __restrict__ outp) {
  __shared__ float IN[160 * 64];
  __shared__ float WT[1984];
  __shared__ float PRM[4][64];
  const int tid = threadIdx.x;
  const int cg = blockIdx.x << 6;
  const int t0 = blockIdx.y << 7;
  const int bb = blockIdx.z;

  if (tid < 64) {
    int c = cg + tid;
    float sc = bng[c] / sqrtf(bnv[c] + 1e-5f);
    PRM[0][tid] = sc;
    PRM[1][tid] = (dwb[c] - bnm[c]) * sc + bnb[c];
    PRM[2][tid] = __expf(la[c]);
    PRM[3][tid] = 1.0f / (__expf(lb[c]) + 1e-9f);
  }
  for (int i = tid; i < 1984; i += 256) WT[i] = dww[cg * 31 + i];

#pragma unroll
  for (int p = 0; p < 5; ++p) {
    int r = p * 32 + (tid >> 3);
    int t = t0 - 16 + r;
    int c8 = (tid & 7) << 3;
    float4 lo = make_float4(0.f, 0.f, 0.f, 0.f);
    float4 hv = make_float4(0.f, 0.f, 0.f, 0.f);
    if (t >= 0 && t < 2048) {
      const u16* rp = g3 + ((size_t)(bb * 2048 + t)) * 1024 + cg + c8;
      v8s a8 = *(const v8s*)rp;
      v8s g8 = *(const v8s*)(rp + 512);
      float va[8];
#pragma unroll
      for (int j = 0; j < 8; ++j) {
        float fa = bf2f((u16)a8[j]);
        float fg = bf2f((u16)g8[j]);
        va[j] = fa / (1.f + __expf(-fg));
      }
      lo = make_float4(va[0], va[1], va[2], va[3]);
      hv = make_float4(va[4], va[5], va[6], va[7]);
    }
    *(float4*)&IN[r * 64 + c8] = lo;
    *(float4*)&IN[r * 64 + c8 + 4] = hv;
  }
  __syncthreads();

  const int ch = tid & 63;
  const int tg = tid >> 6;
  const float sc = PRM[0][ch], sh = PRM[1][ch], sa = PRM[2][ch], sib = PRM[3][ch];
  float w[31];
#pragma unroll
  for (int k = 0; k < 31; ++k) w[k] = WT[ch * 31 + k];

  for (int pass = 0; pass < 4; ++pass) {
    int tl = pass * 32 + tg * 8;
    float x[38];
#pragma unroll
    for (int i = 0; i < 38; ++i) x[i] = IN[(tl + 1 + i) * 64 + ch];
    float acc[8] = {0.f, 0.f, 0.f, 0.f, 0.f, 0.f, 0.f, 0.f};
#pragma unroll
    for (int k = 0; k < 31; ++k)
#pragma unroll
      for (int j = 0; j < 8; ++j) acc[j] = fmaf(x[k + j], w[k], acc[j]);
#pragma unroll
    for (int j = 0; j < 8; ++j) {
      float v = acc[j] * sc + sh;
      float s = __sinf(sa * v);
      v += s * s * sib;
      outp[((size_t)(bb * 2048 + t0 + tl + j)) * 512 + cg + ch] = f2bf(v);
    }
  }
}

// ---------------------------------------------------------------------------
extern "C" void kernel_launch(void* const* d_in, const int* in_sizes, int n_in,
                              void* d_out, int out_size, void* d_ws, size_t ws_size,
                              hipStream_t stream) {
  const float* x_in = (const float*)d_in[0];
  const float* ff1_norm_w = (const float*)d_in[1];
  const float* ff1_w1 = (const float*)d_in[2];
  const float* ff1_a = (const float*)d_in[3];
  const float* ff1_b = (const float*)d_in[4];
  const float* ff1_w2 = (const float*)d_in[5];
  const float* attn_norm_w = (const float*)d_in[6];
  const float* in_proj_w = (const float*)d_in[7];
  const float* in_proj_b = (const float*)d_in[8];
  const float* out_proj_w = (const float*)d_in[9];
  const float* out_proj_b = (const float*)d_in[10];
  const float* conv_norm_w = (const float*)d_in[11];
  const float* pw1_w = (const float*)d_in[12];
  const float* dw_w = (const float*)d_in[13];
  const float* dw_b = (const float*)d_in[14];
  const float* bn_g = (const float*)d_in[15];
  const float* bn_b = (const float*)d_in[16];
  const float* bn_m = (const float*)d_in[17];
  const float* bn_v = (const float*)d_in[18];
  const float* snake_a = (const float*)d_in[19];
  const float* snake_b = (const float*)d_in[20];
  const float* pw2_w = (const float*)d_in[21];
  const float* ff2_norm_w = (const float*)d_in[22];
  const float* ff2_w1 = (const float*)d_in[23];
  const float* ff2_a = (const float*)d_in[24];
  const float* ff2_b = (const float*)d_in[25];
  const float* ff2_w2 = (const float*)d_in[26];
  const float* final_norm_w = (const float*)d_in[27];
  float* out = (float*)d_out;

  char* ws = (char*)d_ws;
  float* x_cur = (float*)(ws + 0);                     // 16 MiB
  // attn phase:
  u16* qkv = (u16*)(ws + 16777216);                    // 24 MiB
  u16* kvqp = (u16*)(ws + 41943040);                   // 24 MiB (Q/K/V frags)
  u16* opart = (u16*)(ws + 67108864);                  // 16 MiB (2 x 8 MiB)
  u16* attno = (u16*)(ws + 88080384);                  // 8 MiB
  float* ml = (float*)(ws + 96468992);                 // 1 MiB
  // FFN phase:
  u16* h_b = (u16*)(ws + 16777216);                    // 32 MiB
  // conv phase:
  u16* g3b = (u16*)(ws + 16777216);                    // 16 MiB
  u16* convout = (u16*)(ws + 50331648);                // 8 MiB (bf16)
  signed char* a8a = (signed char*)(ws + 83886080);    // 4 MiB
  signed char* a8b = (signed char*)(ws + 88080384);    // 16 MiB (FFN phases)
  u16* xnb = (u16*)(ws + 104857600);                   // 8 MiB
  signed char* wq = (signed char*)(ws + 113246208);    // 4.75 MiB
  signed char* wq_w1 = wq;
  signed char* wq_w2 = wq + 1048576;
  signed char* wq_p1 = wq + 2097152;
  signed char* wq_p2 = wq + 2621440;
  signed char* wq_f21 = wq + 2883584;
  signed char* wq_f22 = wq + 3932160;
  u16* wb = (u16*)(ws + 118226944);                    // 2 MiB
  u16* wb_ip = wb;
  u16* wb_op = wb + 786432;
  float* scales = (float*)(ws + 120324096);
  float* partials = (float*)(ws + 120324352);
  float* ascale = (float*)(ws + 120325888);            // 32 KiB
  float* tabs = (float*)(ws + 120358912);              // 32 KiB

  // --- weight prep ---
  wabs_stage1<<<384, 256, 0, stream>>>(ff1_w1, ff1_w2, pw1_w, pw2_w, ff2_w1, ff2_w2, partials);
  wabs_stage2<<<1, 64, 0, stream>>>(partials, scales);
  wquant_all<<<dim3(128, 6), 256, 0, stream>>>(ff1_w1, ff1_w2, pw1_w, pw2_w, ff2_w1, ff2_w2,
                                               scales, wq);
  wcvt2<<<4096, 256, 0, stream>>>(in_proj_w, out_proj_w, wb);
  prep_tables<<<8, 256, 0, stream>>>(ff1_a, ff1_b, ff2_a, ff2_b, tabs);

  // --- FFN1: x_cur = x + 0.5*ffn(x) ---
  rmsnorm_multi<<<8192, 256, 0, stream>>>(x_in, ff1_norm_w, 1, nullptr, a8a, nullptr, ascale);
  gemm_i8_t<128, true><<<dim3(16, 64), 256, 0, stream>>>(
      a8a, wq_w1, scales + 0, ascale, nullptr, 1.0f, nullptr, h_b, 2048, 512);
  snake_q8<<<8192, 256, 0, stream>>>(h_b, tabs, tabs + 2048, a8b, ascale);
  gemm_i8_t<64, false><<<dim3(8, 64), 256, 0, stream>>>(
      a8b, wq_w2, scales + 1, ascale, x_in, 0.5f, x_cur, nullptr, 512, 2048);

  // --- MHA: x_cur += mha(x_cur) ---
  rmsnorm_multi<<<8192, 256, 0, stream>>>(x_cur, attn_norm_w, 2, nullptr, nullptr, xnb, nullptr);
  gemm_bf16_t<128, true><<<dim3(12, 64), 256, 0, stream>>>(
      xnb, wb_ip, in_proj_b, nullptr, nullptr, qkv, 1536, 512);
  kvqpack<<<dim3(64, 32), 256, 0, stream>>>(qkv, kvqp);
  attn32<<<dim3(16, 32, 2), 256, 0, stream>>>(kvqp, opart, ml);
  attn_merge<<<8192, 256, 0, stream>>>(opart, ml, attno);
  gemm_bf16_t<64, false><<<dim3(8, 64), 256, 0, stream>>>(
      attno, wb_op, out_proj_b, x_cur, x_cur, nullptr, 512, 512);

  // --- conv branch: x_cur += conv(x_cur) ---
  rmsnorm_multi<<<8192, 256, 0, stream>>>(x_cur, conv_norm_w, 1, nullptr, a8a, nullptr, ascale);
  gemm_i8_t<128, true><<<dim3(8, 64), 256, 0, stream>>>(
      a8a, wq_p1, scales + 2, ascale, nullptr, 1.0f, nullptr, g3b, 1024, 512);
  dwconv_fused<<<dim3(8, 16, 4), 256, 0, stream>>>(g3b, dw_w, dw_b, bn_g, bn_b, bn_m, bn_v,
                                                   snake_a, snake_b, convout);
  rowquant512_bf<<<8192, 256, 0, stream>>>(convout, a8a, ascale);
  gemm_i8_t<64, false><<<dim3(8, 64), 256, 0, stream>>>(
      a8a, wq_p2, scales + 3, ascale, x_cur, 1.0f, x_cur, nullptr, 512, 512);

  // --- FFN2: x_cur += 0.5*ffn(x_cur) ---
  rmsnorm_multi<<<8192, 256, 0, stream>>>(x_cur, ff2_norm_w, 1, nullptr, a8a, nullptr, ascale);
  gemm_i8_t<128, true><<<dim3(16, 64), 256, 0, stream>>>(
      a8a, wq_f21, scales + 4, ascale, nullptr, 1.0f, nullptr, h_b, 2048, 512);
  snake_q8<<<8192, 256, 0, stream>>>(h_b, tabs + 4096, tabs + 6144, a8b, ascale);
  gemm_i8_t<64, false><<<dim3(8, 64), 256, 0, stream>>>(
      a8b, wq_f22, scales + 5, ascale, x_cur, 0.5f, x_cur, nullptr, 512, 2048);

  // --- final rmsnorm -> out ---
  rmsnorm_multi<<<8192, 256, 0, stream>>>(x_cur, final_norm_w, 0, out, nullptr, nullptr, nullptr);
}

// Round 8
// 381.762 us; speedup vs baseline: 8.4586x; 1.0091x over previous
//
#include <hip/hip_runtime.h>
#include <math.h>

// ---------------------------------------------------------------------------
// ConformerBlock MFMA implementation.
// B=4, T=2048, D=512, H=8, hd=64, K=31.  M = B*T = 8192.
// Bitlinear GEMMs: int8 MFMA (exact). Attention/projections: bf16 MFMA.
// Attention: swapped-operand 32x32 MFMA, fragment-packed Q/K/V (coalesced),
// ping-pong unroll-2 k-loop, MFMA l-sum, k-split x2 + flash merge.
// ---------------------------------------------------------------------------

typedef int   v4i __attribute__((ext_vector_type(4)));
typedef float v4f __attribute__((ext_vector_type(4)));
typedef float v16f __attribute__((ext_vector_type(16)));
typedef short v8s __attribute__((ext_vector_type(8)));
typedef unsigned short u16;

#define GLOAD_LDS(g, l) __builtin_amdgcn_global_load_lds( \
    (const __attribute__((address_space(1))) void*)(g),   \
    (__attribute__((address_space(3))) void*)(l), 16, 0, 0)

__device__ __forceinline__ float blk_sum256(float v, float* sm) {
#pragma unroll
  for (int m = 32; m; m >>= 1) v += __shfl_xor(v, m);
  int w = threadIdx.x >> 6;
  __syncthreads();
  if ((threadIdx.x & 63) == 0) sm[w] = v;
  __syncthreads();
  return sm[0] + sm[1] + sm[2] + sm[3];
}

__device__ __forceinline__ float blk_max256(float v, float* sm) {
#pragma unroll
  for (int m = 32; m; m >>= 1) v = fmaxf(v, __shfl_xor(v, m));
  int w = threadIdx.x >> 6;
  __syncthreads();
  if ((threadIdx.x & 63) == 0) sm[w] = v;
  __syncthreads();
  return fmaxf(fmaxf(sm[0], sm[1]), fmaxf(sm[2], sm[3]));
}

__device__ __forceinline__ u16 f2bf(float f) {
  union { float f; unsigned u; } x;
  x.f = f;
  unsigned r = x.u + 0x7fffu + ((x.u >> 16) & 1u);
  return (u16)(r >> 16);
}

__device__ __forceinline__ float bf2f(u16 u) {
  union { unsigned u; float f; } x;
  x.u = ((unsigned)u) << 16;
  return x.f;
}

// ---------------------------------------------------------------------------
// Weight absmean (deterministic two-stage) + quantizers.
// ---------------------------------------------------------------------------
__global__ __launch_bounds__(256) void wabs_stage1(
    const float* __restrict__ w0, const float* __restrict__ w1,
    const float* __restrict__ w2, const float* __restrict__ w3,
    const float* __restrict__ w4, const float* __restrict__ w5,
    float* __restrict__ part) {
  __shared__ float sm[4];
  const float* ws[6] = {w0, w1, w2, w3, w4, w5};
  const int ns[6] = {1048576, 1048576, 524288, 262144, 1048576, 1048576};
  int widx = blockIdx.x >> 6;
  int chunk = blockIdx.x & 63;
  const float* w = ws[widx];
  int n = ns[widx];
  float s = 0.f;
  for (int i = chunk * 256 + threadIdx.x; i < n; i += 64 * 256) s += fabsf(w[i]);
  s = blk_sum256(s, sm);
  if (threadIdx.x == 0) part[widx * 64 + chunk] = s;
}

__global__ void wabs_stage2(const float* __restrict__ part, float* __restrict__ scales) {
  int t = threadIdx.x;
  if (t < 6) {
    const int ns[6] = {1048576, 1048576, 524288, 262144, 1048576, 1048576};
    float s = 0.f;
    for (int i = 0; i < 64; ++i) s += part[t * 64 + i];
    scales[t] = fmaxf(s / (float)ns[t], 1e-5f);  // wsc = clip(mean|w|,1e-5)
  }
}

__global__ __launch_bounds__(256) void wquant_all(
    const float* __restrict__ w0, const float* __restrict__ w1,
    const float* __restrict__ w2, const float* __restrict__ w3,
    const float* __restrict__ w4, const float* __restrict__ w5,
    const float* __restrict__ scales, signed char* __restrict__ out) {
  const float* ws[6] = {w0, w1, w2, w3, w4, w5};
  const int ns[6] = {1048576, 1048576, 524288, 262144, 1048576, 1048576};
  const int offs[6] = {0, 1048576, 2097152, 2621440, 2883584, 3932160};
  int widx = blockIdx.y;
  const float* w = ws[widx];
  int n = ns[widx];
  signed char* o = out + offs[widx];
  float s = 1.0f / scales[widx];
  for (int i = blockIdx.x * 256 + threadIdx.x; i < n; i += 128 * 256)
    o[i] = (signed char)(int)fminf(fmaxf(rintf(w[i] * s), -1.f), 1.f);
}

__global__ __launch_bounds__(256) void wcvt2(
    const float* __restrict__ ip, const float* __restrict__ op, u16* __restrict__ wb) {
  int i = blockIdx.x * 256 + threadIdx.x;  // 1048576 total
  if (i < 786432) wb[i] = f2bf(ip[i]);
  else wb[i] = f2bf(op[i - 786432]);
}

// snake tables: exp(la), 1/(exp(lb)+1e-9) for ff1 and ff2 (2048 each).
__global__ void prep_tables(
    const float* __restrict__ a1, const float* __restrict__ b1,
    const float* __restrict__ a2, const float* __restrict__ b2,
    float* __restrict__ tabs) {
  int i = blockIdx.x * 256 + threadIdx.x;
  if (i < 2048) {
    tabs[i] = __expf(a1[i]);
    tabs[2048 + i] = 1.0f / (__expf(b1[i]) + 1e-9f);
    tabs[4096 + i] = __expf(a2[i]);
    tabs[6144 + i] = 1.0f / (__expf(b2[i]) + 1e-9f);
  }
}

// ---------------------------------------------------------------------------
// RMSNorm: mode 0 = f32 out, 1 = int8-quant out + dq, 2 = bf16 out.
// ---------------------------------------------------------------------------
__global__ __launch_bounds__(256) void rmsnorm_multi(
    const float* __restrict__ x, const float* __restrict__ w, int mode,
    float* __restrict__ outf, signed char* __restrict__ out8,
    u16* __restrict__ outb, float* __restrict__ dq) {
  __shared__ float sm[4];
  int row = blockIdx.x, tid = threadIdx.x;
  const float* xr = x + (size_t)row * 512;
  float v0 = xr[tid], v1 = xr[tid + 256];
  float ss = blk_sum256(v0 * v0 + v1 * v1, sm);
  float sc = 1.0f / sqrtf(ss * (1.0f / 512.0f) + 1e-6f);
  float y0 = v0 * sc * w[tid];
  float y1 = v1 * sc * w[tid + 256];
  size_t o = (size_t)row * 512 + tid;
  if (mode == 0) {
    outf[o] = y0; outf[o + 256] = y1;
  } else if (mode == 1) {
    float am = blk_max256(fmaxf(fabsf(y0), fabsf(y1)), sm);
    float amc = fmaxf(am, 1e-5f);
    float s = 127.0f / amc;
    out8[o] = (signed char)(int)rintf(y0 * s);
    out8[o + 256] = (signed char)(int)rintf(y1 * s);
    if (tid == 0) dq[row] = amc * (1.0f / 127.0f);
  } else {
    outb[o] = f2bf(y0); outb[o + 256] = f2bf(y1);
  }
}

// ---------------------------------------------------------------------------
// snake_beta + int8 act-quant over bf16 rows of 2048, with exp tables.
// ---------------------------------------------------------------------------
__global__ __launch_bounds__(256) void snake_q8(
    const u16* __restrict__ h, const float* __restrict__ ta, const float* __restrict__ tb,
    signed char* __restrict__ out, float* __restrict__ dq) {
  __shared__ float sm[4];
  int row = blockIdx.x, tid = threadIdx.x;
  const u16* hr = h + (size_t)row * 2048;
  int c0 = tid * 8;
  v8s hv = *(const v8s*)(hr + c0);
  float4 ta0 = *(const float4*)(ta + c0);
  float4 ta1 = *(const float4*)(ta + c0 + 4);
  float4 tb0 = *(const float4*)(tb + c0);
  float4 tb1 = *(const float4*)(tb + c0 + 4);
  float sa[8] = {ta0.x, ta0.y, ta0.z, ta0.w, ta1.x, ta1.y, ta1.z, ta1.w};
  float sib[8] = {tb0.x, tb0.y, tb0.z, tb0.w, tb1.x, tb1.y, tb1.z, tb1.w};
  float vals[8];
  float am = 0.f;
#pragma unroll
  for (int j = 0; j < 8; ++j) {
    float v = bf2f((u16)hv[j]);
    float s = __sinf(sa[j] * v);
    v += s * s * sib[j];
    vals[j] = v;
    am = fmaxf(am, fabsf(v));
  }
  am = blk_max256(am, sm);
  float amc = fmaxf(am, 1e-5f);
  float s = 127.0f / amc;
  unsigned long long pkt = 0;
#pragma unroll
  for (int j = 0; j < 8; ++j) {
    int q = (int)rintf(vals[j] * s);
    pkt |= ((unsigned long long)(unsigned char)(signed char)q) << (8 * j);
  }
  *(unsigned long long*)(out + (size_t)row * 2048 + c0) = pkt;
  if (tid == 0) dq[row] = amc * (1.0f / 127.0f);
}

// ---------------------------------------------------------------------------
// Per-token int8 quant of a [M,512] bf16 buffer.
// ---------------------------------------------------------------------------
__global__ __launch_bounds__(256) void rowquant512_bf(
    const u16* __restrict__ in, signed char* __restrict__ out, float* __restrict__ dq) {
  __shared__ float sm[4];
  int row = blockIdx.x, tid = threadIdx.x;
  unsigned pv = *(const unsigned*)(in + (size_t)row * 512 + tid * 2);
  float v0 = bf2f((u16)pv), v1 = bf2f((u16)(pv >> 16));
  float am = blk_max256(fmaxf(fabsf(v0), fabsf(v1)), sm);
  float amc = fmaxf(am, 1e-5f);
  float s = 127.0f / amc;
  signed char q0 = (signed char)(int)rintf(v0 * s);
  signed char q1 = (signed char)(int)rintf(v1 * s);
  unsigned short pk = (unsigned short)((unsigned char)q0 | ((unsigned)(unsigned char)q1 << 8));
  *(unsigned short*)(out + (size_t)row * 512 + tid * 2) = pk;
  if (tid == 0) dq[row] = amc * (1.0f / 127.0f);
}

// ---------------------------------------------------------------------------
// int8 GEMM: acc = (A i8[M,K] @ B i8[N,K]^T) * wsc * dq[m].
// 128xBN tile, BK=64, 4 waves (2x2), JF = BN/32 j-frags per wave.
// OBF: write bf16; else f32 (+resid).
// ---------------------------------------------------------------------------
template <int BN, bool OBF>
__global__ __launch_bounds__(256) void gemm_i8_t(
    const signed char* __restrict__ A, const signed char* __restrict__ B,
    const float* __restrict__ wsp, const float* __restrict__ adq,
    const float* __restrict__ resid, float rscale,
    float* __restrict__ outf, u16* __restrict__ outb, int N, int K) {
  constexpr int JF = BN / 32;  // j-fragments per wave (wave covers 16*JF cols)
  __shared__ signed char As[8192];
  __shared__ signed char Bs[BN * 64];
  const int tid = threadIdx.x;
  const int m0 = blockIdx.y << 7;
  const int n0 = blockIdx.x * BN;
  const int lane = tid & 63;
  const int wv = tid >> 6;
  const int wr = (wv >> 1) << 6, wc = (wv & 1) * (16 * JF);
  const int r15 = lane & 15, khi = lane >> 4;
  const int srow = tid >> 2;
  const int sslot = (tid & 3) ^ ((srow >> 1) & 3);
  const signed char* Ag = A + (size_t)(m0 + srow) * K + sslot * 16;
  const signed char* Bg = B + (size_t)(n0 + srow) * K + sslot * 16;
  const size_t half = (size_t)64 * K;

  int aoff[4], boff[JF];
#pragma unroll
  for (int i = 0; i < 4; ++i) {
    int r = wr + i * 16 + r15;
    aoff[i] = r * 64 + ((khi ^ ((r >> 1) & 3)) << 4);
  }
#pragma unroll
  for (int j = 0; j < JF; ++j) {
    int c = wc + j * 16 + r15;
    boff[j] = c * 64 + ((khi ^ ((c >> 1) & 3)) << 4);
  }
  v4i acc[4][JF] = {};
  for (int k0 = 0; k0 < K; k0 += 64) {
    __syncthreads();
    GLOAD_LDS(Ag + k0, As + tid * 16);
    GLOAD_LDS(Ag + half + k0, As + 4096 + tid * 16);
    GLOAD_LDS(Bg + k0, Bs + tid * 16);
    if constexpr (BN == 128) GLOAD_LDS(Bg + half + k0, Bs + 4096 + tid * 16);
    __syncthreads();
    v4i a[4], b[JF];
#pragma unroll
    for (int i = 0; i < 4; ++i) a[i] = *(const v4i*)(As + aoff[i]);
#pragma unroll
    for (int j = 0; j < JF; ++j) b[j] = *(const v4i*)(Bs + boff[j]);
#pragma unroll
    for (int i = 0; i < 4; ++i)
#pragma unroll
      for (int j = 0; j < JF; ++j)
        acc[i][j] = __builtin_amdgcn_mfma_i32_16x16x64_i8(a[i], b[j], acc[i][j], 0, 0, 0);
  }
  const float wsc = *wsp;
#pragma unroll
  for (int i = 0; i < 4; ++i) {
    int rb = m0 + wr + i * 16 + (khi << 2);
    float dqv[4];
#pragma unroll
    for (int rr = 0; rr < 4; ++rr) dqv[rr] = adq[rb + rr] * wsc;
#pragma unroll
    for (int j = 0; j < JF; ++j) {
      int col = n0 + wc + j * 16 + r15;
#pragma unroll
      for (int rr = 0; rr < 4; ++rr) {
        size_t idx = (size_t)(rb + rr) * N + col;
        float v = (float)acc[i][j][rr] * dqv[rr];
        if constexpr (OBF) outb[idx] = f2bf(v);
        else outf[idx] = resid ? fmaf(rscale, v, resid[idx]) : v;
      }
    }
  }
}

// ---------------------------------------------------------------------------
// bf16 GEMM: acc = A bf16[M,K] @ B bf16[N,K]^T + bias. OBF: bf16 out, else
// f32 resid+acc.
// ---------------------------------------------------------------------------
template <int BN, bool OBF>
__global__ __launch_bounds__(256) void gemm_bf16_t(
    const u16* __restrict__ A, const u16* __restrict__ B,
    const float* __restrict__ bias, const float* __restrict__ resid,
    float* __restrict__ outf, u16* __restrict__ outb, int N, int K) {
  constexpr int JF = BN / 32;
  __shared__ signed char As[8192];
  __shared__ signed char Bs[BN * 64];
  const int tid = threadIdx.x;
  const int m0 = blockIdx.y << 7;
  const int n0 = blockIdx.x * BN;
  const int lane = tid & 63;
  const int wv = tid >> 6;
  const int wr = (wv >> 1) << 6, wc = (wv & 1) * (16 * JF);
  const int r15 = lane & 15, khi = lane >> 4;
  const int srow = tid >> 2;
  const int sslot = (tid & 3) ^ ((srow >> 1) & 3);
  const int K2 = K * 2;
  const signed char* Ag = (const signed char*)A + (size_t)(m0 + srow) * K2 + sslot * 16;
  const signed char* Bg = (const signed char*)B + (size_t)(n0 + srow) * K2 + sslot * 16;
  const size_t half = (size_t)64 * K2;

  int aoff[4], boff[JF];
#pragma unroll
  for (int i = 0; i < 4; ++i) {
    int r = wr + i * 16 + r15;
    aoff[i] = r * 64 + ((khi ^ ((r >> 1) & 3)) << 4);
  }
#pragma unroll
  for (int j = 0; j < JF; ++j) {
    int c = wc + j * 16 + r15;
    boff[j] = c * 64 + ((khi ^ ((c >> 1) & 3)) << 4);
  }
  v4f acc[4][JF] = {};
  for (int kb = 0; kb < K2; kb += 64) {
    __syncthreads();
    GLOAD_LDS(Ag + kb, As + tid * 16);
    GLOAD_LDS(Ag + half + kb, As + 4096 + tid * 16);
    GLOAD_LDS(Bg + kb, Bs + tid * 16);
    if constexpr (BN == 128) GLOAD_LDS(Bg + half + kb, Bs + 4096 + tid * 16);
    __syncthreads();
    v8s a[4], b[JF];
#pragma unroll
    for (int i = 0; i < 4; ++i) a[i] = *(const v8s*)(As + aoff[i]);
#pragma unroll
    for (int j = 0; j < JF; ++j) b[j] = *(const v8s*)(Bs + boff[j]);
#pragma unroll
    for (int i = 0; i < 4; ++i)
#pragma unroll
      for (int j = 0; j < JF; ++j)
        acc[i][j] = __builtin_amdgcn_mfma_f32_16x16x32_bf16(a[i], b[j], acc[i][j], 0, 0, 0);
  }
#pragma unroll
  for (int i = 0; i < 4; ++i) {
    int rb = m0 + wr + i * 16 + (khi << 2);
#pragma unroll
    for (int j = 0; j < JF; ++j) {
      int col = n0 + wc + j * 16 + r15;
      float bv = bias[col];
#pragma unroll
      for (int rr = 0; rr < 4; ++rr) {
        size_t idx = (size_t)(rb + rr) * N + col;
        float v = acc[i][j][rr] + bv;
        if constexpr (OBF) outb[idx] = f2bf(v);
        else outf[idx] = resid[idx] + v;
      }
    }
  }
}

// ---------------------------------------------------------------------------
// Q/K/V fragment pack: kvqp[bh][tile(64)][frag(12)][lane(64)] 16B chunks.
// frag 0..3 = K, 4..7 = V^T (via LDS transpose), 8..11 = Q.
// ---------------------------------------------------------------------------
__global__ __launch_bounds__(256) void kvqpack(
    const u16* __restrict__ qkv, u16* __restrict__ kvqp) {
  __shared__ u16 Lv[32 * 72];  // V rows [t=32][d=64] padded to 72
  const int tid = threadIdx.x;
  const int tile = blockIdx.x;  // 0..63
  const int bh = blockIdx.y;    // 0..31
  const int b = bh >> 3, h = bh & 7;
  u16* outb = kvqp + ((size_t)(bh * 64 + tile)) * 6144;
  const int lane = tid & 63, f = tid >> 6;  // f in 0..3
  const int l31 = lane & 31, hi = lane >> 5;

  // stage V rows into LDS (coalesced)
  {
    int r = tid >> 3, c = (tid & 7) << 3;
    const u16* src = qkv + (size_t)(b * 2048 + tile * 32 + r) * 1536 + 1024 + h * 64 + c;
    *(v8s*)(&Lv[r * 72 + c]) = *(const v8s*)src;
  }
  {  // Q fragment ks = f
    const u16* src = qkv + (size_t)(b * 2048 + tile * 32 + l31) * 1536 + h * 64 + f * 16 + hi * 8;
    *(v8s*)(outb + (size_t)(8 + f) * 512 + lane * 8) = *(const v8s*)src;
  }
  {  // K fragment ks = f
    const u16* src = qkv + (size_t)(b * 2048 + tile * 32 + l31) * 1536 + 512 + h * 64 + f * 16 + hi * 8;
    *(v8s*)(outb + (size_t)f * 512 + lane * 8) = *(const v8s*)src;
  }
  __syncthreads();
  {  // V^T fragment f: d = (f>>1)*32 + l31, t_off = (f&1)*16 + hi*8 + j
    int d = ((f >> 1) << 5) + l31;
    int tbase = ((f & 1) << 4) + hi * 8;
    v8s v;
#pragma unroll
    for (int j = 0; j < 8; ++j) v[j] = (short)Lv[(tbase + j) * 72 + d];
    *(v8s*)(outb + (size_t)(4 + f) * 512 + lane * 8) = v;
  }
}

// ---------------------------------------------------------------------------
// One attention k-tile step: QK^T MFMA, prefetch (into KN/VN via running
// pointer), online softmax, P-pack, PV + l-sum MFMAs.
// ---------------------------------------------------------------------------
__device__ __forceinline__ void attn_step(
    v8s (&kf)[4], v8s (&vf)[4], v8s (&kn)[4], v8s (&vn)[4],
    const v8s (&qf)[4], const u16*& pf, v16f& o0, v16f& o1, v16f& lacc,
    float& m_run, const v8s& ones, int hi) {
  const float C = 0.18033688011112042f;  // 0.125 * log2(e)
  __builtin_amdgcn_s_setprio(1);
  v16f sacc = {};
#pragma unroll
  for (int ks = 0; ks < 4; ++ks)
    sacc = __builtin_amdgcn_mfma_f32_32x32x16_bf16(kf[ks], qf[ks], sacc, 0, 0, 0);
  __builtin_amdgcn_s_setprio(0);

  // prefetch next tile via running pointer (constant fold-able offsets)
#pragma unroll
  for (int ks = 0; ks < 4; ++ks) kn[ks] = *(const v8s*)(pf + ks * 512);
#pragma unroll
  for (int j = 0; j < 4; ++j) vn[j] = *(const v8s*)(pf + 2048 + j * 512);
  pf += 6144;

  float s[16];
#pragma unroll
  for (int r = 0; r < 16; ++r) s[r] = sacc[r];
  float mx = fmaxf(fmaxf(s[0], s[1]), s[2]);
  mx = fmaxf(fmaxf(mx, s[3]), s[4]);
  mx = fmaxf(fmaxf(mx, s[5]), s[6]);
  mx = fmaxf(fmaxf(mx, s[7]), s[8]);
  mx = fmaxf(fmaxf(mx, s[9]), s[10]);
  mx = fmaxf(fmaxf(mx, s[11]), s[12]);
  mx = fmaxf(fmaxf(mx, s[13]), s[14]);
  mx = fmaxf(mx, s[15]);
  mx = fmaxf(mx, __shfl_xor(mx, 32));
  // defer-max: rescale only when the bound would exceed 2^8
  if (__any((mx - m_run) * C > 8.0f)) {
    float mn = fmaxf(m_run, mx);
    float corr = exp2f((m_run - mn) * C);
    m_run = mn;
    lacc[0] *= corr;
#pragma unroll
    for (int r = 0; r < 16; ++r) { o0[r] *= corr; o1[r] *= corr; }
  }
  float mnC = m_run * C;
#pragma unroll
  for (int r = 0; r < 16; ++r) s[r] = exp2f(fmaf(s[r], C, -mnC));

  // pack P to bf16 pairs, assemble B-fragments (P^T, col q = l31)
  unsigned pk[8], px[8];
#pragma unroll
  for (int g = 0; g < 8; ++g) {
    unsigned u;
    asm("v_cvt_pk_bf16_f32 %0, %1, %2" : "=v"(u) : "v"(s[2 * g]), "v"(s[2 * g + 1]));
    pk[g] = u;
    px[g] = (unsigned)__shfl_xor((int)u, 32);
  }
  v4i w0, w1;
  w0[0] = hi ? px[2] : pk[0];
  w0[1] = hi ? px[3] : pk[1];
  w0[2] = hi ? pk[2] : px[0];
  w0[3] = hi ? pk[3] : px[1];
  w1[0] = hi ? px[6] : pk[4];
  w1[1] = hi ? px[7] : pk[5];
  w1[2] = hi ? pk[6] : px[4];
  w1[3] = hi ? pk[7] : px[5];
  v8s pf0 = *(v8s*)&w0;
  v8s pf1 = *(v8s*)&w1;

  // O^T += V^T · P^T ; l += 1^T · P^T (matrix pipe)
  __builtin_amdgcn_s_setprio(1);
  lacc = __builtin_amdgcn_mfma_f32_32x32x16_bf16(ones, pf0, lacc, 0, 0, 0);
  lacc = __builtin_amdgcn_mfma_f32_32x32x16_bf16(ones, pf1, lacc, 0, 0, 0);
  o0 = __builtin_amdgcn_mfma_f32_32x32x16_bf16(vf[0], pf0, o0, 0, 0, 0);
  o0 = __builtin_amdgcn_mfma_f32_32x32x16_bf16(vf[1], pf1, o0, 0, 0, 0);
  o1 = __builtin_amdgcn_mfma_f32_32x32x16_bf16(vf[2], pf0, o1, 0, 0, 0);
  o1 = __builtin_amdgcn_mfma_f32_32x32x16_bf16(vf[3], pf1, o1, 0, 0, 0);
  __builtin_amdgcn_s_setprio(0);
}

// ---------------------------------------------------------------------------
// Flash attention, swapped-operand 32x32 bf16 MFMA, fragment-packed Q/K/V,
// ping-pong unroll-2, k-split x2. grid (16 qgroups, 32 bh, 2 k-halves),
// 4 waves. Writes normalized bf16 partials + (m,l) per (z, row, head).
// ---------------------------------------------------------------------------
__global__ __launch_bounds__(256) void attn32(
    const u16* __restrict__ kvqp, u16* __restrict__ opart, float* __restrict__ ml) {
  const int tid = threadIdx.x;
  const int lane = tid & 63;
  const int wv = tid >> 6;
  const int l31 = lane & 31;
  const int hi = lane >> 5;
  const int bh = blockIdx.y;
  const int z = blockIdx.z;
  const int b = bh >> 3, h = bh & 7;
  const int qt = blockIdx.x * 4 + wv;
  const int q0 = qt << 5;

  v8s qf[4];
  {
    const u16* qb = kvqp + ((size_t)(bh * 64 + qt)) * 6144 + lane * 8;
#pragma unroll
    for (int ks = 0; ks < 4; ++ks) qf[ks] = *(const v8s*)(qb + (8 + ks) * 512);
  }
  v16f o0 = {}, o1 = {}, lacc = {};
  float m_run = -INFINITY;

  const u16* pf = kvqp + ((size_t)(bh * 64 + z * 32)) * 6144 + lane * 8;

  v8s kfA[4], vfA[4], kfB[4], vfB[4];
#pragma unroll
  for (int ks = 0; ks < 4; ++ks) kfA[ks] = *(const v8s*)(pf + ks * 512);
#pragma unroll
  for (int j = 0; j < 4; ++j) vfA[j] = *(const v8s*)(pf + 2048 + j * 512);
  pf += 6144;

  v8s ones;
#pragma unroll
  for (int j = 0; j < 8; ++j) ones[j] = (short)0x3F80;  // bf16 1.0

  // 32 tiles, ping-pong A/B (last prefetch reads 1 tile past half: harmless,
  // lands in opart region of d_ws, never consumed).
  for (int it = 0; it < 16; ++it) {
    attn_step(kfA, vfA, kfB, vfB, qf, pf, o0, o1, lacc, m_run, ones, hi);
    attn_step(kfB, vfB, kfA, vfA, qf, pf, o0, o1, lacc, m_run, ones, hi);
  }

  float l_run = lacc[0];
  float inv = 1.0f / l_run;
  u16* orow = opart + (size_t)z * 4194304 + (size_t)(b * 2048 + q0 + l31) * 512 + h * 64;
#pragma unroll
  for (int dt = 0; dt < 2; ++dt) {
#pragma unroll
    for (int g = 0; g < 8; ++g) {
      int d = dt * 32 + ((2 * g) & 3) + 8 * (g >> 1) + 4 * hi;
      float a = (dt ? o1[2 * g] : o0[2 * g]) * inv;
      float bv = (dt ? o1[2 * g + 1] : o0[2 * g + 1]) * inv;
      unsigned u;
      asm("v_cvt_pk_bf16_f32 %0, %1, %2" : "=v"(u) : "v"(a), "v"(bv));
      *(unsigned*)(orow + d) = u;
    }
  }
  if (hi == 0) {
    size_t mi = ((size_t)(z * 8192 + b * 2048 + q0 + l31) * 8 + h) * 2;
    ml[mi] = m_run;
    ml[mi + 1] = l_run;
  }
}

// ---------------------------------------------------------------------------
// Merge the two k-halves: attno = w0*O0 + w1*O1 (flash combine).
// ---------------------------------------------------------------------------
__global__ __launch_bounds__(256) void attn_merge(
    const u16* __restrict__ opart, const float* __restrict__ ml,
    u16* __restrict__ attno) {
  __shared__ float w0s[8], w1s[8];
  const int r = blockIdx.x, tid = threadIdx.x;
  if (tid < 8) {
    const float C = 0.18033688011112042f;
    size_t i0 = ((size_t)r * 8 + tid) * 2;
    size_t i1 = ((size_t)(8192 + r) * 8 + tid) * 2;
    float m0 = ml[i0], l0 = ml[i0 + 1];
    float m1 = ml[i1], l1 = ml[i1 + 1];
    float M = fmaxf(m0, m1);
    float a0 = exp2f((m0 - M) * C) * l0;
    float a1 = exp2f((m1 - M) * C) * l1;
    float inv = 1.0f / (a0 + a1);
    w0s[tid] = a0 * inv;
    w1s[tid] = a1 * inv;
  }
  __syncthreads();
  int c = tid * 2;
  unsigned p0 = *(const unsigned*)(opart + (size_t)r * 512 + c);
  unsigned p1 = *(const unsigned*)(opart + 4194304 + (size_t)r * 512 + c);
  int hh = c >> 6;
  float w0 = w0s[hh], w1 = w1s[hh];
  float x0 = bf2f((u16)p0) * w0 + bf2f((u16)p1) * w1;
  float x1 = bf2f((u16)(p0 >> 16)) * w0 + bf2f((u16)(p1 >> 16)) * w1;
  unsigned u;
  asm("v_cvt_pk_bf16_f32 %0, %1, %2" : "=v"(u) : "v"(x0), "v"(x1));
  *(unsigned*)(attno + (size_t)r * 512 + c) = u;
}

// ---------------------------------------------------------------------------
// Fused GLU + depthwise conv(K=31) + BN + snake. In: g3 bf16 [8192,1024]
// (a|g). Out: bf16 [8192,512]. Block: (chgroup 64, t-tile 128, batch).
// ---------------------------------------------------------------------------
__global__ __launch_bounds__(256) void dwconv_fused(
    const u16* __restrict__ g3, const float* __restrict__ dww,
    const float* __restrict__ dwb, const float* __restrict__ bng,
    const float* __restrict__ bnb, const float* __restrict__ bnm,
    const float* __restrict__ bnv, const float* __restrict__ la,
    const float* __restrict__ lb, u16* __restrict__ outp) {
  __shared__ float IN[160 * 64];
  __shared__ float WT[1984];
  __shared__ float PRM[4][64];
  const int tid = threadIdx.x;
  const int cg = blockIdx.x << 6;
  const int t0 = blockIdx.y << 7;
  const int bb = blockIdx.z;

  if (tid < 64) {
    int c = cg + tid;
    float sc = bng[c] / sqrtf(bnv[c] + 1e-5f);
    PRM[0][tid] = sc;
    PRM[1][tid] = (dwb[c] - bnm[c]) * sc + bnb[c];
    PRM[2][tid] = __expf(la[c]);
    PRM[3][tid] = 1.0f / (__expf(lb[c]) + 1e-9f);
  }
  for (int i = tid; i < 1984; i += 256) WT[i] = dww[cg * 31 + i];

#pragma unroll
  for (int p = 0; p < 5; ++p) {
    int r = p * 32 + (tid >> 3);
    int t = t0 - 16 + r;
    int c8 = (tid & 7) << 3;
    float4 lo = make_float4(0.f, 0.f, 0.f, 0.f);
    float4 hv = make_float4(0.f, 0.f, 0.f, 0.f);
    if (t >= 0 && t < 2048) {
      const u16* rp = g3 + ((size_t)(bb * 2048 + t)) * 1024 + cg + c8;
      v8s a8 = *(const v8s*)rp;
      v8s g8 = *(const v8s*)(rp + 512);
      float va[8];
#pragma unroll
      for (int j = 0; j < 8; ++j) {
        float fa = bf2f((u16)a8[j]);
        float fg = bf2f((u16)g8[j]);
        va[j] = fa / (1.f + __expf(-fg));
      }
      lo = make_float4(va[0], va[1], va[2], va[3]);
      hv = make_float4(va[4], va[5], va[6], va[7]);
    }
    *(float4*)&IN[r * 64 + c8] = lo;
    *(float4*)&IN[r * 64 + c8 + 4] = hv;
  }
  __syncthreads();

  const int ch = tid & 63;
  const int tg = tid >> 6;
  const float sc = PRM[0][ch], sh = PRM[1][ch], sa = PRM[2][ch], sib = PRM[3][ch];
  float w[31];
#pragma unroll
  for (int k = 0; k < 31; ++k) w[k] = WT[ch * 31 + k];

  for (int pass = 0; pass < 4; ++pass) {
    int tl = pass * 32 + tg * 8;
    float x[38];
#pragma unroll
    for (int i = 0; i < 38; ++i) x[i] = IN[(tl + 1 + i) * 64 + ch];
    float acc[8] = {0.f, 0.f, 0.f, 0.f, 0.f, 0.f, 0.f, 0.f};
#pragma unroll
    for (int k = 0; k < 31; ++k)
#pragma unroll
      for (int j = 0; j < 8; ++j) acc[j] = fmaf(x[k + j], w[k], acc[j]);
#pragma unroll
    for (int j = 0; j < 8; ++j) {
      float v = acc[j] * sc + sh;
      float s = __sinf(sa * v);
      v += s * s * sib;
      outp[((size_t)(bb * 2048 + t0 + tl + j)) * 512 + cg + ch] = f2bf(v);
    }
  }
}

// ---------------------------------------------------------------------------
extern "C" void kernel_launch(void* const* d_in, const int* in_sizes, int n_in,
                              void* d_out, int out_size, void* d_ws, size_t ws_size,
                              hipStream_t stream) {
  const float* x_in = (const float*)d_in[0];
  const float* ff1_norm_w = (const float*)d_in[1];
  const float* ff1_w1 = (const float*)d_in[2];
  const float* ff1_a = (const float*)d_in[3];
  const float* ff1_b = (const float*)d_in[4];
  const float* ff1_w2 = (const float*)d_in[5];
  const float* attn_norm_w = (const float*)d_in[6];
  const float* in_proj_w = (const float*)d_in[7];
  const float* in_proj_b = (const float*)d_in[8];
  const float* out_proj_w = (const float*)d_in[9];
  const float* out_proj_b = (const float*)d_in[10];
  const float* conv_norm_w = (const float*)d_in[11];
  const float* pw1_w = (const float*)d_in[12];
  const float* dw_w = (const float*)d_in[13];
  const float* dw_b = (const float*)d_in[14];
  const float* bn_g = (const float*)d_in[15];
  const float* bn_b = (const float*)d_in[16];
  const float* bn_m = (const float*)d_in[17];
  const float* bn_v = (const float*)d_in[18];
  const float* snake_a = (const float*)d_in[19];
  const float* snake_b = (const float*)d_in[20];
  const float* pw2_w = (const float*)d_in[21];
  const float* ff2_norm_w = (const float*)d_in[22];
  const float* ff2_w1 = (const float*)d_in[23];
  const float* ff2_a = (const float*)d_in[24];
  const float* ff2_b = (const float*)d_in[25];
  const float* ff2_w2 = (const float*)d_in[26];
  const float* final_norm_w = (const float*)d_in[27];
  float* out = (float*)d_out;

  char* ws = (char*)d_ws;
  float* x_cur = (float*)(ws + 0);                     // 16 MiB
  // attn phase:
  u16* qkv = (u16*)(ws + 16777216);                    // 24 MiB
  u16* kvqp = (u16*)(ws + 41943040);                   // 24 MiB (Q/K/V frags)
  u16* opart = (u16*)(ws + 67108864);                  // 16 MiB (2 x 8 MiB)
  u16* attno = (u16*)(ws + 88080384);                  // 8 MiB
  float* ml = (float*)(ws + 96468992);                 // 1 MiB
  // FFN phase:
  u16* h_b = (u16*)(ws + 16777216);                    // 32 MiB
  // conv phase:
  u16* g3b = (u16*)(ws + 16777216);                    // 16 MiB
  u16* convout = (u16*)(ws + 50331648);                // 8 MiB (bf16)
  signed char* a8a = (signed char*)(ws + 83886080);    // 4 MiB
  signed char* a8b = (signed char*)(ws + 88080384);    // 16 MiB (FFN phases)
  u16* xnb = (u16*)(ws + 104857600);                   // 8 MiB
  signed char* wq = (signed char*)(ws + 113246208);    // 4.75 MiB
  signed char* wq_w1 = wq;
  signed char* wq_w2 = wq + 1048576;
  signed char* wq_p1 = wq + 2097152;
  signed char* wq_p2 = wq + 2621440;
  signed char* wq_f21 = wq + 2883584;
  signed char* wq_f22 = wq + 3932160;
  u16* wb = (u16*)(ws + 118226944);                    // 2 MiB
  u16* wb_ip = wb;
  u16* wb_op = wb + 786432;
  float* scales = (float*)(ws + 120324096);
  float* partials = (float*)(ws + 120324352);
  float* ascale = (float*)(ws + 120325888);            // 32 KiB
  float* tabs = (float*)(ws + 120358912);              // 32 KiB

  // --- weight prep ---
  wabs_stage1<<<384, 256, 0, stream>>>(ff1_w1, ff1_w2, pw1_w, pw2_w, ff2_w1, ff2_w2, partials);
  wabs_stage2<<<1, 64, 0, stream>>>(partials, scales);
  wquant_all<<<dim3(128, 6), 256, 0, stream>>>(ff1_w1, ff1_w2, pw1_w, pw2_w, ff2_w1, ff2_w2,
                                               scales, wq);
  wcvt2<<<4096, 256, 0, stream>>>(in_proj_w, out_proj_w, wb);
  prep_tables<<<8, 256, 0, stream>>>(ff1_a, ff1_b, ff2_a, ff2_b, tabs);

  // --- FFN1: x_cur = x + 0.5*ffn(x) ---
  rmsnorm_multi<<<8192, 256, 0, stream>>>(x_in, ff1_norm_w, 1, nullptr, a8a, nullptr, ascale);
  gemm_i8_t<128, true><<<dim3(16, 64), 256, 0, stream>>>(
      a8a, wq_w1, scales + 0, ascale, nullptr, 1.0f, nullptr, h_b, 2048, 512);
  snake_q8<<<8192, 256, 0, stream>>>(h_b, tabs, tabs + 2048, a8b, ascale);
  gemm_i8_t<64, false><<<dim3(8, 64), 256, 0, stream>>>(
      a8b, wq_w2, scales + 1, ascale, x_in, 0.5f, x_cur, nullptr, 512, 2048);

  // --- MHA: x_cur += mha(x_cur) ---
  rmsnorm_multi<<<8192, 256, 0, stream>>>(x_cur, attn_norm_w, 2, nullptr, nullptr, xnb, nullptr);
  gemm_bf16_t<128, true><<<dim3(12, 64), 256, 0, stream>>>(
      xnb, wb_ip, in_proj_b, nullptr, nullptr, qkv, 1536, 512);
  kvqpack<<<dim3(64, 32), 256, 0, stream>>>(qkv, kvqp);
  attn32<<<dim3(16, 32, 2), 256, 0, stream>>>(kvqp, opart, ml);
  attn_merge<<<8192, 256, 0, stream>>>(opart, ml, attno);
  gemm_bf16_t<64, false><<<dim3(8, 64), 256, 0, stream>>>(
      attno, wb_op, out_proj_b, x_cur, x_cur, nullptr, 512, 512);

  // --- conv branch: x_cur += conv(x_cur) ---
  rmsnorm_multi<<<8192, 256, 0, stream>>>(x_cur, conv_norm_w, 1, nullptr, a8a, nullptr, ascale);
  gemm_i8_t<128, true><<<dim3(8, 64), 256, 0, stream>>>(
      a8a, wq_p1, scales + 2, ascale, nullptr, 1.0f, nullptr, g3b, 1024, 512);
  dwconv_fused<<<dim3(8, 16, 4), 256, 0, stream>>>(g3b, dw_w, dw_b, bn_g, bn_b, bn_m, bn_v,
                                                   snake_a, snake_b, convout);
  rowquant512_bf<<<8192, 256, 0, stream>>>(convout, a8a, ascale);
  gemm_i8_t<64, false><<<dim3(8, 64), 256, 0, stream>>>(
      a8a, wq_p2, scales + 3, ascale, x_cur, 1.0f, x_cur, nullptr, 512, 512);

  // --- FFN2: x_cur += 0.5*ffn(x_cur) ---
  rmsnorm_multi<<<8192, 256, 0, stream>>>(x_cur, ff2_norm_w, 1, nullptr, a8a, nullptr, ascale);
  gemm_i8_t<128, true><<<dim3(16, 64), 256, 0, stream>>>(
      a8a, wq_f21, scales + 4, ascale, nullptr, 1.0f, nullptr, h_b, 2048, 512);
  snake_q8<<<8192, 256, 0, stream>>>(h_b, tabs + 4096, tabs + 6144, a8b, ascale);
  gemm_i8_t<64, false><<<dim3(8, 64), 256, 0, stream>>>(
      a8b, wq_f22, scales + 5, ascale, x_cur, 0.5f, x_cur, nullptr, 512, 2048);

  // --- final rmsnorm -> out ---
  rmsnorm_multi<<<8192, 256, 0, stream>>>(x_cur, final_norm_w, 0, out, nullptr, nullptr, nullptr);
}

// Round 9
// 378.901 us; speedup vs baseline: 8.5225x; 1.0076x over previous
//
#include <hip/hip_runtime.h>
#include <math.h>

// ---------------------------------------------------------------------------
// ConformerBlock MFMA implementation.
// B=4, T=2048, D=512, H=8, hd=64, K=31.  M = B*T = 8192.
// Bitlinear GEMMs: int8 MFMA (exact). Attention/projections: bf16 MFMA.
// Attention: swapped-operand 32x32 MFMA, fragment-packed Q/K/V, ping-pong
// unroll-2, permlane32 cross-half, k-split x4 + flash merge.
// ---------------------------------------------------------------------------

typedef int   v4i __attribute__((ext_vector_type(4)));
typedef float v4f __attribute__((ext_vector_type(4)));
typedef float v16f __attribute__((ext_vector_type(16)));
typedef short v8s __attribute__((ext_vector_type(8)));
typedef unsigned short u16;

#define GLOAD_LDS(g, l) __builtin_amdgcn_global_load_lds( \
    (const __attribute__((address_space(1))) void*)(g),   \
    (__attribute__((address_space(3))) void*)(l), 16, 0, 0)

__device__ __forceinline__ float blk_sum256(float v, float* sm) {
#pragma unroll
  for (int m = 32; m; m >>= 1) v += __shfl_xor(v, m);
  int w = threadIdx.x >> 6;
  __syncthreads();
  if ((threadIdx.x & 63) == 0) sm[w] = v;
  __syncthreads();
  return sm[0] + sm[1] + sm[2] + sm[3];
}

__device__ __forceinline__ float blk_max256(float v, float* sm) {
#pragma unroll
  for (int m = 32; m; m >>= 1) v = fmaxf(v, __shfl_xor(v, m));
  int w = threadIdx.x >> 6;
  __syncthreads();
  if ((threadIdx.x & 63) == 0) sm[w] = v;
  __syncthreads();
  return fmaxf(fmaxf(sm[0], sm[1]), fmaxf(sm[2], sm[3]));
}

__device__ __forceinline__ u16 f2bf(float f) {
  union { float f; unsigned u; } x;
  x.f = f;
  unsigned r = x.u + 0x7fffu + ((x.u >> 16) & 1u);
  return (u16)(r >> 16);
}

__device__ __forceinline__ float bf2f(u16 u) {
  union { unsigned u; float f; } x;
  x.u = ((unsigned)u) << 16;
  return x.f;
}

// ---------------------------------------------------------------------------
// Weight absmean stage 1 + fused quantizers.
// ---------------------------------------------------------------------------
__global__ __launch_bounds__(256) void wabs_stage1(
    const float* __restrict__ w0, const float* __restrict__ w1,
    const float* __restrict__ w2, const float* __restrict__ w3,
    const float* __restrict__ w4, const float* __restrict__ w5,
    float* __restrict__ part) {
  __shared__ float sm[4];
  const float* ws[6] = {w0, w1, w2, w3, w4, w5};
  const int ns[6] = {1048576, 1048576, 524288, 262144, 1048576, 1048576};
  int widx = blockIdx.x >> 6;
  int chunk = blockIdx.x & 63;
  const float* w = ws[widx];
  int n = ns[widx];
  float s = 0.f;
  for (int i = chunk * 256 + threadIdx.x; i < n; i += 64 * 256) s += fabsf(w[i]);
  s = blk_sum256(s, sm);
  if (threadIdx.x == 0) part[widx * 64 + chunk] = s;
}

// stage2 folded in: every block recomputes the 64-partial sum for its widx.
__global__ __launch_bounds__(256) void wquant_all(
    const float* __restrict__ w0, const float* __restrict__ w1,
    const float* __restrict__ w2, const float* __restrict__ w3,
    const float* __restrict__ w4, const float* __restrict__ w5,
    const float* __restrict__ part, float* __restrict__ scales,
    signed char* __restrict__ out) {
  const float* ws[6] = {w0, w1, w2, w3, w4, w5};
  const int ns[6] = {1048576, 1048576, 524288, 262144, 1048576, 1048576};
  const int offs[6] = {0, 1048576, 2097152, 2621440, 2883584, 3932160};
  int widx = blockIdx.y;
  const float* w = ws[widx];
  int n = ns[widx];
  signed char* o = out + offs[widx];
  float ssum = 0.f;
#pragma unroll 8
  for (int i = 0; i < 64; ++i) ssum += part[widx * 64 + i];
  float wsc = fmaxf(ssum / (float)n, 1e-5f);
  if (blockIdx.x == 0 && threadIdx.x == 0) scales[widx] = wsc;
  float s = 1.0f / wsc;
  for (int i = blockIdx.x * 256 + threadIdx.x; i < n; i += 128 * 256)
    o[i] = (signed char)(int)fminf(fmaxf(rintf(w[i] * s), -1.f), 1.f);
}

// bf16 weight convert + snake exp tables in one launch.
__global__ __launch_bounds__(256) void wcvt_tabs(
    const float* __restrict__ ip, const float* __restrict__ op, u16* __restrict__ wb,
    const float* __restrict__ a1, const float* __restrict__ b1,
    const float* __restrict__ a2, const float* __restrict__ b2,
    float* __restrict__ tabs) {
  int bid = blockIdx.x;
  if (bid < 4096) {
    int i = bid * 256 + threadIdx.x;
    if (i < 786432) wb[i] = f2bf(ip[i]);
    else wb[i] = f2bf(op[i - 786432]);
  } else {
    int i = (bid - 4096) * 256 + threadIdx.x;
    if (i < 2048) {
      tabs[i] = __expf(a1[i]);
      tabs[2048 + i] = 1.0f / (__expf(b1[i]) + 1e-9f);
      tabs[4096 + i] = __expf(a2[i]);
      tabs[6144 + i] = 1.0f / (__expf(b2[i]) + 1e-9f);
    }
  }
}

// ---------------------------------------------------------------------------
// RMSNorm: mode 0 = f32 out, 1 = int8-quant out + dq, 2 = bf16 out.
// ---------------------------------------------------------------------------
__global__ __launch_bounds__(256) void rmsnorm_multi(
    const float* __restrict__ x, const float* __restrict__ w, int mode,
    float* __restrict__ outf, signed char* __restrict__ out8,
    u16* __restrict__ outb, float* __restrict__ dq) {
  __shared__ float sm[4];
  int row = blockIdx.x, tid = threadIdx.x;
  const float* xr = x + (size_t)row * 512;
  float v0 = xr[tid], v1 = xr[tid + 256];
  float ss = blk_sum256(v0 * v0 + v1 * v1, sm);
  float sc = 1.0f / sqrtf(ss * (1.0f / 512.0f) + 1e-6f);
  float y0 = v0 * sc * w[tid];
  float y1 = v1 * sc * w[tid + 256];
  size_t o = (size_t)row * 512 + tid;
  if (mode == 0) {
    outf[o] = y0; outf[o + 256] = y1;
  } else if (mode == 1) {
    float am = blk_max256(fmaxf(fabsf(y0), fabsf(y1)), sm);
    float amc = fmaxf(am, 1e-5f);
    float s = 127.0f / amc;
    out8[o] = (signed char)(int)rintf(y0 * s);
    out8[o + 256] = (signed char)(int)rintf(y1 * s);
    if (tid == 0) dq[row] = amc * (1.0f / 127.0f);
  } else {
    outb[o] = f2bf(y0); outb[o + 256] = f2bf(y1);
  }
}

// ---------------------------------------------------------------------------
// snake_beta + int8 act-quant over bf16 rows of 2048, with exp tables.
// ---------------------------------------------------------------------------
__global__ __launch_bounds__(256) void snake_q8(
    const u16* __restrict__ h, const float* __restrict__ ta, const float* __restrict__ tb,
    signed char* __restrict__ out, float* __restrict__ dq) {
  __shared__ float sm[4];
  int row = blockIdx.x, tid = threadIdx.x;
  const u16* hr = h + (size_t)row * 2048;
  int c0 = tid * 8;
  v8s hv = *(const v8s*)(hr + c0);
  float4 ta0 = *(const float4*)(ta + c0);
  float4 ta1 = *(const float4*)(ta + c0 + 4);
  float4 tb0 = *(const float4*)(tb + c0);
  float4 tb1 = *(const float4*)(tb + c0 + 4);
  float sa[8] = {ta0.x, ta0.y, ta0.z, ta0.w, ta1.x, ta1.y, ta1.z, ta1.w};
  float sib[8] = {tb0.x, tb0.y, tb0.z, tb0.w, tb1.x, tb1.y, tb1.z, tb1.w};
  float vals[8];
  float am = 0.f;
#pragma unroll
  for (int j = 0; j < 8; ++j) {
    float v = bf2f((u16)hv[j]);
    float s = __sinf(sa[j] * v);
    v += s * s * sib[j];
    vals[j] = v;
    am = fmaxf(am, fabsf(v));
  }
  am = blk_max256(am, sm);
  float amc = fmaxf(am, 1e-5f);
  float s = 127.0f / amc;
  unsigned long long pkt = 0;
#pragma unroll
  for (int j = 0; j < 8; ++j) {
    int q = (int)rintf(vals[j] * s);
    pkt |= ((unsigned long long)(unsigned char)(signed char)q) << (8 * j);
  }
  *(unsigned long long*)(out + (size_t)row * 2048 + c0) = pkt;
  if (tid == 0) dq[row] = amc * (1.0f / 127.0f);
}

// ---------------------------------------------------------------------------
// Per-token int8 quant of a [M,512] bf16 buffer.
// ---------------------------------------------------------------------------
__global__ __launch_bounds__(256) void rowquant512_bf(
    const u16* __restrict__ in, signed char* __restrict__ out, float* __restrict__ dq) {
  __shared__ float sm[4];
  int row = blockIdx.x, tid = threadIdx.x;
  unsigned pv = *(const unsigned*)(in + (size_t)row * 512 + tid * 2);
  float v0 = bf2f((u16)pv), v1 = bf2f((u16)(pv >> 16));
  float am = blk_max256(fmaxf(fabsf(v0), fabsf(v1)), sm);
  float amc = fmaxf(am, 1e-5f);
  float s = 127.0f / amc;
  signed char q0 = (signed char)(int)rintf(v0 * s);
  signed char q1 = (signed char)(int)rintf(v1 * s);
  unsigned short pk = (unsigned short)((unsigned char)q0 | ((unsigned)(unsigned char)q1 << 8));
  *(unsigned short*)(out + (size_t)row * 512 + tid * 2) = pk;
  if (tid == 0) dq[row] = amc * (1.0f / 127.0f);
}

// ---------------------------------------------------------------------------
// int8 GEMM: acc = (A i8[M,K] @ B i8[N,K]^T) * wsc * dq[m].
// 128xBN tile, BK=64, 4 waves (2x2), JF = BN/32 j-frags per wave.
// OBF: write bf16; else f32 (+resid).
// ---------------------------------------------------------------------------
template <int BN, bool OBF>
__global__ __launch_bounds__(256) void gemm_i8_t(
    const signed char* __restrict__ A, const signed char* __restrict__ B,
    const float* __restrict__ wsp, const float* __restrict__ adq,
    const float* __restrict__ resid, float rscale,
    float* __restrict__ outf, u16* __restrict__ outb, int N, int K) {
  constexpr int JF = BN / 32;  // j-fragments per wave (wave covers 16*JF cols)
  __shared__ signed char As[8192];
  __shared__ signed char Bs[BN * 64];
  const int tid = threadIdx.x;
  const int m0 = blockIdx.y << 7;
  const int n0 = blockIdx.x * BN;
  const int lane = tid & 63;
  const int wv = tid >> 6;
  const int wr = (wv >> 1) << 6, wc = (wv & 1) * (16 * JF);
  const int r15 = lane & 15, khi = lane >> 4;
  const int srow = tid >> 2;
  const int sslot = (tid & 3) ^ ((srow >> 1) & 3);
  const signed char* Ag = A + (size_t)(m0 + srow) * K + sslot * 16;
  const signed char* Bg = B + (size_t)(n0 + srow) * K + sslot * 16;
  const size_t half = (size_t)64 * K;

  int aoff[4], boff[JF];
#pragma unroll
  for (int i = 0; i < 4; ++i) {
    int r = wr + i * 16 + r15;
    aoff[i] = r * 64 + ((khi ^ ((r >> 1) & 3)) << 4);
  }
#pragma unroll
  for (int j = 0; j < JF; ++j) {
    int c = wc + j * 16 + r15;
    boff[j] = c * 64 + ((khi ^ ((c >> 1) & 3)) << 4);
  }
  v4i acc[4][JF] = {};
  for (int k0 = 0; k0 < K; k0 += 64) {
    __syncthreads();
    GLOAD_LDS(Ag + k0, As + tid * 16);
    GLOAD_LDS(Ag + half + k0, As + 4096 + tid * 16);
    GLOAD_LDS(Bg + k0, Bs + tid * 16);
    if constexpr (BN == 128) GLOAD_LDS(Bg + half + k0, Bs + 4096 + tid * 16);
    __syncthreads();
    v4i a[4], b[JF];
#pragma unroll
    for (int i = 0; i < 4; ++i) a[i] = *(const v4i*)(As + aoff[i]);
#pragma unroll
    for (int j = 0; j < JF; ++j) b[j] = *(const v4i*)(Bs + boff[j]);
#pragma unroll
    for (int i = 0; i < 4; ++i)
#pragma unroll
      for (int j = 0; j < JF; ++j)
        acc[i][j] = __builtin_amdgcn_mfma_i32_16x16x64_i8(a[i], b[j], acc[i][j], 0, 0, 0);
  }
  const float wsc = *wsp;
#pragma unroll
  for (int i = 0; i < 4; ++i) {
    int rb = m0 + wr + i * 16 + (khi << 2);
    float dqv[4];
#pragma unroll
    for (int rr = 0; rr < 4; ++rr) dqv[rr] = adq[rb + rr] * wsc;
#pragma unroll
    for (int j = 0; j < JF; ++j) {
      int col = n0 + wc + j * 16 + r15;
#pragma unroll
      for (int rr = 0; rr < 4; ++rr) {
        size_t idx = (size_t)(rb + rr) * N + col;
        float v = (float)acc[i][j][rr] * dqv[rr];
        if constexpr (OBF) outb[idx] = f2bf(v);
        else outf[idx] = resid ? fmaf(rscale, v, resid[idx]) : v;
      }
    }
  }
}

// ---------------------------------------------------------------------------
// bf16 GEMM: acc = A bf16[M,K] @ B bf16[N,K]^T + bias. OBF: bf16 out, else
// f32 resid+acc.
// ---------------------------------------------------------------------------
template <int BN, bool OBF>
__global__ __launch_bounds__(256) void gemm_bf16_t(
    const u16* __restrict__ A, const u16* __restrict__ B,
    const float* __restrict__ bias, const float* __restrict__ resid,
    float* __restrict__ outf, u16* __restrict__ outb, int N, int K) {
  constexpr int JF = BN / 32;
  __shared__ signed char As[8192];
  __shared__ signed char Bs[BN * 64];
  const int tid = threadIdx.x;
  const int m0 = blockIdx.y << 7;
  const int n0 = blockIdx.x * BN;
  const int lane = tid & 63;
  const int wv = tid >> 6;
  const int wr = (wv >> 1) << 6, wc = (wv & 1) * (16 * JF);
  const int r15 = lane & 15, khi = lane >> 4;
  const int srow = tid >> 2;
  const int sslot = (tid & 3) ^ ((srow >> 1) & 3);
  const int K2 = K * 2;
  const signed char* Ag = (const signed char*)A + (size_t)(m0 + srow) * K2 + sslot * 16;
  const signed char* Bg = (const signed char*)B + (size_t)(n0 + srow) * K2 + sslot * 16;
  const size_t half = (size_t)64 * K2;

  int aoff[4], boff[JF];
#pragma unroll
  for (int i = 0; i < 4; ++i) {
    int r = wr + i * 16 + r15;
    aoff[i] = r * 64 + ((khi ^ ((r >> 1) & 3)) << 4);
  }
#pragma unroll
  for (int j = 0; j < JF; ++j) {
    int c = wc + j * 16 + r15;
    boff[j] = c * 64 + ((khi ^ ((c >> 1) & 3)) << 4);
  }
  v4f acc[4][JF] = {};
  for (int kb = 0; kb < K2; kb += 64) {
    __syncthreads();
    GLOAD_LDS(Ag + kb, As + tid * 16);
    GLOAD_LDS(Ag + half + kb, As + 4096 + tid * 16);
    GLOAD_LDS(Bg + kb, Bs + tid * 16);
    if constexpr (BN == 128) GLOAD_LDS(Bg + half + kb, Bs + 4096 + tid * 16);
    __syncthreads();
    v8s a[4], b[JF];
#pragma unroll
    for (int i = 0; i < 4; ++i) a[i] = *(const v8s*)(As + aoff[i]);
#pragma unroll
    for (int j = 0; j < JF; ++j) b[j] = *(const v8s*)(Bs + boff[j]);
#pragma unroll
    for (int i = 0; i < 4; ++i)
#pragma unroll
      for (int j = 0; j < JF; ++j)
        acc[i][j] = __builtin_amdgcn_mfma_f32_16x16x32_bf16(a[i], b[j], acc[i][j], 0, 0, 0);
  }
#pragma unroll
  for (int i = 0; i < 4; ++i) {
    int rb = m0 + wr + i * 16 + (khi << 2);
#pragma unroll
    for (int j = 0; j < JF; ++j) {
      int col = n0 + wc + j * 16 + r15;
      float bv = bias[col];
#pragma unroll
      for (int rr = 0; rr < 4; ++rr) {
        size_t idx = (size_t)(rb + rr) * N + col;
        float v = acc[i][j][rr] + bv;
        if constexpr (OBF) outb[idx] = f2bf(v);
        else outf[idx] = resid[idx] + v;
      }
    }
  }
}

// ---------------------------------------------------------------------------
// Q/K/V fragment pack: kvqp[bh][tile(64)][frag(12)][lane(64)] 16B chunks.
// frag 0..3 = K, 4..7 = V^T (via LDS transpose), 8..11 = Q.
// ---------------------------------------------------------------------------
__global__ __launch_bounds__(256) void kvqpack(
    const u16* __restrict__ qkv, u16* __restrict__ kvqp) {
  __shared__ u16 Lv[32 * 72];  // V rows [t=32][d=64] padded to 72
  const int tid = threadIdx.x;
  const int tile = blockIdx.x;  // 0..63
  const int bh = blockIdx.y;    // 0..31
  const int b = bh >> 3, h = bh & 7;
  u16* outb = kvqp + ((size_t)(bh * 64 + tile)) * 6144;
  const int lane = tid & 63, f = tid >> 6;  // f in 0..3
  const int l31 = lane & 31, hi = lane >> 5;

  // stage V rows into LDS (coalesced)
  {
    int r = tid >> 3, c = (tid & 7) << 3;
    const u16* src = qkv + (size_t)(b * 2048 + tile * 32 + r) * 1536 + 1024 + h * 64 + c;
    *(v8s*)(&Lv[r * 72 + c]) = *(const v8s*)src;
  }
  {  // Q fragment ks = f
    const u16* src = qkv + (size_t)(b * 2048 + tile * 32 + l31) * 1536 + h * 64 + f * 16 + hi * 8;
    *(v8s*)(outb + (size_t)(8 + f) * 512 + lane * 8) = *(const v8s*)src;
  }
  {  // K fragment ks = f
    const u16* src = qkv + (size_t)(b * 2048 + tile * 32 + l31) * 1536 + 512 + h * 64 + f * 16 + hi * 8;
    *(v8s*)(outb + (size_t)f * 512 + lane * 8) = *(const v8s*)src;
  }
  __syncthreads();
  {  // V^T fragment f: d = (f>>1)*32 + l31, t_off = (f&1)*16 + hi*8 + j
    int d = ((f >> 1) << 5) + l31;
    int tbase = ((f & 1) << 4) + hi * 8;
    v8s v;
#pragma unroll
    for (int j = 0; j < 8; ++j) v[j] = (short)Lv[(tbase + j) * 72 + d];
    *(v8s*)(outb + (size_t)(4 + f) * 512 + lane * 8) = v;
  }
}

// ---------------------------------------------------------------------------
// One attention k-tile step. Cross-half traffic via v_permlane32_swap_b32:
//   swap(A,B): A'[<32]=B[l+32], A'[>=32]=A;  B'[<32]=B, B'[>=32]=A[l-32].
// P-fragment words: after swap(pk2,pk0) & swap(pk3,pk1), W0 = [pk0..pk3];
// after swap(pk6,pk4) & swap(pk7,pk5), W1 = [pk4..pk7]  (all lanes).
// ---------------------------------------------------------------------------
__device__ __forceinline__ void attn_step(
    v8s (&kf)[4], v8s (&vf)[4], v8s (&kn)[4], v8s (&vn)[4],
    const v8s (&qf)[4], const u16*& pf, v16f& o0, v16f& o1,
    float& m_run, float& l_run) {
  const float C = 0.18033688011112042f;  // 0.125 * log2(e)
  __builtin_amdgcn_s_setprio(1);
  v16f sacc = {};
#pragma unroll
  for (int ks = 0; ks < 4; ++ks)
    sacc = __builtin_amdgcn_mfma_f32_32x32x16_bf16(kf[ks], qf[ks], sacc, 0, 0, 0);
  __builtin_amdgcn_s_setprio(0);

  // prefetch next tile via running pointer (constant fold-able offsets)
#pragma unroll
  for (int ks = 0; ks < 4; ++ks) kn[ks] = *(const v8s*)(pf + ks * 512);
#pragma unroll
  for (int j = 0; j < 4; ++j) vn[j] = *(const v8s*)(pf + 2048 + j * 512);
  pf += 6144;

  float s[16];
#pragma unroll
  for (int r = 0; r < 16; ++r) s[r] = sacc[r];
  // tree max (depth 3, max3-shaped)
  float m0 = fmaxf(fmaxf(s[0], s[1]), s[2]);
  float m1 = fmaxf(fmaxf(s[3], s[4]), s[5]);
  float m2 = fmaxf(fmaxf(s[6], s[7]), s[8]);
  float m3 = fmaxf(fmaxf(s[9], s[10]), s[11]);
  float m4 = fmaxf(fmaxf(s[12], s[13]), s[14]);
  float t0 = fmaxf(fmaxf(m0, m1), m2);
  float t1 = fmaxf(fmaxf(m3, m4), s[15]);
  float mx = fmaxf(t0, t1);
  {
    float tsw = mx;
    asm("v_permlane32_swap_b32 %0, %1" : "+v"(tsw), "+v"(mx));
    mx = fmaxf(mx, tsw);  // both lanes now hold max(own, partner)
  }
  // defer-max: rescale only when the bound would exceed 2^8
  if (__any((mx - m_run) * C > 8.0f)) {
    float mn = fmaxf(m_run, mx);
    float corr = exp2f((m_run - mn) * C);
    m_run = mn;
    l_run *= corr;
#pragma unroll
    for (int r = 0; r < 16; ++r) { o0[r] *= corr; o1[r] *= corr; }
  }
  float mnC = m_run * C;
#pragma unroll
  for (int r = 0; r < 16; ++r) s[r] = exp2f(fmaf(s[r], C, -mnC));

  // tree sum (depth 4) + cross-half via permlane
  {
    float a0 = (s[0] + s[1]) + (s[2] + s[3]);
    float a1 = (s[4] + s[5]) + (s[6] + s[7]);
    float a2 = (s[8] + s[9]) + (s[10] + s[11]);
    float a3 = (s[12] + s[13]) + (s[14] + s[15]);
    float ls = (a0 + a1) + (a2 + a3);
    float tsw = ls;
    asm("v_permlane32_swap_b32 %0, %1" : "+v"(tsw), "+v"(ls));
    l_run += ls + tsw;
  }

  // pack P to bf16 pairs; permlane swaps assemble both fragment words
  unsigned pk[8];
#pragma unroll
  for (int g = 0; g < 8; ++g) {
    unsigned u;
    asm("v_cvt_pk_bf16_f32 %0, %1, %2" : "=v"(u) : "v"(s[2 * g]), "v"(s[2 * g + 1]));
    pk[g] = u;
  }
  asm("v_permlane32_swap_b32 %0, %1" : "+v"(pk[2]), "+v"(pk[0]));
  asm("v_permlane32_swap_b32 %0, %1" : "+v"(pk[3]), "+v"(pk[1]));
  asm("v_permlane32_swap_b32 %0, %1" : "+v"(pk[6]), "+v"(pk[4]));
  asm("v_permlane32_swap_b32 %0, %1" : "+v"(pk[7]), "+v"(pk[5]));
  v4i w0, w1;
  w0[0] = pk[0]; w0[1] = pk[1]; w0[2] = pk[2]; w0[3] = pk[3];
  w1[0] = pk[4]; w1[1] = pk[5]; w1[2] = pk[6]; w1[3] = pk[7];
  v8s pf0 = *(v8s*)&w0;
  v8s pf1 = *(v8s*)&w1;

  // O^T += V^T · P^T
  __builtin_amdgcn_s_setprio(1);
  o0 = __builtin_amdgcn_mfma_f32_32x32x16_bf16(vf[0], pf0, o0, 0, 0, 0);
  o0 = __builtin_amdgcn_mfma_f32_32x32x16_bf16(vf[1], pf1, o0, 0, 0, 0);
  o1 = __builtin_amdgcn_mfma_f32_32x32x16_bf16(vf[2], pf0, o1, 0, 0, 0);
  o1 = __builtin_amdgcn_mfma_f32_32x32x16_bf16(vf[3], pf1, o1, 0, 0, 0);
  __builtin_amdgcn_s_setprio(0);
}

// ---------------------------------------------------------------------------
// Flash attention, k-split x4. grid (16 qgroups, 32 bh, 4 k-quarters),
// 4 waves. Writes normalized bf16 partials + (m,l) per (z, row, head).
// ---------------------------------------------------------------------------
__global__ __launch_bounds__(256) void attn32(
    const u16* __restrict__ kvqp, u16* __restrict__ opart, float* __restrict__ ml) {
  const int tid = threadIdx.x;
  const int lane = tid & 63;
  const int wv = tid >> 6;
  const int l31 = lane & 31;
  const int hi = lane >> 5;
  const int bh = blockIdx.y;
  const int z = blockIdx.z;
  const int b = bh >> 3, h = bh & 7;
  const int qt = blockIdx.x * 4 + wv;
  const int q0 = qt << 5;

  v8s qf[4];
  {
    const u16* qb = kvqp + ((size_t)(bh * 64 + qt)) * 6144 + lane * 8;
#pragma unroll
    for (int ks = 0; ks < 4; ++ks) qf[ks] = *(const v8s*)(qb + (8 + ks) * 512);
  }
  v16f o0 = {}, o1 = {};
  float m_run = -INFINITY, l_run = 0.f;

  const u16* pf = kvqp + ((size_t)(bh * 64 + z * 16)) * 6144 + lane * 8;

  v8s kfA[4], vfA[4], kfB[4], vfB[4];
#pragma unroll
  for (int ks = 0; ks < 4; ++ks) kfA[ks] = *(const v8s*)(pf + ks * 512);
#pragma unroll
  for (int j = 0; j < 4; ++j) vfA[j] = *(const v8s*)(pf + 2048 + j * 512);
  pf += 6144;

  // 16 tiles, ping-pong A/B (last prefetch reads 1 tile past quarter:
  // harmless, lands in opart region of d_ws, never consumed).
  for (int it = 0; it < 8; ++it) {
    attn_step(kfA, vfA, kfB, vfB, qf, pf, o0, o1, m_run, l_run);
    attn_step(kfB, vfB, kfA, vfA, qf, pf, o0, o1, m_run, l_run);
  }

  float inv = 1.0f / l_run;
  u16* orow = opart + (size_t)z * 4194304 + (size_t)(b * 2048 + q0 + l31) * 512 + h * 64;
#pragma unroll
  for (int dt = 0; dt < 2; ++dt) {
#pragma unroll
    for (int g = 0; g < 8; ++g) {
      int d = dt * 32 + ((2 * g) & 3) + 8 * (g >> 1) + 4 * hi;
      float a = (dt ? o1[2 * g] : o0[2 * g]) * inv;
      float bv = (dt ? o1[2 * g + 1] : o0[2 * g + 1]) * inv;
      unsigned u;
      asm("v_cvt_pk_bf16_f32 %0, %1, %2" : "=v"(u) : "v"(a), "v"(bv));
      *(unsigned*)(orow + d) = u;
    }
  }
  if (hi == 0) {
    size_t mi = ((size_t)(z * 8192 + b * 2048 + q0 + l31) * 8 + h) * 2;
    ml[mi] = m_run;
    ml[mi + 1] = l_run;
  }
}

// ---------------------------------------------------------------------------
// Merge the four k-quarters: attno = sum_z w_z * O_z (flash combine).
// ---------------------------------------------------------------------------
__global__ __launch_bounds__(256) void attn_merge(
    const u16* __restrict__ opart, const float* __restrict__ ml,
    u16* __restrict__ attno) {
  __shared__ float wsm[4][8];
  const int r = blockIdx.x, tid = threadIdx.x;
  if (tid < 8) {
    const float C = 0.18033688011112042f;
    float m[4], l[4];
#pragma unroll
    for (int z = 0; z < 4; ++z) {
      size_t i = ((size_t)(z * 8192 + r) * 8 + tid) * 2;
      m[z] = ml[i];
      l[z] = ml[i + 1];
    }
    float M = fmaxf(fmaxf(m[0], m[1]), fmaxf(m[2], m[3]));
    float a[4], sum = 0.f;
#pragma unroll
    for (int z = 0; z < 4; ++z) {
      a[z] = exp2f((m[z] - M) * C) * l[z];
      sum += a[z];
    }
    float inv = 1.0f / sum;
#pragma unroll
    for (int z = 0; z < 4; ++z) wsm[z][tid] = a[z] * inv;
  }
  __syncthreads();
  int c = tid * 2;
  int hh = c >> 6;
  float x0 = 0.f, x1 = 0.f;
#pragma unroll
  for (int z = 0; z < 4; ++z) {
    unsigned p = *(const unsigned*)(opart + (size_t)z * 4194304 + (size_t)r * 512 + c);
    float w = wsm[z][hh];
    x0 = fmaf(bf2f((u16)p), w, x0);
    x1 = fmaf(bf2f((u16)(p >> 16)), w, x1);
  }
  unsigned u;
  asm("v_cvt_pk_bf16_f32 %0, %1, %2" : "=v"(u) : "v"(x0), "v"(x1));
  *(unsigned*)(attno + (size_t)r * 512 + c) = u;
}

// ---------------------------------------------------------------------------
// Fused GLU + depthwise conv(K=31) + BN + snake. In: g3 bf16 [8192,1024]
// (a|g). Out: bf16 [8192,512]. Block: (chgroup 64, t-tile 128, batch).
// ---------------------------------------------------------------------------
__global__ __launch_bounds__(256) void dwconv_fused(
    const u16* __restrict__ g3, const float* __restrict__ dww,
    const float* __restrict__ dwb, const float* __restrict__ bng,
    const float* __restrict__ bnb, const float* __restrict__ bnm,
    const float* __restrict__ bnv, const float* __restrict__ la,
    const float* __restrict__ lb, u16* __restrict__ outp) {
  __shared__ float IN[160 * 64];
  __shared__ float WT[1984];
  __shared__ float PRM[4][64];
  const int tid = threadIdx.x;
  const int cg = blockIdx.x << 6;
  const int t0 = blockIdx.y << 7;
  const int bb = blockIdx.z;

  if (tid < 64) {
    int c = cg + tid;
    float sc = bng[c] / sqrtf(bnv[c] + 1e-5f);
    PRM[0][tid] = sc;
    PRM[1][tid] = (dwb[c] - bnm[c]) * sc + bnb[c];
    PRM[2][tid] = __expf(la[c]);
    PRM[3][tid] = 1.0f / (__expf(lb[c]) + 1e-9f);
  }
  for (int i = tid; i < 1984; i += 256) WT[i] = dww[cg * 31 + i];

#pragma unroll
  for (int p = 0; p < 5; ++p) {
    int r = p * 32 + (tid >> 3);
    int t = t0 - 16 + r;
    int c8 = (tid & 7) << 3;
    float4 lo = make_float4(0.f, 0.f, 0.f, 0.f);
    float4 hv = make_float4(0.f, 0.f, 0.f, 0.f);
    if (t >= 0 && t < 2048) {
      const u16* rp = g3 + ((size_t)(bb * 2048 + t)) * 1024 + cg + c8;
      v8s a8 = *(const v8s*)rp;
      v8s g8 = *(const v8s*)(rp + 512);
      float va[8];
#pragma unroll
      for (int j = 0; j < 8; ++j) {
        float fa = bf2f((u16)a8[j]);
        float fg = bf2f((u16)g8[j]);
        va[j] = fa / (1.f + __expf(-fg));
      }
      lo = make_float4(va[0], va[1], va[2], va[3]);
      hv = make_float4(va[4], va[5], va[6], va[7]);
    }
    *(float4*)&IN[r * 64 + c8] = lo;
    *(float4*)&IN[r * 64 + c8 + 4] = hv;
  }
  __syncthreads();

  const int ch = tid & 63;
  const int tg = tid >> 6;
  const float sc = PRM[0][ch], sh = PRM[1][ch], sa = PRM[2][ch], sib = PRM[3][ch];
  float w[31];
#pragma unroll
  for (int k = 0; k < 31; ++k) w[k] = WT[ch * 31 + k];

  for (int pass = 0; pass < 4; ++pass) {
    int tl = pass * 32 + tg * 8;
    float x[38];
#pragma unroll
    for (int i = 0; i < 38; ++i) x[i] = IN[(tl + 1 + i) * 64 + ch];
    float acc[8] = {0.f, 0.f, 0.f, 0.f, 0.f, 0.f, 0.f, 0.f};
#pragma unroll
    for (int k = 0; k < 31; ++k)
#pragma unroll
      for (int j = 0; j < 8; ++j) acc[j] = fmaf(x[k + j], w[k], acc[j]);
#pragma unroll
    for (int j = 0; j < 8; ++j) {
      float v = acc[j] * sc + sh;
      float s = __sinf(sa * v);
      v += s * s * sib;
      outp[((size_t)(bb * 2048 + t0 + tl + j)) * 512 + cg + ch] = f2bf(v);
    }
  }
}

// ---------------------------------------------------------------------------
extern "C" void kernel_launch(void* const* d_in, const int* in_sizes, int n_in,
                              void* d_out, int out_size, void* d_ws, size_t ws_size,
                              hipStream_t stream) {
  const float* x_in = (const float*)d_in[0];
  const float* ff1_norm_w = (const float*)d_in[1];
  const float* ff1_w1 = (const float*)d_in[2];
  const float* ff1_a = (const float*)d_in[3];
  const float* ff1_b = (const float*)d_in[4];
  const float* ff1_w2 = (const float*)d_in[5];
  const float* attn_norm_w = (const float*)d_in[6];
  const float* in_proj_w = (const float*)d_in[7];
  const float* in_proj_b = (const float*)d_in[8];
  const float* out_proj_w = (const float*)d_in[9];
  const float* out_proj_b = (const float*)d_in[10];
  const float* conv_norm_w = (const float*)d_in[11];
  const float* pw1_w = (const float*)d_in[12];
  const float* dw_w = (const float*)d_in[13];
  const float* dw_b = (const float*)d_in[14];
  const float* bn_g = (const float*)d_in[15];
  const float* bn_b = (const float*)d_in[16];
  const float* bn_m = (const float*)d_in[17];
  const float* bn_v = (const float*)d_in[18];
  const float* snake_a = (const float*)d_in[19];
  const float* snake_b = (const float*)d_in[20];
  const float* pw2_w = (const float*)d_in[21];
  const float* ff2_norm_w = (const float*)d_in[22];
  const float* ff2_w1 = (const float*)d_in[23];
  const float* ff2_a = (const float*)d_in[24];
  const float* ff2_b = (const float*)d_in[25];
  const float* ff2_w2 = (const float*)d_in[26];
  const float* final_norm_w = (const float*)d_in[27];
  float* out = (float*)d_out;

  char* ws = (char*)d_ws;
  float* x_cur = (float*)(ws + 0);                     // 16 MiB
  // attn phase:
  u16* qkv = (u16*)(ws + 16777216);                    // 24 MiB
  u16* kvqp = (u16*)(ws + 41943040);                   // 24 MiB (Q/K/V frags)
  u16* opart = (u16*)(ws + 67108864);                  // 32 MiB (4 x 8 MiB)
  u16* attno = (u16*)(ws + 100663296);                 // 8 MiB
  float* ml = (float*)(ws + 109051904);                // 2 MiB
  // FFN phase:
  u16* h_b = (u16*)(ws + 16777216);                    // 32 MiB
  // conv phase:
  u16* g3b = (u16*)(ws + 16777216);                    // 16 MiB
  u16* convout = (u16*)(ws + 50331648);                // 8 MiB (bf16)
  signed char* a8a = (signed char*)(ws + 83886080);    // 4 MiB (FFN phases)
  signed char* a8b = (signed char*)(ws + 88080384);    // 16 MiB (FFN phases)
  u16* xnb = (u16*)(ws + 104857600);                   // 8 MiB (dead before attno/ml writes)
  signed char* wq = (signed char*)(ws + 113246208);    // 4.75 MiB
  signed char* wq_w1 = wq;
  signed char* wq_w2 = wq + 1048576;
  signed char* wq_p1 = wq + 2097152;
  signed char* wq_p2 = wq + 2621440;
  signed char* wq_f21 = wq + 2883584;
  signed char* wq_f22 = wq + 3932160;
  u16* wb = (u16*)(ws + 118226944);                    // 2 MiB
  u16* wb_ip = wb;
  u16* wb_op = wb + 786432;
  float* scales = (float*)(ws + 120324096);
  float* partials = (float*)(ws + 120324352);
  float* ascale = (float*)(ws + 120325888);            // 32 KiB
  float* tabs = (float*)(ws + 120358912);              // 32 KiB

  // --- weight prep ---
  wabs_stage1<<<384, 256, 0, stream>>>(ff1_w1, ff1_w2, pw1_w, pw2_w, ff2_w1, ff2_w2, partials);
  wquant_all<<<dim3(128, 6), 256, 0, stream>>>(ff1_w1, ff1_w2, pw1_w, pw2_w, ff2_w1, ff2_w2,
                                               partials, scales, wq);
  wcvt_tabs<<<4104, 256, 0, stream>>>(in_proj_w, out_proj_w, wb, ff1_a, ff1_b, ff2_a, ff2_b,
                                      tabs);

  // --- FFN1: x_cur = x + 0.5*ffn(x) ---
  rmsnorm_multi<<<8192, 256, 0, stream>>>(x_in, ff1_norm_w, 1, nullptr, a8a, nullptr, ascale);
  gemm_i8_t<128, true><<<dim3(16, 64), 256, 0, stream>>>(
      a8a, wq_w1, scales + 0, ascale, nullptr, 1.0f, nullptr, h_b, 2048, 512);
  snake_q8<<<8192, 256, 0, stream>>>(h_b, tabs, tabs + 2048, a8b, ascale);
  gemm_i8_t<64, false><<<dim3(8, 64), 256, 0, stream>>>(
      a8b, wq_w2, scales + 1, ascale, x_in, 0.5f, x_cur, nullptr, 512, 2048);

  // --- MHA: x_cur += mha(x_cur) ---
  rmsnorm_multi<<<8192, 256, 0, stream>>>(x_cur, attn_norm_w, 2, nullptr, nullptr, xnb, nullptr);
  gemm_bf16_t<128, true><<<dim3(12, 64), 256, 0, stream>>>(
      xnb, wb_ip, in_proj_b, nullptr, nullptr, qkv, 1536, 512);
  kvqpack<<<dim3(64, 32), 256, 0, stream>>>(qkv, kvqp);
  attn32<<<dim3(16, 32, 4), 256, 0, stream>>>(kvqp, opart, ml);
  attn_merge<<<8192, 256, 0, stream>>>(opart, ml, attno);
  gemm_bf16_t<64, false><<<dim3(8, 64), 256, 0, stream>>>(
      attno, wb_op, out_proj_b, x_cur, x_cur, nullptr, 512, 512);

  // --- conv branch: x_cur += conv(x_cur) ---
  rmsnorm_multi<<<8192, 256, 0, stream>>>(x_cur, conv_norm_w, 1, nullptr, a8a, nullptr, ascale);
  gemm_i8_t<128, true><<<dim3(8, 64), 256, 0, stream>>>(
      a8a, wq_p1, scales + 2, ascale, nullptr, 1.0f, nullptr, g3b, 1024, 512);
  dwconv_fused<<<dim3(8, 16, 4), 256, 0, stream>>>(g3b, dw_w, dw_b, bn_g, bn_b, bn_m, bn_v,
                                                   snake_a, snake_b, convout);
  rowquant512_bf<<<8192, 256, 0, stream>>>(convout, a8a, ascale);
  gemm_i8_t<64, false><<<dim3(8, 64), 256, 0, stream>>>(
      a8a, wq_p2, scales + 3, ascale, x_cur, 1.0f, x_cur, nullptr, 512, 512);

  // --- FFN2: x_cur += 0.5*ffn(x_cur) ---
  rmsnorm_multi<<<8192, 256, 0, stream>>>(x_cur, ff2_norm_w, 1, nullptr, a8a, nullptr, ascale);
  gemm_i8_t<128, true><<<dim3(16, 64), 256, 0, stream>>>(
      a8a, wq_f21, scales + 4, ascale, nullptr, 1.0f, nullptr, h_b, 2048, 512);
  snake_q8<<<8192, 256, 0, stream>>>(h_b, tabs + 4096, tabs + 6144, a8b, ascale);
  gemm_i8_t<64, false><<<dim3(8, 64), 256, 0, stream>>>(
      a8b, wq_f22, scales + 5, ascale, x_cur, 0.5f, x_cur, nullptr, 512, 2048);

  // --- final rmsnorm -> out ---
  rmsnorm_multi<<<8192, 256, 0, stream>>>(x_cur, final_norm_w, 0, out, nullptr, nullptr, nullptr);
}